// Round 4
// baseline (313.190 us; speedup 1.0000x reference)
//
#include <hip/hip_runtime.h>
#include <hip/hip_bf16.h>

typedef __hip_bfloat16 bf16;
typedef short s8v __attribute__((ext_vector_type(8)));
typedef float f4v __attribute__((ext_vector_type(4)));

#define B   128
#define N   2000
#define S   64
#define CAP 128          // max neighbors per row (mean ~65, 8-sigma safe)
#define JT  16           // neighbors per block in k_x2
#define XROW 1088        // S*17

__device__ inline ushort bfb(float v) {
    union { __hip_bfloat16 h; ushort u; } c; c.h = __float2bfloat16(v); return c.u;
}

// ---------------- kernel 1: d[m] = rsqrt(sum(adj[m,:]) + 1) ----------------
__global__ __launch_bounds__(256) void k_rowsum(const float* __restrict__ adj,
                                                float* __restrict__ d) {
    int m = blockIdx.x;
    const float* row = adj + (size_t)m * N;
    float s = 0.f;
    for (int c = threadIdx.x; c < N; c += 256) s += row[c];
    for (int o = 32; o > 0; o >>= 1) s += __shfl_down(s, o);
    __shared__ float red[4];
    int wave = threadIdx.x >> 6;
    if ((threadIdx.x & 63) == 0) red[wave] = s;
    __syncthreads();
    if (threadIdx.x == 0)
        d[m] = rsqrtf(red[0] + red[1] + red[2] + red[3] + 1.0f);
}

// ---------------- kernel 2: CSR of Ahat (ordered ballot compaction) --------
__global__ __launch_bounds__(64) void k_csr(const float* __restrict__ adj,
                                            const float* __restrict__ d,
                                            int* __restrict__ cnt,
                                            int* __restrict__ idx,
                                            float* __restrict__ val) {
    int m = blockIdx.x;
    int lane = threadIdx.x;
    const float* row = adj + (size_t)m * N;
    float dm = d[m];
    int base = 0;
    for (int c0 = 0; c0 < N; c0 += 64) {
        int c = c0 + lane;
        float a = 0.f;
        if (c < N) { a = row[c]; if (c == m) a += 1.0f; }
        bool pred = (a != 0.f);
        unsigned long long mask = __ballot(pred);
        int pos = base + __popcll(mask & ((1ull << lane) - 1ull));
        if (pred && pos < CAP) {
            idx[m * CAP + pos] = c;
            val[m * CAP + pos] = dm * d[c] * a;
        }
        base += (int)__popcll(mask);
    }
    if (lane == 0) cnt[m] = base < CAP ? base : CAP;
}

// ---------------- kernel 3: extract sids / sid_last / dss-premult feats ----
__global__ __launch_bounds__(256) void k_extract(const float* __restrict__ x,
                                                 const float* __restrict__ d,
                                                 int* __restrict__ sid,
                                                 int* __restrict__ sid_last,
                                                 float* __restrict__ fes) {
    int b = blockIdx.x, tid = threadIdx.x;
    const float* xb = x + (size_t)b * XROW;
    __shared__ float dss_sh[63];
    if (tid < S - 1) {
        int s_ = (int)xb[tid * 17 + 15];
        sid[b * (S - 1) + tid] = s_;
        dss_sh[tid] = d[s_];
    }
    if (tid == S - 1) sid_last[b] = (int)xb[(S - 1) * 17 + 15];
    __syncthreads();
    for (int i = tid; i < (S - 1) * 16; i += 256) {
        int t = i >> 4, f = i & 15;
        fes[(size_t)b * 1008 + i] = dss_sh[t] * xb[t * 17 + (f < 15 ? f : 16)];
    }
}

// ---------------- kernel 3b: pack W1^T MFMA fragments (bf16, K-pad to 32) --
__global__ __launch_bounds__(256) void k_wfrag(const float* __restrict__ w1,
                                               uint4* __restrict__ wf) {
    int e = blockIdx.x * 256 + threadIdx.x;       // 0..1023
    int ct = e >> 6, l = e & 63;
    int kg = l >> 4, ch = ct * 16 + (l & 15);
    ushort h[8];
#pragma unroll
    for (int j = 0; j < 8; ++j) {
        int f = kg * 8 + j;
        h[j] = (f < 16) ? bfb(w1[f * 256 + ch]) : (ushort)0;
    }
    uint4 r;
    r.x = h[0] | ((uint)h[1] << 16);
    r.y = h[2] | ((uint)h[3] << 16);
    r.z = h[4] | ((uint)h[5] << 16);
    r.w = h[6] | ((uint)h[7] << 16);
    wf[e] = r;
}

// ---------------- kernel 3c: pack W2 MFMA B-fragments (bf16) ---------------
// e = (nt*8 + kc)*64 + lane: 8 bf16 of w2[kc*32 + (lane>>4)*8 + i][nt*16 + (lane&15)]
__global__ __launch_bounds__(256) void k_w2frag(const float* __restrict__ w2,
                                                uint4* __restrict__ wf) {
    int e = blockIdx.x * 256 + threadIdx.x;       // 0..8191
    int l = e & 63;
    int kc = (e >> 6) & 7;
    int nt = e >> 9;
    int col = l & 15, kg = l >> 4;
    ushort h[8];
#pragma unroll
    for (int i = 0; i < 8; ++i) {
        int k = kc * 32 + kg * 8 + i;
        h[i] = bfb(w2[k * 256 + nt * 16 + col]);
    }
    uint4 r;
    r.x = h[0] | ((uint)h[1] << 16);
    r.y = h[2] | ((uint)h[3] << 16);
    r.z = h[4] | ((uint)h[5] << 16);
    r.w = h[6] | ((uint)h[7] << 16);
    wf[e] = r;
}

// ---------------- kernel 4: X1[b,p,:] = relu((Ahat X)[b,p] @ w1 + b1) ------
__global__ __launch_bounds__(256) void k_x1(const float* __restrict__ adj,
                                            const float* __restrict__ d,
                                            const int* __restrict__ sid,
                                            const float* __restrict__ fes,
                                            const uint4* __restrict__ wfrag,
                                            const float* __restrict__ b1,
                                            bf16* __restrict__ X1) {
    __shared__ ushort Ylds[64][32];
    __shared__ float b1s[256];
    int b = blockIdx.y, p0 = blockIdx.x * 64, tid = threadIdx.x;
    b1s[tid] = b1[tid];

    int pl = tid & 63;
    int fgu = __builtin_amdgcn_readfirstlane(tid >> 6);   // wave-uniform -> SGPR
    int f0 = fgu * 4;
    int p = p0 + pl;
    const float* fes_b = fes + (size_t)b * 1008 + f0;     // uniform base
    const int* sid_b = sid + b * 63;
    float a0 = 0.f, a1 = 0.f, a2 = 0.f, a3 = 0.f;
    if (p < N) {
        for (int t = 0; t < 63; ++t) {
            int s_ = sid_b[t];                             // uniform -> s_load
            float a = adj[(size_t)s_ * N + p];
            if (p == s_) a += 1.0f;
            const float* fr = fes_b + t * 16;              // uniform -> s_load
            a0 += a * fr[0]; a1 += a * fr[1];
            a2 += a * fr[2]; a3 += a * fr[3];
        }
    }
    float dp = (p < N) ? d[p] : 0.f;
    a0 *= dp; a1 *= dp; a2 *= dp; a3 *= dp;
    uint lo = bfb(a0) | ((uint)bfb(a1) << 16);
    uint hi = bfb(a2) | ((uint)bfb(a3) << 16);
    *(uint2*)&Ylds[pl][f0] = make_uint2(lo, hi);
    *(uint2*)&Ylds[pl][16 + f0] = make_uint2(0u, 0u);      // K-pad zeros
    __syncthreads();

    // ---- phase 2 ----
    int l = tid & 63, wv = tid >> 6;
    int lm = l & 15, lg = l >> 4;
    s8v yf = *(const s8v*)&Ylds[wv * 16 + lm][lg * 8];     // B = Y^T frag
    f4v acc[16];
#pragma unroll
    for (int ct = 0; ct < 16; ++ct) acc[ct] = (f4v){0.f, 0.f, 0.f, 0.f};
#pragma unroll
    for (int ct = 0; ct < 16; ++ct) {
        s8v wfv = *(const s8v*)&wfrag[ct * 64 + l];        // A = W^T frag
        acc[ct] = __builtin_amdgcn_mfma_f32_16x16x32_bf16(wfv, yf, acc[ct], 0, 0, 0);
    }
    int pp = p0 + wv * 16 + lm;
    if (pp < N) {
        uint2* dst = (uint2*)X1 + ((size_t)b * N + pp) * 64;
#pragma unroll
        for (int ct = 0; ct < 16; ++ct) {
            float4 bz = *(float4*)&b1s[ct * 16 + lg * 4];
            float v0 = acc[ct][0] + bz.x; v0 = v0 > 0.f ? v0 : 0.f;
            float v1 = acc[ct][1] + bz.y; v1 = v1 > 0.f ? v1 : 0.f;
            float v2 = acc[ct][2] + bz.z; v2 = v2 > 0.f ? v2 : 0.f;
            float v3 = acc[ct][3] + bz.w; v3 = v3 > 0.f ? v3 : 0.f;
            uint2 pk;
            pk.x = bfb(v0) | ((uint)bfb(v1) << 16);
            pk.y = bfb(v2) | ((uint)bfb(v3) << 16);
            dst[ct * 4 + lg] = pk;
        }
    }
}

// ---------------- kernel 5: X2 at one-hop(m_b), JT=16 neighbors per block --
// aggregation: one wave per j-row, whole X1 row per global_load_dwordx2
// matmul tail: agg(bf16, LDS) @ w2frag via mfma_f32_16x16x32_bf16
__global__ __launch_bounds__(256) void k_x2(const int* __restrict__ cnt,
                                            const int* __restrict__ idxA,
                                            const float* __restrict__ valA,
                                            const int* __restrict__ sid_last,
                                            const bf16* __restrict__ X1,
                                            const uint4* __restrict__ w2f,
                                            const float* __restrict__ b2,
                                            float* __restrict__ X2) {
    __shared__ int    nns[JT];
    __shared__ int    ncn_s[JT];
    __shared__ int    nidx[JT][CAP];
    __shared__ float  nval[JT][CAP];
    __shared__ ushort agg[JT][264];   // 528B row stride: 2-way max bank aliasing
    int b = blockIdx.y, j0 = blockIdx.x * JT, tid = threadIdx.x;
    int m = sid_last[b];
    int cj = cnt[m];
    if (j0 >= cj) return;
    int nj = cj - j0; if (nj > JT) nj = JT;
    if (tid < JT) {
        int n = idxA[m * CAP + j0 + (tid < nj ? tid : 0)];
        nns[tid] = n;
        ncn_s[tid] = (tid < nj) ? cnt[n] : 0;
    }
    __syncthreads();
    for (int i = tid; i < JT * CAP; i += 256) {
        int jj = i >> 7, k = i & (CAP - 1);
        int n = nns[jj];
        nidx[jj][k] = idxA[n * CAP + k];
        nval[jj][k] = valA[n * CAP + k];
    }
    __syncthreads();
    int lane = tid & 63, w = tid >> 6;
    const uint2* X1bl = (const uint2*)X1 + (size_t)b * N * 64 + lane;
    for (int jj = 0; jj < 4; ++jj) {
        int j = w * 4 + jj;
        int cn = ncn_s[j];
        float a0 = 0.f, a1 = 0.f, a2 = 0.f, a3 = 0.f;
        if (cn > 0) {
            int p = nidx[j][0];
            float v = nval[j][0];
            uint2 u = X1bl[(size_t)p * 64];
            for (int k = 0; k < cn; ++k) {
                uint2 uc = u; float vc = v;
                if (k + 1 < cn) {
                    p = nidx[j][k + 1];
                    v = nval[j][k + 1];
                    u = X1bl[(size_t)p * 64];
                }
                float f0 = __uint_as_float(uc.x << 16);
                float f1 = __uint_as_float(uc.x & 0xffff0000u);
                float f2 = __uint_as_float(uc.y << 16);
                float f3 = __uint_as_float(uc.y & 0xffff0000u);
                a0 += vc * f0; a1 += vc * f1; a2 += vc * f2; a3 += vc * f3;
            }
        }
        uint2 pk;
        pk.x = bfb(a0) | ((uint)bfb(a1) << 16);
        pk.y = bfb(a2) | ((uint)bfb(a3) << 16);
        *(uint2*)&agg[j][lane * 4] = pk;
    }
    __syncthreads();
    // MFMA tail: D[j, n] = agg[16 x 256] @ w2[256 x 256], one 16-wide n-tile/wave/t
    int col = lane & 15, rg = lane >> 4;
    s8v af[8];
#pragma unroll
    for (int kc = 0; kc < 8; ++kc)
        af[kc] = *(const s8v*)&agg[col][kc * 32 + rg * 8];   // A: row=lane&15 (j)
#pragma unroll
    for (int t = 0; t < 4; ++t) {
        int nt = w * 4 + t;
        f4v acc = (f4v){0.f, 0.f, 0.f, 0.f};
#pragma unroll
        for (int kc = 0; kc < 8; ++kc) {
            s8v bf = *(const s8v*)&w2f[(nt * 8 + kc) * 64 + lane];
            acc = __builtin_amdgcn_mfma_f32_16x16x32_bf16(af[kc], bf, acc, 0, 0, 0);
        }
        float bv = b2[nt * 16 + col];
        float* dst = X2 + ((size_t)b * CAP + j0) * 256 + nt * 16 + col;
#pragma unroll
        for (int i = 0; i < 4; ++i) {
            int row = rg * 4 + i;
            if (row < nj) {
                float vv = acc[i] + bv;
                dst[(size_t)row * 256] = vv > 0.f ? vv : 0.f;
            }
        }
    }
}

// ---------------- kernel 6: g[b] = relu((Ahat X2)[b,m_b] @ w3 + b3) --------
__global__ __launch_bounds__(256) void k_g(const int* __restrict__ cnt,
                                           const int* __restrict__ idxA,
                                           const float* __restrict__ valA,
                                           const int* __restrict__ sid_last,
                                           const float* __restrict__ X2,
                                           const float* __restrict__ w3,
                                           const float* __restrict__ b3,
                                           float* __restrict__ g) {
    int b = blockIdx.x, tid = threadIdx.x;
    int m = sid_last[b];
    int cj = cnt[m];
    __shared__ float g1[256];
    float acc = 0.f;
    for (int jj = 0; jj < cj; ++jj)
        acc += valA[m * CAP + jj] * X2[((size_t)b * CAP + jj) * 256 + tid];
    g1[tid] = acc;
    __syncthreads();
    for (int oo = tid; oo < 512; oo += 256) {
        float a2 = b3[oo];
#pragma unroll 4
        for (int f = 0; f < 256; ++f) a2 += g1[f] * w3[f * 512 + oo];
        g[(size_t)b * 512 + oo] = a2 > 0.f ? a2 : 0.f;
    }
}

// ---------------- kernel 7: hp0 = x_last[:, :15] @ w0 + b0 -----------------
__global__ __launch_bounds__(256) void k_fc0(const float* __restrict__ x,
                                             const float* __restrict__ w0,
                                             const float* __restrict__ b0,
                                             float* __restrict__ hp0) {
    int i = blockIdx.x * 256 + threadIdx.x;
    int b = i >> 9, o = i & 511;
    const float* xr = x + (size_t)b * XROW + (S - 1) * 17;
    float acc = b0[o];
#pragma unroll
    for (int f = 0; f < 15; ++f) acc += xr[f] * w0[f * 512 + o];
    hp0[i] = acc;
}

// ---------------- kernel 8/10: batch-norm stats (biased var) ---------------
__global__ __launch_bounds__(256) void k_bnstats(const float* __restrict__ h,
                                                 float* __restrict__ mu,
                                                 float* __restrict__ rstd) {
    int o = blockIdx.x * 256 + threadIdx.x;
    float s = 0.f, s2 = 0.f;
    for (int b = 0; b < B; ++b) { float v = h[b * 512 + o]; s += v; s2 += v * v; }
    float m = s * (1.f / B);
    float var = s2 * (1.f / B) - m * m;
    mu[o] = m;
    rstd[o] = rsqrtf(var + 1e-5f);
}

// ---------------- kernel 9: hp1 = [leaky(bn(hp0)), g] @ w1 + b1 ------------
__global__ __launch_bounds__(256) void k_fc1(const float* __restrict__ hp0,
                                             const float* __restrict__ mu0,
                                             const float* __restrict__ rstd0,
                                             const float* __restrict__ gam,
                                             const float* __restrict__ bet,
                                             const float* __restrict__ gbuf,
                                             const float* __restrict__ w1,
                                             const float* __restrict__ b1,
                                             float* __restrict__ hp1) {
    int b = blockIdx.x, ot = blockIdx.y, tid = threadIdx.x;
    __shared__ float h[1024];
    for (int o = tid; o < 512; o += 256) {
        float v = hp0[b * 512 + o];
        v = gam[o] * (v - mu0[o]) * rstd0[o] + bet[o];
        h[o] = v >= 0.f ? v : 0.01f * v;
        h[512 + o] = gbuf[(size_t)b * 512 + o];
    }
    __syncthreads();
    int q  = tid & 31;
    int kg = tid >> 5;
    const float4* w4 = (const float4*)w1;
    int wq = ot * 32 + q;
    float4 acc = {0.f, 0.f, 0.f, 0.f};
    for (int k = kg * 128; k < kg * 128 + 128; ++k) {
        float hk = h[k];
        float4 w = w4[(size_t)k * 128 + wq];
        acc.x += hk * w.x; acc.y += hk * w.y; acc.z += hk * w.z; acc.w += hk * w.w;
    }
    __shared__ float4 red[8][32];
    red[kg][q] = acc;
    __syncthreads();
    if (tid < 32) {
        float4 s = red[0][tid];
#pragma unroll
        for (int gr = 1; gr < 8; ++gr) {
            float4 r = red[gr][tid];
            s.x += r.x; s.y += r.y; s.z += r.z; s.w += r.w;
        }
        int ob = ot * 128 + tid * 4;
        s.x += b1[ob]; s.y += b1[ob + 1]; s.z += b1[ob + 2]; s.w += b1[ob + 3];
        *(float4*)&hp1[b * 512 + ob] = s;
    }
}

// ---------------- kernel 11: out = sigmoid(leaky(bn(hp1)) @ w2 + b2) -------
__global__ __launch_bounds__(64) void k_out(const float* __restrict__ hp1,
                                            const float* __restrict__ mu1,
                                            const float* __restrict__ rstd1,
                                            const float* __restrict__ gam,
                                            const float* __restrict__ bet,
                                            const float* __restrict__ w2,
                                            const float* __restrict__ b2,
                                            float* __restrict__ out) {
    int b = blockIdx.x, lane = threadIdx.x;
    float acc = 0.f;
    for (int o = lane; o < 512; o += 64) {
        float v = hp1[b * 512 + o];
        v = gam[o] * (v - mu1[o]) * rstd1[o] + bet[o];
        v = v >= 0.f ? v : 0.01f * v;
        acc += v * w2[o];
    }
    for (int off = 32; off > 0; off >>= 1) acc += __shfl_down(acc, off);
    if (lane == 0) out[b] = 1.f / (1.f + expf(-(acc + b2[0])));
}

static inline size_t align256(size_t x) { return (x + 255) & ~(size_t)255; }

extern "C" void kernel_launch(void* const* d_in, const int* in_sizes, int n_in,
                              void* d_out, int out_size, void* d_ws, size_t ws_size,
                              hipStream_t stream) {
    const float* x     = (const float*)d_in[0];
    const float* adj   = (const float*)d_in[1];
    const float* w_gc1 = (const float*)d_in[2];
    const float* b_gc1 = (const float*)d_in[3];
    const float* w_gc2 = (const float*)d_in[4];
    const float* b_gc2 = (const float*)d_in[5];
    const float* w_gc3 = (const float*)d_in[6];
    const float* b_gc3 = (const float*)d_in[7];
    const float* w_fc0 = (const float*)d_in[8];
    const float* b_fc0 = (const float*)d_in[9];
    const float* g_fc0 = (const float*)d_in[10];
    const float* be_fc0= (const float*)d_in[11];
    const float* w_fc1 = (const float*)d_in[12];
    const float* b_fc1 = (const float*)d_in[13];
    const float* g_fc1 = (const float*)d_in[14];
    const float* be_fc1= (const float*)d_in[15];
    const float* w_fc2 = (const float*)d_in[16];
    const float* b_fc2 = (const float*)d_in[17];

    char* wsp = (char*)d_ws;
    size_t off = 0;
    auto alloc = [&](size_t bytes) { void* p = wsp + off; off = align256(off + bytes); return p; };
    float* d_deg   = (float*)alloc((size_t)N * 4);
    int*   sid     = (int*)  alloc((size_t)B * 63 * 4);
    int*   sidl    = (int*)  alloc((size_t)B * 4);
    float* fes     = (float*)alloc((size_t)B * 63 * 16 * 4);
    uint4* wfrag   = (uint4*)alloc((size_t)1024 * 16);
    uint4* w2frag  = (uint4*)alloc((size_t)8192 * 16);
    int*   csr_cnt = (int*)  alloc((size_t)N * 4);
    int*   csr_idx = (int*)  alloc((size_t)N * CAP * 4);
    float* csr_val = (float*)alloc((size_t)N * CAP * 4);
    bf16*  X1      = (bf16*) alloc((size_t)B * N * 256 * 2);
    float* X2      = (float*)alloc((size_t)B * CAP * 256 * 4);
    float* gbuf    = (float*)alloc((size_t)B * 512 * 4);
    float* hp0     = (float*)alloc((size_t)B * 512 * 4);
    float* mu0     = (float*)alloc(512 * 4);
    float* rstd0   = (float*)alloc(512 * 4);
    float* hp1     = (float*)alloc((size_t)B * 512 * 4);
    float* mu1     = (float*)alloc(512 * 4);
    float* rstd1   = (float*)alloc(512 * 4);

    k_rowsum <<<N, 256, 0, stream>>>(adj, d_deg);
    k_csr    <<<N, 64, 0, stream>>>(adj, d_deg, csr_cnt, csr_idx, csr_val);
    k_extract<<<B, 256, 0, stream>>>(x, d_deg, sid, sidl, fes);
    k_wfrag  <<<4, 256, 0, stream>>>(w_gc1, wfrag);
    k_w2frag <<<32, 256, 0, stream>>>(w_gc2, w2frag);
    k_x1     <<<dim3(32, B), 256, 0, stream>>>(adj, d_deg, sid, fes, wfrag, b_gc1, X1);
    k_x2     <<<dim3(CAP / JT, B), 256, 0, stream>>>(csr_cnt, csr_idx, csr_val, sidl, X1, w2frag, b_gc2, X2);
    k_g      <<<B, 256, 0, stream>>>(csr_cnt, csr_idx, csr_val, sidl, X2, w_gc3, b_gc3, gbuf);
    k_fc0    <<<(B * 512) / 256, 256, 0, stream>>>(x, w_fc0, b_fc0, hp0);
    k_bnstats<<<2, 256, 0, stream>>>(hp0, mu0, rstd0);
    k_fc1    <<<dim3(B, 4), 256, 0, stream>>>(hp0, mu0, rstd0, g_fc0, be_fc0, gbuf, w_fc1, b_fc1, hp1);
    k_bnstats<<<2, 256, 0, stream>>>(hp1, mu1, rstd1);
    k_out    <<<B, 64, 0, stream>>>(hp1, mu1, rstd1, g_fc1, be_fc1, w_fc2, b_fc2, (float*)d_out);
}

// Round 5
// 276.054 us; speedup vs baseline: 1.1345x; 1.1345x over previous
//
#include <hip/hip_runtime.h>
#include <hip/hip_bf16.h>

typedef __hip_bfloat16 bf16;
typedef short s8v __attribute__((ext_vector_type(8)));
typedef float f4v __attribute__((ext_vector_type(4)));

#define B   128
#define N   2000
#define S   64
#define CAP 128          // max neighbors per row (mean ~65, 8-sigma safe)
#define JT  16           // neighbors per block in k_x2
#define XROW 1088        // S*17

__device__ inline ushort bfb(float v) {
    union { __hip_bfloat16 h; ushort u; } c; c.h = __float2bfloat16(v); return c.u;
}

// ---------------- kernel 1: d[m] = rsqrt(sum(adj[m,:]) + 1) ----------------
__global__ __launch_bounds__(256) void k_rowsum(const float* __restrict__ adj,
                                                float* __restrict__ d) {
    int m = blockIdx.x;
    const float* row = adj + (size_t)m * N;
    float s = 0.f;
    for (int c = threadIdx.x; c < N; c += 256) s += row[c];
    for (int o = 32; o > 0; o >>= 1) s += __shfl_down(s, o);
    __shared__ float red[4];
    int wave = threadIdx.x >> 6;
    if ((threadIdx.x & 63) == 0) red[wave] = s;
    __syncthreads();
    if (threadIdx.x == 0)
        d[m] = rsqrtf(red[0] + red[1] + red[2] + red[3] + 1.0f);
}

// ---------------- kernel 2: CSR of Ahat (ordered ballot compaction) --------
__global__ __launch_bounds__(64) void k_csr(const float* __restrict__ adj,
                                            const float* __restrict__ d,
                                            int* __restrict__ cnt,
                                            int* __restrict__ idx,
                                            float* __restrict__ val) {
    int m = blockIdx.x;
    int lane = threadIdx.x;
    const float* row = adj + (size_t)m * N;
    float dm = d[m];
    int base = 0;
    for (int c0 = 0; c0 < N; c0 += 64) {
        int c = c0 + lane;
        float a = 0.f;
        if (c < N) { a = row[c]; if (c == m) a += 1.0f; }
        bool pred = (a != 0.f);
        unsigned long long mask = __ballot(pred);
        int pos = base + __popcll(mask & ((1ull << lane) - 1ull));
        if (pred && pos < CAP) {
            idx[m * CAP + pos] = c;
            val[m * CAP + pos] = dm * d[c] * a;
        }
        base += (int)__popcll(mask);
    }
    if (lane == 0) cnt[m] = base < CAP ? base : CAP;
}

// ---------------- kernel 3: extract sids / sid_last / dss-premult feats ----
__global__ __launch_bounds__(256) void k_extract(const float* __restrict__ x,
                                                 const float* __restrict__ d,
                                                 int* __restrict__ sid,
                                                 int* __restrict__ sid_last,
                                                 float* __restrict__ fes) {
    int b = blockIdx.x, tid = threadIdx.x;
    const float* xb = x + (size_t)b * XROW;
    __shared__ float dss_sh[63];
    if (tid < S - 1) {
        int s_ = (int)xb[tid * 17 + 15];
        sid[b * (S - 1) + tid] = s_;
        dss_sh[tid] = d[s_];
    }
    if (tid == S - 1) sid_last[b] = (int)xb[(S - 1) * 17 + 15];
    __syncthreads();
    for (int i = tid; i < (S - 1) * 16; i += 256) {
        int t = i >> 4, f = i & 15;
        fes[(size_t)b * 1008 + i] = dss_sh[t] * xb[t * 17 + (f < 15 ? f : 16)];
    }
}

// ---------------- kernel 3b: pack W1^T MFMA fragments (bf16, K-pad to 32) --
__global__ __launch_bounds__(256) void k_wfrag(const float* __restrict__ w1,
                                               uint4* __restrict__ wf) {
    int e = blockIdx.x * 256 + threadIdx.x;       // 0..1023
    int ct = e >> 6, l = e & 63;
    int kg = l >> 4, ch = ct * 16 + (l & 15);
    ushort h[8];
#pragma unroll
    for (int j = 0; j < 8; ++j) {
        int f = kg * 8 + j;
        h[j] = (f < 16) ? bfb(w1[f * 256 + ch]) : (ushort)0;
    }
    uint4 r;
    r.x = h[0] | ((uint)h[1] << 16);
    r.y = h[2] | ((uint)h[3] << 16);
    r.z = h[4] | ((uint)h[5] << 16);
    r.w = h[6] | ((uint)h[7] << 16);
    wf[e] = r;
}

// ---------------- kernel 3c: pack W2 MFMA B-fragments (bf16) ---------------
__global__ __launch_bounds__(256) void k_w2frag(const float* __restrict__ w2,
                                                uint4* __restrict__ wf) {
    int e = blockIdx.x * 256 + threadIdx.x;       // 0..8191
    int l = e & 63;
    int kc = (e >> 6) & 7;
    int nt = e >> 9;
    int col = l & 15, kg = l >> 4;
    ushort h[8];
#pragma unroll
    for (int i = 0; i < 8; ++i) {
        int k = kc * 32 + kg * 8 + i;
        h[i] = bfb(w2[k * 256 + nt * 16 + col]);
    }
    uint4 r;
    r.x = h[0] | ((uint)h[1] << 16);
    r.y = h[2] | ((uint)h[3] << 16);
    r.z = h[4] | ((uint)h[5] << 16);
    r.w = h[6] | ((uint)h[7] << 16);
    wf[e] = r;
}

// ---------------- kernel 4: X1[b,p,:] = relu((Ahat X)[b,p] @ w1 + b1) ------
__global__ __launch_bounds__(256) void k_x1(const float* __restrict__ adj,
                                            const float* __restrict__ d,
                                            const int* __restrict__ sid,
                                            const float* __restrict__ fes,
                                            const uint4* __restrict__ wfrag,
                                            const float* __restrict__ b1,
                                            bf16* __restrict__ X1) {
    __shared__ ushort Ylds[64][32];
    __shared__ float b1s[256];
    int b = blockIdx.y, p0 = blockIdx.x * 64, tid = threadIdx.x;
    b1s[tid] = b1[tid];

    int pl = tid & 63;
    int fgu = __builtin_amdgcn_readfirstlane(tid >> 6);   // wave-uniform -> SGPR
    int f0 = fgu * 4;
    int p = p0 + pl;
    const float* fes_b = fes + (size_t)b * 1008 + f0;     // uniform base
    const int* sid_b = sid + b * 63;
    float a0 = 0.f, a1 = 0.f, a2 = 0.f, a3 = 0.f;
    if (p < N) {
        for (int t = 0; t < 63; ++t) {
            int s_ = sid_b[t];                             // uniform -> s_load
            float a = adj[(size_t)s_ * N + p];
            if (p == s_) a += 1.0f;
            const float* fr = fes_b + t * 16;              // uniform -> s_load
            a0 += a * fr[0]; a1 += a * fr[1];
            a2 += a * fr[2]; a3 += a * fr[3];
        }
    }
    float dp = (p < N) ? d[p] : 0.f;
    a0 *= dp; a1 *= dp; a2 *= dp; a3 *= dp;
    uint lo = bfb(a0) | ((uint)bfb(a1) << 16);
    uint hi = bfb(a2) | ((uint)bfb(a3) << 16);
    *(uint2*)&Ylds[pl][f0] = make_uint2(lo, hi);
    *(uint2*)&Ylds[pl][16 + f0] = make_uint2(0u, 0u);      // K-pad zeros
    __syncthreads();

    // ---- phase 2 ----
    int l = tid & 63, wv = tid >> 6;
    int lm = l & 15, lg = l >> 4;
    s8v yf = *(const s8v*)&Ylds[wv * 16 + lm][lg * 8];     // B = Y^T frag
    f4v acc[16];
#pragma unroll
    for (int ct = 0; ct < 16; ++ct) acc[ct] = (f4v){0.f, 0.f, 0.f, 0.f};
#pragma unroll
    for (int ct = 0; ct < 16; ++ct) {
        s8v wfv = *(const s8v*)&wfrag[ct * 64 + l];        // A = W^T frag
        acc[ct] = __builtin_amdgcn_mfma_f32_16x16x32_bf16(wfv, yf, acc[ct], 0, 0, 0);
    }
    int pp = p0 + wv * 16 + lm;
    if (pp < N) {
        uint2* dst = (uint2*)X1 + ((size_t)b * N + pp) * 64;
#pragma unroll
        for (int ct = 0; ct < 16; ++ct) {
            float4 bz = *(float4*)&b1s[ct * 16 + lg * 4];
            float v0 = acc[ct][0] + bz.x; v0 = v0 > 0.f ? v0 : 0.f;
            float v1 = acc[ct][1] + bz.y; v1 = v1 > 0.f ? v1 : 0.f;
            float v2 = acc[ct][2] + bz.z; v2 = v2 > 0.f ? v2 : 0.f;
            float v3 = acc[ct][3] + bz.w; v3 = v3 > 0.f ? v3 : 0.f;
            uint2 pk;
            pk.x = bfb(v0) | ((uint)bfb(v1) << 16);
            pk.y = bfb(v2) | ((uint)bfb(v3) << 16);
            dst[ct * 4 + lg] = pk;
        }
    }
}

// ---------------- kernel 5: X2 at one-hop(m_b), JT=16 neighbors per block --
// gather: each wave interleaves its 4 j-rows as 4 independent load chains
// (4-8 outstanding 512B loads/wave); tail: MFMA vs pre-packed w2 fragments
__global__ __launch_bounds__(256) void k_x2(const int* __restrict__ cnt,
                                            const int* __restrict__ idxA,
                                            const float* __restrict__ valA,
                                            const int* __restrict__ sid_last,
                                            const bf16* __restrict__ X1,
                                            const uint4* __restrict__ w2f,
                                            const float* __restrict__ b2,
                                            float* __restrict__ X2) {
    __shared__ int    nns[JT];
    __shared__ int    ncn_s[JT];
    __shared__ int    nidx[JT][CAP];
    __shared__ float  nval[JT][CAP];
    __shared__ ushort agg[JT][264];   // 528B row stride
    int b = blockIdx.y, j0 = blockIdx.x * JT, tid = threadIdx.x;
    int m = sid_last[b];
    int cj = cnt[m];
    if (j0 >= cj) return;
    int nj = cj - j0; if (nj > JT) nj = JT;
    if (tid < JT) {
        int n = idxA[m * CAP + j0 + (tid < nj ? tid : 0)];
        nns[tid] = n;
        ncn_s[tid] = (tid < nj) ? cnt[n] : 0;
    }
    __syncthreads();
    for (int i = tid; i < JT * CAP; i += 256) {
        int jj = i >> 7, k = i & (CAP - 1);
        int n = nns[jj];
        nidx[jj][k] = idxA[n * CAP + k];
        nval[jj][k] = valA[n * CAP + k];
    }
    __syncthreads();
    int lane = tid & 63;
    int w = __builtin_amdgcn_readfirstlane(tid >> 6);
    int jbase = w * 4;
    const uint2* X1bl = (const uint2*)X1 + (size_t)b * N * 64 + lane;

    float a0[4] = {0.f, 0.f, 0.f, 0.f};
    float a1[4] = {0.f, 0.f, 0.f, 0.f};
    float a2[4] = {0.f, 0.f, 0.f, 0.f};
    float a3[4] = {0.f, 0.f, 0.f, 0.f};
    int   cn[4];
    uint2 u[4];
    float v[4];
#pragma unroll
    for (int jj = 0; jj < 4; ++jj) {
        cn[jj] = ncn_s[jbase + jj];
        if (cn[jj] > 0) {
            int p = nidx[jbase + jj][0];
            v[jj] = nval[jbase + jj][0];
            u[jj] = X1bl[(size_t)p * 64];
        }
    }
    int cmax = cn[0];
    if (cn[1] > cmax) cmax = cn[1];
    if (cn[2] > cmax) cmax = cn[2];
    if (cn[3] > cmax) cmax = cn[3];
    for (int k = 0; k < cmax; ++k) {
        uint2 uc[4]; float vc[4];
#pragma unroll
        for (int jj = 0; jj < 4; ++jj) { uc[jj] = u[jj]; vc[jj] = v[jj]; }
#pragma unroll
        for (int jj = 0; jj < 4; ++jj) {          // issue next loads (4 chains)
            if (k + 1 < cn[jj]) {
                int p = nidx[jbase + jj][k + 1];
                v[jj] = nval[jbase + jj][k + 1];
                u[jj] = X1bl[(size_t)p * 64];
            }
        }
#pragma unroll
        for (int jj = 0; jj < 4; ++jj) {          // accumulate current
            if (k < cn[jj]) {
                float f0 = __uint_as_float(uc[jj].x << 16);
                float f1 = __uint_as_float(uc[jj].x & 0xffff0000u);
                float f2 = __uint_as_float(uc[jj].y << 16);
                float f3 = __uint_as_float(uc[jj].y & 0xffff0000u);
                a0[jj] += vc[jj] * f0; a1[jj] += vc[jj] * f1;
                a2[jj] += vc[jj] * f2; a3[jj] += vc[jj] * f3;
            }
        }
    }
#pragma unroll
    for (int jj = 0; jj < 4; ++jj) {
        uint2 pk;
        pk.x = bfb(a0[jj]) | ((uint)bfb(a1[jj]) << 16);
        pk.y = bfb(a2[jj]) | ((uint)bfb(a3[jj]) << 16);
        *(uint2*)&agg[jbase + jj][lane * 4] = pk;
    }
    __syncthreads();
    // MFMA tail: D[j, n] = agg[16 x 256] @ w2[256 x 256]
    int col = lane & 15, rg = lane >> 4;
    s8v af[8];
#pragma unroll
    for (int kc = 0; kc < 8; ++kc)
        af[kc] = *(const s8v*)&agg[col][kc * 32 + rg * 8];
#pragma unroll
    for (int t = 0; t < 4; ++t) {
        int nt = w * 4 + t;
        f4v acc = (f4v){0.f, 0.f, 0.f, 0.f};
#pragma unroll
        for (int kc = 0; kc < 8; ++kc) {
            s8v bf = *(const s8v*)&w2f[(nt * 8 + kc) * 64 + lane];
            acc = __builtin_amdgcn_mfma_f32_16x16x32_bf16(af[kc], bf, acc, 0, 0, 0);
        }
        float bv = b2[nt * 16 + col];
        float* dst = X2 + ((size_t)b * CAP + j0) * 256 + nt * 16 + col;
#pragma unroll
        for (int i = 0; i < 4; ++i) {
            int row = rg * 4 + i;
            if (row < nj) {
                float vv = acc[i] + bv;
                dst[(size_t)row * 256] = vv > 0.f ? vv : 0.f;
            }
        }
    }
}

// ---------------- kernel 6: g[b] = relu((Ahat X2)[b,m_b] @ w3 + b3) --------
__global__ __launch_bounds__(256) void k_g(const int* __restrict__ cnt,
                                           const int* __restrict__ idxA,
                                           const float* __restrict__ valA,
                                           const int* __restrict__ sid_last,
                                           const float* __restrict__ X2,
                                           const float* __restrict__ w3,
                                           const float* __restrict__ b3,
                                           float* __restrict__ g) {
    int b = blockIdx.x, tid = threadIdx.x;
    int m = sid_last[b];
    int cj = cnt[m];
    __shared__ float g1[256];
    float acc = 0.f;
    for (int jj = 0; jj < cj; ++jj)
        acc += valA[m * CAP + jj] * X2[((size_t)b * CAP + jj) * 256 + tid];
    g1[tid] = acc;
    __syncthreads();
    for (int oo = tid; oo < 512; oo += 256) {
        float a2 = b3[oo];
#pragma unroll 4
        for (int f = 0; f < 256; ++f) a2 += g1[f] * w3[f * 512 + oo];
        g[(size_t)b * 512 + oo] = a2 > 0.f ? a2 : 0.f;
    }
}

// ---------------- kernel 7: hp0 = x_last[:, :15] @ w0 + b0 -----------------
__global__ __launch_bounds__(256) void k_fc0(const float* __restrict__ x,
                                             const float* __restrict__ w0,
                                             const float* __restrict__ b0,
                                             float* __restrict__ hp0) {
    int i = blockIdx.x * 256 + threadIdx.x;
    int b = i >> 9, o = i & 511;
    const float* xr = x + (size_t)b * XROW + (S - 1) * 17;
    float acc = b0[o];
#pragma unroll
    for (int f = 0; f < 15; ++f) acc += xr[f] * w0[f * 512 + o];
    hp0[i] = acc;
}

// ---------------- kernel 8/10: batch-norm stats (biased var) ---------------
__global__ __launch_bounds__(256) void k_bnstats(const float* __restrict__ h,
                                                 float* __restrict__ mu,
                                                 float* __restrict__ rstd) {
    int o = blockIdx.x * 256 + threadIdx.x;
    float s = 0.f, s2 = 0.f;
    for (int b = 0; b < B; ++b) { float v = h[b * 512 + o]; s += v; s2 += v * v; }
    float m = s * (1.f / B);
    float var = s2 * (1.f / B) - m * m;
    mu[o] = m;
    rstd[o] = rsqrtf(var + 1e-5f);
}

// ---------------- kernel 9: hp1 = [leaky(bn(hp0)), g] @ w1 + b1 ------------
__global__ __launch_bounds__(256) void k_fc1(const float* __restrict__ hp0,
                                             const float* __restrict__ mu0,
                                             const float* __restrict__ rstd0,
                                             const float* __restrict__ gam,
                                             const float* __restrict__ bet,
                                             const float* __restrict__ gbuf,
                                             const float* __restrict__ w1,
                                             const float* __restrict__ b1,
                                             float* __restrict__ hp1) {
    int b = blockIdx.x, ot = blockIdx.y, tid = threadIdx.x;
    __shared__ float h[1024];
    for (int o = tid; o < 512; o += 256) {
        float v = hp0[b * 512 + o];
        v = gam[o] * (v - mu0[o]) * rstd0[o] + bet[o];
        h[o] = v >= 0.f ? v : 0.01f * v;
        h[512 + o] = gbuf[(size_t)b * 512 + o];
    }
    __syncthreads();
    int q  = tid & 31;
    int kg = tid >> 5;
    const float4* w4 = (const float4*)w1;
    int wq = ot * 32 + q;
    float4 acc = {0.f, 0.f, 0.f, 0.f};
    for (int k = kg * 128; k < kg * 128 + 128; ++k) {
        float hk = h[k];
        float4 w = w4[(size_t)k * 128 + wq];
        acc.x += hk * w.x; acc.y += hk * w.y; acc.z += hk * w.z; acc.w += hk * w.w;
    }
    __shared__ float4 red[8][32];
    red[kg][q] = acc;
    __syncthreads();
    if (tid < 32) {
        float4 s = red[0][tid];
#pragma unroll
        for (int gr = 1; gr < 8; ++gr) {
            float4 r = red[gr][tid];
            s.x += r.x; s.y += r.y; s.z += r.z; s.w += r.w;
        }
        int ob = ot * 128 + tid * 4;
        s.x += b1[ob]; s.y += b1[ob + 1]; s.z += b1[ob + 2]; s.w += b1[ob + 3];
        *(float4*)&hp1[b * 512 + ob] = s;
    }
}

// ---------------- kernel 11: out = sigmoid(leaky(bn(hp1)) @ w2 + b2) -------
__global__ __launch_bounds__(64) void k_out(const float* __restrict__ hp1,
                                            const float* __restrict__ mu1,
                                            const float* __restrict__ rstd1,
                                            const float* __restrict__ gam,
                                            const float* __restrict__ bet,
                                            const float* __restrict__ w2,
                                            const float* __restrict__ b2,
                                            float* __restrict__ out) {
    int b = blockIdx.x, lane = threadIdx.x;
    float acc = 0.f;
    for (int o = lane; o < 512; o += 64) {
        float v = hp1[b * 512 + o];
        v = gam[o] * (v - mu1[o]) * rstd1[o] + bet[o];
        v = v >= 0.f ? v : 0.01f * v;
        acc += v * w2[o];
    }
    for (int off = 32; off > 0; off >>= 1) acc += __shfl_down(acc, off);
    if (lane == 0) out[b] = 1.f / (1.f + expf(-(acc + b2[0])));
}

static inline size_t align256(size_t x) { return (x + 255) & ~(size_t)255; }

extern "C" void kernel_launch(void* const* d_in, const int* in_sizes, int n_in,
                              void* d_out, int out_size, void* d_ws, size_t ws_size,
                              hipStream_t stream) {
    const float* x     = (const float*)d_in[0];
    const float* adj   = (const float*)d_in[1];
    const float* w_gc1 = (const float*)d_in[2];
    const float* b_gc1 = (const float*)d_in[3];
    const float* w_gc2 = (const float*)d_in[4];
    const float* b_gc2 = (const float*)d_in[5];
    const float* w_gc3 = (const float*)d_in[6];
    const float* b_gc3 = (const float*)d_in[7];
    const float* w_fc0 = (const float*)d_in[8];
    const float* b_fc0 = (const float*)d_in[9];
    const float* g_fc0 = (const float*)d_in[10];
    const float* be_fc0= (const float*)d_in[11];
    const float* w_fc1 = (const float*)d_in[12];
    const float* b_fc1 = (const float*)d_in[13];
    const float* g_fc1 = (const float*)d_in[14];
    const float* be_fc1= (const float*)d_in[15];
    const float* w_fc2 = (const float*)d_in[16];
    const float* b_fc2 = (const float*)d_in[17];

    char* wsp = (char*)d_ws;
    size_t off = 0;
    auto alloc = [&](size_t bytes) { void* p = wsp + off; off = align256(off + bytes); return p; };
    float* d_deg   = (float*)alloc((size_t)N * 4);
    int*   sid     = (int*)  alloc((size_t)B * 63 * 4);
    int*   sidl    = (int*)  alloc((size_t)B * 4);
    float* fes     = (float*)alloc((size_t)B * 63 * 16 * 4);
    uint4* wfrag   = (uint4*)alloc((size_t)1024 * 16);
    uint4* w2frag  = (uint4*)alloc((size_t)8192 * 16);
    int*   csr_cnt = (int*)  alloc((size_t)N * 4);
    int*   csr_idx = (int*)  alloc((size_t)N * CAP * 4);
    float* csr_val = (float*)alloc((size_t)N * CAP * 4);
    bf16*  X1      = (bf16*) alloc((size_t)B * N * 256 * 2);
    float* X2      = (float*)alloc((size_t)B * CAP * 256 * 4);
    float* gbuf    = (float*)alloc((size_t)B * 512 * 4);
    float* hp0     = (float*)alloc((size_t)B * 512 * 4);
    float* mu0     = (float*)alloc(512 * 4);
    float* rstd0   = (float*)alloc(512 * 4);
    float* hp1     = (float*)alloc((size_t)B * 512 * 4);
    float* mu1     = (float*)alloc(512 * 4);
    float* rstd1   = (float*)alloc(512 * 4);

    k_rowsum <<<N, 256, 0, stream>>>(adj, d_deg);
    k_csr    <<<N, 64, 0, stream>>>(adj, d_deg, csr_cnt, csr_idx, csr_val);
    k_extract<<<B, 256, 0, stream>>>(x, d_deg, sid, sidl, fes);
    k_wfrag  <<<4, 256, 0, stream>>>(w_gc1, wfrag);
    k_w2frag <<<32, 256, 0, stream>>>(w_gc2, w2frag);
    k_x1     <<<dim3(32, B), 256, 0, stream>>>(adj, d_deg, sid, fes, wfrag, b_gc1, X1);
    k_x2     <<<dim3(CAP / JT, B), 256, 0, stream>>>(csr_cnt, csr_idx, csr_val, sidl, X1, w2frag, b_gc2, X2);
    k_g      <<<B, 256, 0, stream>>>(csr_cnt, csr_idx, csr_val, sidl, X2, w_gc3, b_gc3, gbuf);
    k_fc0    <<<(B * 512) / 256, 256, 0, stream>>>(x, w_fc0, b_fc0, hp0);
    k_bnstats<<<2, 256, 0, stream>>>(hp0, mu0, rstd0);
    k_fc1    <<<dim3(B, 4), 256, 0, stream>>>(hp0, mu0, rstd0, g_fc0, be_fc0, gbuf, w_fc1, b_fc1, hp1);
    k_bnstats<<<2, 256, 0, stream>>>(hp1, mu1, rstd1);
    k_out    <<<B, 64, 0, stream>>>(hp1, mu1, rstd1, g_fc1, be_fc1, w_fc2, b_fc2, (float*)d_out);
}

// Round 6
// 274.452 us; speedup vs baseline: 1.1411x; 1.0058x over previous
//
#include <hip/hip_runtime.h>
#include <hip/hip_bf16.h>

typedef __hip_bfloat16 bf16;
typedef short s8v __attribute__((ext_vector_type(8)));
typedef float f4v __attribute__((ext_vector_type(4)));

#define B   128
#define N   2000
#define S   64
#define CAP 128          // max neighbors per row (mean ~65, 8-sigma safe)
#define JT  16           // neighbors per block in k_x2
#define XROW 1088        // S*17

__device__ inline ushort bfb(float v) {
    union { __hip_bfloat16 h; ushort u; } c; c.h = __float2bfloat16(v); return c.u;
}

// ---------------- kernel 1: d[m] = rsqrt(sum(adj[m,:]) + 1) ----------------
__global__ __launch_bounds__(256) void k_rowsum(const float* __restrict__ adj,
                                                float* __restrict__ d) {
    int m = blockIdx.x;
    const float* row = adj + (size_t)m * N;
    float s = 0.f;
    for (int c = threadIdx.x; c < N; c += 256) s += row[c];
    for (int o = 32; o > 0; o >>= 1) s += __shfl_down(s, o);
    __shared__ float red[4];
    int wave = threadIdx.x >> 6;
    if ((threadIdx.x & 63) == 0) red[wave] = s;
    __syncthreads();
    if (threadIdx.x == 0)
        d[m] = rsqrtf(red[0] + red[1] + red[2] + red[3] + 1.0f);
}

// ---------------- kernel 2: CSR of Ahat (ordered ballot compaction) --------
__global__ __launch_bounds__(64) void k_csr(const float* __restrict__ adj,
                                            const float* __restrict__ d,
                                            int* __restrict__ cnt,
                                            int* __restrict__ idx,
                                            float* __restrict__ val) {
    int m = blockIdx.x;
    int lane = threadIdx.x;
    const float* row = adj + (size_t)m * N;
    float dm = d[m];
    int base = 0;
    for (int c0 = 0; c0 < N; c0 += 64) {
        int c = c0 + lane;
        float a = 0.f;
        if (c < N) { a = row[c]; if (c == m) a += 1.0f; }
        bool pred = (a != 0.f);
        unsigned long long mask = __ballot(pred);
        int pos = base + __popcll(mask & ((1ull << lane) - 1ull));
        if (pred && pos < CAP) {
            idx[m * CAP + pos] = c;
            val[m * CAP + pos] = dm * d[c] * a;
        }
        base += (int)__popcll(mask);
    }
    if (lane == 0) cnt[m] = base < CAP ? base : CAP;
}

// ---------------- kernel 3: extract sids / sid_last / dss-premult feats ----
__global__ __launch_bounds__(256) void k_extract(const float* __restrict__ x,
                                                 const float* __restrict__ d,
                                                 int* __restrict__ sid,
                                                 int* __restrict__ sid_last,
                                                 float* __restrict__ fes) {
    int b = blockIdx.x, tid = threadIdx.x;
    const float* xb = x + (size_t)b * XROW;
    __shared__ float dss_sh[63];
    if (tid < S - 1) {
        int s_ = (int)xb[tid * 17 + 15];
        sid[b * (S - 1) + tid] = s_;
        dss_sh[tid] = d[s_];
    }
    if (tid == S - 1) sid_last[b] = (int)xb[(S - 1) * 17 + 15];
    __syncthreads();
    for (int i = tid; i < (S - 1) * 16; i += 256) {
        int t = i >> 4, f = i & 15;
        fes[(size_t)b * 1008 + i] = dss_sh[t] * xb[t * 17 + (f < 15 ? f : 16)];
    }
}

// ---------------- kernel 3b: pack W1^T MFMA fragments (bf16, K-pad to 32) --
__global__ __launch_bounds__(256) void k_wfrag(const float* __restrict__ w1,
                                               uint4* __restrict__ wf) {
    int e = blockIdx.x * 256 + threadIdx.x;       // 0..1023
    int ct = e >> 6, l = e & 63;
    int kg = l >> 4, ch = ct * 16 + (l & 15);
    ushort h[8];
#pragma unroll
    for (int j = 0; j < 8; ++j) {
        int f = kg * 8 + j;
        h[j] = (f < 16) ? bfb(w1[f * 256 + ch]) : (ushort)0;
    }
    uint4 r;
    r.x = h[0] | ((uint)h[1] << 16);
    r.y = h[2] | ((uint)h[3] << 16);
    r.z = h[4] | ((uint)h[5] << 16);
    r.w = h[6] | ((uint)h[7] << 16);
    wf[e] = r;
}

// ---------------- kernel 3c: pack W2 MFMA B-fragments (bf16) ---------------
__global__ __launch_bounds__(256) void k_w2frag(const float* __restrict__ w2,
                                                uint4* __restrict__ wf) {
    int e = blockIdx.x * 256 + threadIdx.x;       // 0..8191
    int l = e & 63;
    int kc = (e >> 6) & 7;
    int nt = e >> 9;
    int col = l & 15, kg = l >> 4;
    ushort h[8];
#pragma unroll
    for (int i = 0; i < 8; ++i) {
        int k = kc * 32 + kg * 8 + i;
        h[i] = bfb(w2[k * 256 + nt * 16 + col]);
    }
    uint4 r;
    r.x = h[0] | ((uint)h[1] << 16);
    r.y = h[2] | ((uint)h[3] << 16);
    r.z = h[4] | ((uint)h[5] << 16);
    r.w = h[6] | ((uint)h[7] << 16);
    wf[e] = r;
}

// ---------------- kernel 4: X1[b,p,:] = relu((Ahat X)[b,p] @ w1 + b1) ------
// phase 1: LDS-resident fes/sv; t-loop = 1 pipelined adj load + broadcast
//          ds_read_b128 + 4 FMA per t. phase 2: MFMA (unchanged).
__global__ __launch_bounds__(256) void k_x1(const float* __restrict__ adj,
                                            const float* __restrict__ d,
                                            const int* __restrict__ sid,
                                            const float* __restrict__ fes,
                                            const uint4* __restrict__ wfrag,
                                            const float* __restrict__ b1,
                                            bf16* __restrict__ X1) {
    __shared__ __align__(16) float fe[63][16];
    __shared__ int sv[63];
    __shared__ __align__(16) ushort Ylds[64][40];   // 80B row: 16B-aligned, low conflict
    __shared__ float b1s[256];
    int b = blockIdx.y, p0 = blockIdx.x * 64, tid = threadIdx.x;
    b1s[tid] = b1[tid];
    {
        const float4* src = (const float4*)(fes + (size_t)b * 1008);
        float4* dst = (float4*)&fe[0][0];
        if (tid < 252) dst[tid] = src[tid];
        if (tid < 63) sv[tid] = sid[b * 63 + tid];
    }
    __syncthreads();

    int pl = tid & 63, fg = tid >> 6;
    int f0 = fg * 4;
    int p = p0 + pl;
    float a0 = 0.f, a1 = 0.f, a2 = 0.f, a3 = 0.f;
    if (p < N) {
        for (int t = 0; t < 63; ++t) {
            int s_ = __builtin_amdgcn_readfirstlane(sv[t]);   // SGPR row base
            float a = adj[(size_t)s_ * N + p];
            if (p == s_) a += 1.0f;
            float4 fr = *(const float4*)&fe[t][f0];            // broadcast b128
            a0 += a * fr.x; a1 += a * fr.y; a2 += a * fr.z; a3 += a * fr.w;
        }
        float dp = d[p];
        a0 *= dp; a1 *= dp; a2 *= dp; a3 *= dp;
    }
    uint lo = bfb(a0) | ((uint)bfb(a1) << 16);
    uint hi = bfb(a2) | ((uint)bfb(a3) << 16);
    *(uint2*)&Ylds[pl][f0] = make_uint2(lo, hi);
    *(uint2*)&Ylds[pl][16 + f0] = make_uint2(0u, 0u);          // K-pad zeros
    __syncthreads();

    // ---- phase 2 ----
    int l = tid & 63, wv = tid >> 6;
    int lm = l & 15, lg = l >> 4;
    s8v yf = *(const s8v*)&Ylds[wv * 16 + lm][lg * 8];         // B = Y^T frag
    f4v acc[16];
#pragma unroll
    for (int ct = 0; ct < 16; ++ct) acc[ct] = (f4v){0.f, 0.f, 0.f, 0.f};
#pragma unroll
    for (int ct = 0; ct < 16; ++ct) {
        s8v wfv = *(const s8v*)&wfrag[ct * 64 + l];            // A = W^T frag
        acc[ct] = __builtin_amdgcn_mfma_f32_16x16x32_bf16(wfv, yf, acc[ct], 0, 0, 0);
    }
    int pp = p0 + wv * 16 + lm;
    if (pp < N) {
        uint2* dst = (uint2*)X1 + ((size_t)b * N + pp) * 64;
#pragma unroll
        for (int ct = 0; ct < 16; ++ct) {
            float4 bz = *(float4*)&b1s[ct * 16 + lg * 4];
            float v0 = acc[ct][0] + bz.x; v0 = v0 > 0.f ? v0 : 0.f;
            float v1 = acc[ct][1] + bz.y; v1 = v1 > 0.f ? v1 : 0.f;
            float v2 = acc[ct][2] + bz.z; v2 = v2 > 0.f ? v2 : 0.f;
            float v3 = acc[ct][3] + bz.w; v3 = v3 > 0.f ? v3 : 0.f;
            uint2 pk;
            pk.x = bfb(v0) | ((uint)bfb(v1) << 16);
            pk.y = bfb(v2) | ((uint)bfb(v3) << 16);
            dst[ct * 4 + lg] = pk;
        }
    }
}

// ---------------- kernel 5: X2 at one-hop(m_b), JT=16 neighbors per block --
__global__ __launch_bounds__(256) void k_x2(const int* __restrict__ cnt,
                                            const int* __restrict__ idxA,
                                            const float* __restrict__ valA,
                                            const int* __restrict__ sid_last,
                                            const bf16* __restrict__ X1,
                                            const uint4* __restrict__ w2f,
                                            const float* __restrict__ b2,
                                            float* __restrict__ X2) {
    __shared__ int    nns[JT];
    __shared__ int    ncn_s[JT];
    __shared__ int    nidx[JT][CAP];
    __shared__ float  nval[JT][CAP];
    __shared__ ushort agg[JT][264];   // 528B row stride
    int b = blockIdx.y, j0 = blockIdx.x * JT, tid = threadIdx.x;
    int m = sid_last[b];
    int cj = cnt[m];
    if (j0 >= cj) return;
    int nj = cj - j0; if (nj > JT) nj = JT;
    if (tid < JT) {
        int n = idxA[m * CAP + j0 + (tid < nj ? tid : 0)];
        nns[tid] = n;
        ncn_s[tid] = (tid < nj) ? cnt[n] : 0;
    }
    __syncthreads();
    for (int i = tid; i < JT * CAP; i += 256) {
        int jj = i >> 7, k = i & (CAP - 1);
        int n = nns[jj];
        nidx[jj][k] = idxA[n * CAP + k];
        nval[jj][k] = valA[n * CAP + k];
    }
    __syncthreads();
    int lane = tid & 63;
    int w = __builtin_amdgcn_readfirstlane(tid >> 6);
    int jbase = w * 4;
    const uint2* X1bl = (const uint2*)X1 + (size_t)b * N * 64 + lane;

    float a0[4] = {0.f, 0.f, 0.f, 0.f};
    float a1[4] = {0.f, 0.f, 0.f, 0.f};
    float a2[4] = {0.f, 0.f, 0.f, 0.f};
    float a3[4] = {0.f, 0.f, 0.f, 0.f};
    int   cn[4];
    uint2 u[4];
    float v[4];
#pragma unroll
    for (int jj = 0; jj < 4; ++jj) {
        cn[jj] = ncn_s[jbase + jj];
        if (cn[jj] > 0) {
            int p = nidx[jbase + jj][0];
            v[jj] = nval[jbase + jj][0];
            u[jj] = X1bl[(size_t)p * 64];
        }
    }
    int cmax = cn[0];
    if (cn[1] > cmax) cmax = cn[1];
    if (cn[2] > cmax) cmax = cn[2];
    if (cn[3] > cmax) cmax = cn[3];
    for (int k = 0; k < cmax; ++k) {
        uint2 uc[4]; float vc[4];
#pragma unroll
        for (int jj = 0; jj < 4; ++jj) { uc[jj] = u[jj]; vc[jj] = v[jj]; }
#pragma unroll
        for (int jj = 0; jj < 4; ++jj) {          // issue next loads (4 chains)
            if (k + 1 < cn[jj]) {
                int p = nidx[jbase + jj][k + 1];
                v[jj] = nval[jbase + jj][k + 1];
                u[jj] = X1bl[(size_t)p * 64];
            }
        }
#pragma unroll
        for (int jj = 0; jj < 4; ++jj) {          // accumulate current
            if (k < cn[jj]) {
                float f0 = __uint_as_float(uc[jj].x << 16);
                float f1 = __uint_as_float(uc[jj].x & 0xffff0000u);
                float f2 = __uint_as_float(uc[jj].y << 16);
                float f3 = __uint_as_float(uc[jj].y & 0xffff0000u);
                a0[jj] += vc[jj] * f0; a1[jj] += vc[jj] * f1;
                a2[jj] += vc[jj] * f2; a3[jj] += vc[jj] * f3;
            }
        }
    }
#pragma unroll
    for (int jj = 0; jj < 4; ++jj) {
        uint2 pk;
        pk.x = bfb(a0[jj]) | ((uint)bfb(a1[jj]) << 16);
        pk.y = bfb(a2[jj]) | ((uint)bfb(a3[jj]) << 16);
        *(uint2*)&agg[jbase + jj][lane * 4] = pk;
    }
    __syncthreads();
    // MFMA tail: D[j, n] = agg[16 x 256] @ w2[256 x 256]
    int col = lane & 15, rg = lane >> 4;
    s8v af[8];
#pragma unroll
    for (int kc = 0; kc < 8; ++kc)
        af[kc] = *(const s8v*)&agg[col][kc * 32 + rg * 8];
#pragma unroll
    for (int t = 0; t < 4; ++t) {
        int nt = w * 4 + t;
        f4v acc = (f4v){0.f, 0.f, 0.f, 0.f};
#pragma unroll
        for (int kc = 0; kc < 8; ++kc) {
            s8v bf = *(const s8v*)&w2f[(nt * 8 + kc) * 64 + lane];
            acc = __builtin_amdgcn_mfma_f32_16x16x32_bf16(af[kc], bf, acc, 0, 0, 0);
        }
        float bv = b2[nt * 16 + col];
        float* dst = X2 + ((size_t)b * CAP + j0) * 256 + nt * 16 + col;
#pragma unroll
        for (int i = 0; i < 4; ++i) {
            int row = rg * 4 + i;
            if (row < nj) {
                float vv = acc[i] + bv;
                dst[(size_t)row * 256] = vv > 0.f ? vv : 0.f;
            }
        }
    }
}

// ---------------- kernel 6: g[b] = relu((Ahat X2)[b,m_b] @ w3 + b3) --------
__global__ __launch_bounds__(256) void k_g(const int* __restrict__ cnt,
                                           const int* __restrict__ idxA,
                                           const float* __restrict__ valA,
                                           const int* __restrict__ sid_last,
                                           const float* __restrict__ X2,
                                           const float* __restrict__ w3,
                                           const float* __restrict__ b3,
                                           float* __restrict__ g) {
    int b = blockIdx.x, tid = threadIdx.x;
    int m = sid_last[b];
    int cj = cnt[m];
    __shared__ float g1[256];
    float acc = 0.f;
    for (int jj = 0; jj < cj; ++jj)
        acc += valA[m * CAP + jj] * X2[((size_t)b * CAP + jj) * 256 + tid];
    g1[tid] = acc;
    __syncthreads();
    for (int oo = tid; oo < 512; oo += 256) {
        float a2 = b3[oo];
#pragma unroll 4
        for (int f = 0; f < 256; ++f) a2 += g1[f] * w3[f * 512 + oo];
        g[(size_t)b * 512 + oo] = a2 > 0.f ? a2 : 0.f;
    }
}

// ---------------- kernel 7: hp0 = x_last[:, :15] @ w0 + b0 -----------------
__global__ __launch_bounds__(256) void k_fc0(const float* __restrict__ x,
                                             const float* __restrict__ w0,
                                             const float* __restrict__ b0,
                                             float* __restrict__ hp0) {
    int i = blockIdx.x * 256 + threadIdx.x;
    int b = i >> 9, o = i & 511;
    const float* xr = x + (size_t)b * XROW + (S - 1) * 17;
    float acc = b0[o];
#pragma unroll
    for (int f = 0; f < 15; ++f) acc += xr[f] * w0[f * 512 + o];
    hp0[i] = acc;
}

// ---------------- kernel 8/10: batch-norm stats (biased var) ---------------
__global__ __launch_bounds__(256) void k_bnstats(const float* __restrict__ h,
                                                 float* __restrict__ mu,
                                                 float* __restrict__ rstd) {
    int o = blockIdx.x * 256 + threadIdx.x;
    float s = 0.f, s2 = 0.f;
    for (int b = 0; b < B; ++b) { float v = h[b * 512 + o]; s += v; s2 += v * v; }
    float m = s * (1.f / B);
    float var = s2 * (1.f / B) - m * m;
    mu[o] = m;
    rstd[o] = rsqrtf(var + 1e-5f);
}

// ---------------- kernel 9: hp1 = [leaky(bn(hp0)), g] @ w1 + b1 ------------
__global__ __launch_bounds__(256) void k_fc1(const float* __restrict__ hp0,
                                             const float* __restrict__ mu0,
                                             const float* __restrict__ rstd0,
                                             const float* __restrict__ gam,
                                             const float* __restrict__ bet,
                                             const float* __restrict__ gbuf,
                                             const float* __restrict__ w1,
                                             const float* __restrict__ b1,
                                             float* __restrict__ hp1) {
    int b = blockIdx.x, ot = blockIdx.y, tid = threadIdx.x;
    __shared__ float h[1024];
    for (int o = tid; o < 512; o += 256) {
        float v = hp0[b * 512 + o];
        v = gam[o] * (v - mu0[o]) * rstd0[o] + bet[o];
        h[o] = v >= 0.f ? v : 0.01f * v;
        h[512 + o] = gbuf[(size_t)b * 512 + o];
    }
    __syncthreads();
    int q  = tid & 31;
    int kg = tid >> 5;
    const float4* w4 = (const float4*)w1;
    int wq = ot * 32 + q;
    float4 acc = {0.f, 0.f, 0.f, 0.f};
    for (int k = kg * 128; k < kg * 128 + 128; ++k) {
        float hk = h[k];
        float4 w = w4[(size_t)k * 128 + wq];
        acc.x += hk * w.x; acc.y += hk * w.y; acc.z += hk * w.z; acc.w += hk * w.w;
    }
    __shared__ float4 red[8][32];
    red[kg][q] = acc;
    __syncthreads();
    if (tid < 32) {
        float4 s = red[0][tid];
#pragma unroll
        for (int gr = 1; gr < 8; ++gr) {
            float4 r = red[gr][tid];
            s.x += r.x; s.y += r.y; s.z += r.z; s.w += r.w;
        }
        int ob = ot * 128 + tid * 4;
        s.x += b1[ob]; s.y += b1[ob + 1]; s.z += b1[ob + 2]; s.w += b1[ob + 3];
        *(float4*)&hp1[b * 512 + ob] = s;
    }
}

// ---------------- kernel 11: out = sigmoid(leaky(bn(hp1)) @ w2 + b2) -------
__global__ __launch_bounds__(64) void k_out(const float* __restrict__ hp1,
                                            const float* __restrict__ mu1,
                                            const float* __restrict__ rstd1,
                                            const float* __restrict__ gam,
                                            const float* __restrict__ bet,
                                            const float* __restrict__ w2,
                                            const float* __restrict__ b2,
                                            float* __restrict__ out) {
    int b = blockIdx.x, lane = threadIdx.x;
    float acc = 0.f;
    for (int o = lane; o < 512; o += 64) {
        float v = hp1[b * 512 + o];
        v = gam[o] * (v - mu1[o]) * rstd1[o] + bet[o];
        v = v >= 0.f ? v : 0.01f * v;
        acc += v * w2[o];
    }
    for (int off = 32; off > 0; off >>= 1) acc += __shfl_down(acc, off);
    if (lane == 0) out[b] = 1.f / (1.f + expf(-(acc + b2[0])));
}

static inline size_t align256(size_t x) { return (x + 255) & ~(size_t)255; }

extern "C" void kernel_launch(void* const* d_in, const int* in_sizes, int n_in,
                              void* d_out, int out_size, void* d_ws, size_t ws_size,
                              hipStream_t stream) {
    const float* x     = (const float*)d_in[0];
    const float* adj   = (const float*)d_in[1];
    const float* w_gc1 = (const float*)d_in[2];
    const float* b_gc1 = (const float*)d_in[3];
    const float* w_gc2 = (const float*)d_in[4];
    const float* b_gc2 = (const float*)d_in[5];
    const float* w_gc3 = (const float*)d_in[6];
    const float* b_gc3 = (const float*)d_in[7];
    const float* w_fc0 = (const float*)d_in[8];
    const float* b_fc0 = (const float*)d_in[9];
    const float* g_fc0 = (const float*)d_in[10];
    const float* be_fc0= (const float*)d_in[11];
    const float* w_fc1 = (const float*)d_in[12];
    const float* b_fc1 = (const float*)d_in[13];
    const float* g_fc1 = (const float*)d_in[14];
    const float* be_fc1= (const float*)d_in[15];
    const float* w_fc2 = (const float*)d_in[16];
    const float* b_fc2 = (const float*)d_in[17];

    char* wsp = (char*)d_ws;
    size_t off = 0;
    auto alloc = [&](size_t bytes) { void* p = wsp + off; off = align256(off + bytes); return p; };
    float* d_deg   = (float*)alloc((size_t)N * 4);
    int*   sid     = (int*)  alloc((size_t)B * 63 * 4);
    int*   sidl    = (int*)  alloc((size_t)B * 4);
    float* fes     = (float*)alloc((size_t)B * 63 * 16 * 4);
    uint4* wfrag   = (uint4*)alloc((size_t)1024 * 16);
    uint4* w2frag  = (uint4*)alloc((size_t)8192 * 16);
    int*   csr_cnt = (int*)  alloc((size_t)N * 4);
    int*   csr_idx = (int*)  alloc((size_t)N * CAP * 4);
    float* csr_val = (float*)alloc((size_t)N * CAP * 4);
    bf16*  X1      = (bf16*) alloc((size_t)B * N * 256 * 2);
    float* X2      = (float*)alloc((size_t)B * CAP * 256 * 4);
    float* gbuf    = (float*)alloc((size_t)B * 512 * 4);
    float* hp0     = (float*)alloc((size_t)B * 512 * 4);
    float* mu0     = (float*)alloc(512 * 4);
    float* rstd0   = (float*)alloc(512 * 4);
    float* hp1     = (float*)alloc((size_t)B * 512 * 4);
    float* mu1     = (float*)alloc(512 * 4);
    float* rstd1   = (float*)alloc(512 * 4);

    k_rowsum <<<N, 256, 0, stream>>>(adj, d_deg);
    k_csr    <<<N, 64, 0, stream>>>(adj, d_deg, csr_cnt, csr_idx, csr_val);
    k_extract<<<B, 256, 0, stream>>>(x, d_deg, sid, sidl, fes);
    k_wfrag  <<<4, 256, 0, stream>>>(w_gc1, wfrag);
    k_w2frag <<<32, 256, 0, stream>>>(w_gc2, w2frag);
    k_x1     <<<dim3(32, B), 256, 0, stream>>>(adj, d_deg, sid, fes, wfrag, b_gc1, X1);
    k_x2     <<<dim3(CAP / JT, B), 256, 0, stream>>>(csr_cnt, csr_idx, csr_val, sidl, X1, w2frag, b_gc2, X2);
    k_g      <<<B, 256, 0, stream>>>(csr_cnt, csr_idx, csr_val, sidl, X2, w_gc3, b_gc3, gbuf);
    k_fc0    <<<(B * 512) / 256, 256, 0, stream>>>(x, w_fc0, b_fc0, hp0);
    k_bnstats<<<2, 256, 0, stream>>>(hp0, mu0, rstd0);
    k_fc1    <<<dim3(B, 4), 256, 0, stream>>>(hp0, mu0, rstd0, g_fc0, be_fc0, gbuf, w_fc1, b_fc1, hp1);
    k_bnstats<<<2, 256, 0, stream>>>(hp1, mu1, rstd1);
    k_out    <<<B, 64, 0, stream>>>(hp1, mu1, rstd1, g_fc1, be_fc1, w_fc2, b_fc2, (float*)d_out);
}

// Round 7
// 267.201 us; speedup vs baseline: 1.1721x; 1.0271x over previous
//
#include <hip/hip_runtime.h>
#include <hip/hip_bf16.h>

typedef __hip_bfloat16 bf16;
typedef short s8v __attribute__((ext_vector_type(8)));
typedef float f4v __attribute__((ext_vector_type(4)));

#define B   128
#define N   2000
#define S   64
#define CAP 128          // max neighbors per row (mean ~65, 8-sigma safe)
#define JT  16           // neighbors per block in k_x2
#define XROW 1088        // S*17

__device__ inline ushort bfb(float v) {
    union { __hip_bfloat16 h; ushort u; } c; c.h = __float2bfloat16(v); return c.u;
}

// ---------------- kernel 1: d[m] = rsqrt(sum(adj[m,:]) + 1) ----------------
__global__ __launch_bounds__(256) void k_rowsum(const float* __restrict__ adj,
                                                float* __restrict__ d) {
    int m = blockIdx.x;
    const float* row = adj + (size_t)m * N;
    float s = 0.f;
    for (int c = threadIdx.x; c < N; c += 256) s += row[c];
    for (int o = 32; o > 0; o >>= 1) s += __shfl_down(s, o);
    __shared__ float red[4];
    int wave = threadIdx.x >> 6;
    if ((threadIdx.x & 63) == 0) red[wave] = s;
    __syncthreads();
    if (threadIdx.x == 0)
        d[m] = rsqrtf(red[0] + red[1] + red[2] + red[3] + 1.0f);
}

// ---------------- kernel 2: CSR of Ahat (ordered ballot compaction) --------
__global__ __launch_bounds__(64) void k_csr(const float* __restrict__ adj,
                                            const float* __restrict__ d,
                                            int* __restrict__ cnt,
                                            int* __restrict__ idx,
                                            float* __restrict__ val) {
    int m = blockIdx.x;
    int lane = threadIdx.x;
    const float* row = adj + (size_t)m * N;
    float dm = d[m];
    int base = 0;
    for (int c0 = 0; c0 < N; c0 += 64) {
        int c = c0 + lane;
        float a = 0.f;
        if (c < N) { a = row[c]; if (c == m) a += 1.0f; }
        bool pred = (a != 0.f);
        unsigned long long mask = __ballot(pred);
        int pos = base + __popcll(mask & ((1ull << lane) - 1ull));
        if (pred && pos < CAP) {
            idx[m * CAP + pos] = c;
            val[m * CAP + pos] = dm * d[c] * a;
        }
        base += (int)__popcll(mask);
    }
    if (lane == 0) cnt[m] = base < CAP ? base : CAP;
}

// ---------------- kernel 3: extract sids / sid_last / dss-premult feats ----
__global__ __launch_bounds__(256) void k_extract(const float* __restrict__ x,
                                                 const float* __restrict__ d,
                                                 int* __restrict__ sid,
                                                 int* __restrict__ sid_last,
                                                 float* __restrict__ fes) {
    int b = blockIdx.x, tid = threadIdx.x;
    const float* xb = x + (size_t)b * XROW;
    __shared__ float dss_sh[63];
    if (tid < S - 1) {
        int s_ = (int)xb[tid * 17 + 15];
        sid[b * (S - 1) + tid] = s_;
        dss_sh[tid] = d[s_];
    }
    if (tid == S - 1) sid_last[b] = (int)xb[(S - 1) * 17 + 15];
    __syncthreads();
    for (int i = tid; i < (S - 1) * 16; i += 256) {
        int t = i >> 4, f = i & 15;
        fes[(size_t)b * 1008 + i] = dss_sh[t] * xb[t * 17 + (f < 15 ? f : 16)];
    }
}

// ---------------- kernel 3b: pack W1^T MFMA fragments (bf16, K-pad to 32) --
__global__ __launch_bounds__(256) void k_wfrag(const float* __restrict__ w1,
                                               uint4* __restrict__ wf) {
    int e = blockIdx.x * 256 + threadIdx.x;       // 0..1023
    int ct = e >> 6, l = e & 63;
    int kg = l >> 4, ch = ct * 16 + (l & 15);
    ushort h[8];
#pragma unroll
    for (int j = 0; j < 8; ++j) {
        int f = kg * 8 + j;
        h[j] = (f < 16) ? bfb(w1[f * 256 + ch]) : (ushort)0;
    }
    uint4 r;
    r.x = h[0] | ((uint)h[1] << 16);
    r.y = h[2] | ((uint)h[3] << 16);
    r.z = h[4] | ((uint)h[5] << 16);
    r.w = h[6] | ((uint)h[7] << 16);
    wf[e] = r;
}

// ---------------- kernel 3c: pack W2 MFMA B-fragments (bf16) ---------------
__global__ __launch_bounds__(256) void k_w2frag(const float* __restrict__ w2,
                                                uint4* __restrict__ wf) {
    int e = blockIdx.x * 256 + threadIdx.x;       // 0..8191
    int l = e & 63;
    int kc = (e >> 6) & 7;
    int nt = e >> 9;
    int col = l & 15, kg = l >> 4;
    ushort h[8];
#pragma unroll
    for (int i = 0; i < 8; ++i) {
        int k = kc * 32 + kg * 8 + i;
        h[i] = bfb(w2[k * 256 + nt * 16 + col]);
    }
    uint4 r;
    r.x = h[0] | ((uint)h[1] << 16);
    r.y = h[2] | ((uint)h[3] << 16);
    r.z = h[4] | ((uint)h[5] << 16);
    r.w = h[6] | ((uint)h[7] << 16);
    wf[e] = r;
}

// ---------------- kernel 4: X1[b,p,:] = relu((Ahat X)[b,p] @ w1 + b1) ------
// phase 1: t-loop SPLIT ACROSS WAVES (wave w: t = w, w+4, ...), each thread
//   accumulates all 16 channels; 16 gather loads issued as one batch (deep
//   MLP); partials reduced via LDS. phase 2: MFMA (verified, unchanged).
__global__ __launch_bounds__(256) void k_x1(const float* __restrict__ adj,
                                            const float* __restrict__ d,
                                            const int* __restrict__ sid,
                                            const float* __restrict__ fes,
                                            const uint4* __restrict__ wfrag,
                                            const float* __restrict__ b1,
                                            bf16* __restrict__ X1) {
    __shared__ __align__(16) float fe[63][16];          // 4032 B
    __shared__ int sv[64];
    __shared__ __align__(16) float Ypart[4][64][20];    // pad 20: b128 conflict-free
    __shared__ __align__(16) ushort Ylds[64][40];       // 80B row, 16B-aligned
    __shared__ float b1s[256];
    int b = blockIdx.y, p0 = blockIdx.x * 64, tid = threadIdx.x;
    b1s[tid] = b1[tid];
    {
        const float4* src = (const float4*)(fes + (size_t)b * 1008);
        if (tid < 252) ((float4*)&fe[0][0])[tid] = src[tid];
        if (tid < 63) sv[tid] = sid[b * 63 + tid];
    }
    __syncthreads();

    int pl = tid & 63;
    int w  = __builtin_amdgcn_readfirstlane(tid >> 6);
    int p  = p0 + pl;
    bool pv = (p < N);

    // ---- batch-issue this wave's <=16 gather loads (independent chains) ----
    float av[16];
#pragma unroll
    for (int i = 0; i < 16; ++i) {
        int t = w + 4 * i;
        float a = 0.f;
        if (t < 63) {
            int s_ = __builtin_amdgcn_readfirstlane(sv[t]);
            if (pv) a = adj[(size_t)s_ * N + p];
            if (p == s_) a += 1.0f;
        }
        av[i] = a;
    }
    // ---- accumulate 16 channels ----
    float acc[16];
#pragma unroll
    for (int f = 0; f < 16; ++f) acc[f] = 0.f;
#pragma unroll
    for (int i = 0; i < 16; ++i) {
        int t = w + 4 * i;
        if (t < 63) {
            float a = av[i];
            float4 f0 = *(const float4*)&fe[t][0];
            float4 f1 = *(const float4*)&fe[t][4];
            float4 f2 = *(const float4*)&fe[t][8];
            float4 f3 = *(const float4*)&fe[t][12];
            acc[0]  += a * f0.x; acc[1]  += a * f0.y; acc[2]  += a * f0.z; acc[3]  += a * f0.w;
            acc[4]  += a * f1.x; acc[5]  += a * f1.y; acc[6]  += a * f1.z; acc[7]  += a * f1.w;
            acc[8]  += a * f2.x; acc[9]  += a * f2.y; acc[10] += a * f2.z; acc[11] += a * f2.w;
            acc[12] += a * f3.x; acc[13] += a * f3.y; acc[14] += a * f3.z; acc[15] += a * f3.w;
        }
    }
#pragma unroll
    for (int f = 0; f < 16; f += 4)
        *(float4*)&Ypart[w][pl][f] = make_float4(acc[f], acc[f+1], acc[f+2], acc[f+3]);
    __syncthreads();

    // ---- reduce partials, scale by d[p], pack bf16 into Ylds ----
    {
        int fg = tid >> 6;           // channel group (0..3)
        int f0 = fg * 4;
        float4 s0 = *(const float4*)&Ypart[0][pl][f0];
        float4 s1 = *(const float4*)&Ypart[1][pl][f0];
        float4 s2 = *(const float4*)&Ypart[2][pl][f0];
        float4 s3 = *(const float4*)&Ypart[3][pl][f0];
        float dp = pv ? d[p] : 0.f;
        float r0 = (s0.x + s1.x + s2.x + s3.x) * dp;
        float r1 = (s0.y + s1.y + s2.y + s3.y) * dp;
        float r2 = (s0.z + s1.z + s2.z + s3.z) * dp;
        float r3 = (s0.w + s1.w + s2.w + s3.w) * dp;
        uint lo = bfb(r0) | ((uint)bfb(r1) << 16);
        uint hi = bfb(r2) | ((uint)bfb(r3) << 16);
        *(uint2*)&Ylds[pl][f0] = make_uint2(lo, hi);
        *(uint2*)&Ylds[pl][16 + f0] = make_uint2(0u, 0u);   // K-pad zeros
    }
    __syncthreads();

    // ---- phase 2: MFMA ----
    int l = tid & 63, wv = tid >> 6;
    int lm = l & 15, lg = l >> 4;
    s8v yf = *(const s8v*)&Ylds[wv * 16 + lm][lg * 8];      // B = Y^T frag
    f4v acc2[16];
#pragma unroll
    for (int ct = 0; ct < 16; ++ct) acc2[ct] = (f4v){0.f, 0.f, 0.f, 0.f};
#pragma unroll
    for (int ct = 0; ct < 16; ++ct) {
        s8v wfv = *(const s8v*)&wfrag[ct * 64 + l];         // A = W^T frag
        acc2[ct] = __builtin_amdgcn_mfma_f32_16x16x32_bf16(wfv, yf, acc2[ct], 0, 0, 0);
    }
    int pp = p0 + wv * 16 + lm;
    if (pp < N) {
        uint2* dst = (uint2*)X1 + ((size_t)b * N + pp) * 64;
#pragma unroll
        for (int ct = 0; ct < 16; ++ct) {
            float4 bz = *(float4*)&b1s[ct * 16 + lg * 4];
            float v0 = acc2[ct][0] + bz.x; v0 = v0 > 0.f ? v0 : 0.f;
            float v1 = acc2[ct][1] + bz.y; v1 = v1 > 0.f ? v1 : 0.f;
            float v2 = acc2[ct][2] + bz.z; v2 = v2 > 0.f ? v2 : 0.f;
            float v3 = acc2[ct][3] + bz.w; v3 = v3 > 0.f ? v3 : 0.f;
            uint2 pk;
            pk.x = bfb(v0) | ((uint)bfb(v1) << 16);
            pk.y = bfb(v2) | ((uint)bfb(v3) << 16);
            dst[ct * 4 + lg] = pk;
        }
    }
}

// ---------------- kernel 5: X2 at one-hop(m_b), JT=16 neighbors per block --
__global__ __launch_bounds__(256) void k_x2(const int* __restrict__ cnt,
                                            const int* __restrict__ idxA,
                                            const float* __restrict__ valA,
                                            const int* __restrict__ sid_last,
                                            const bf16* __restrict__ X1,
                                            const uint4* __restrict__ w2f,
                                            const float* __restrict__ b2,
                                            float* __restrict__ X2) {
    __shared__ int    nns[JT];
    __shared__ int    ncn_s[JT];
    __shared__ int    nidx[JT][CAP];
    __shared__ float  nval[JT][CAP];
    __shared__ ushort agg[JT][264];   // 528B row stride
    int b = blockIdx.y, j0 = blockIdx.x * JT, tid = threadIdx.x;
    int m = sid_last[b];
    int cj = cnt[m];
    if (j0 >= cj) return;
    int nj = cj - j0; if (nj > JT) nj = JT;
    if (tid < JT) {
        int n = idxA[m * CAP + j0 + (tid < nj ? tid : 0)];
        nns[tid] = n;
        ncn_s[tid] = (tid < nj) ? cnt[n] : 0;
    }
    __syncthreads();
    for (int i = tid; i < JT * CAP; i += 256) {
        int jj = i >> 7, k = i & (CAP - 1);
        int n = nns[jj];
        nidx[jj][k] = idxA[n * CAP + k];
        nval[jj][k] = valA[n * CAP + k];
    }
    __syncthreads();
    int lane = tid & 63;
    int w = __builtin_amdgcn_readfirstlane(tid >> 6);
    int jbase = w * 4;
    const uint2* X1bl = (const uint2*)X1 + (size_t)b * N * 64 + lane;

    float a0[4] = {0.f, 0.f, 0.f, 0.f};
    float a1[4] = {0.f, 0.f, 0.f, 0.f};
    float a2[4] = {0.f, 0.f, 0.f, 0.f};
    float a3[4] = {0.f, 0.f, 0.f, 0.f};
    int   cn[4];
    uint2 u[4];
    float v[4];
#pragma unroll
    for (int jj = 0; jj < 4; ++jj) {
        cn[jj] = ncn_s[jbase + jj];
        if (cn[jj] > 0) {
            int p = nidx[jbase + jj][0];
            v[jj] = nval[jbase + jj][0];
            u[jj] = X1bl[(size_t)p * 64];
        }
    }
    int cmax = cn[0];
    if (cn[1] > cmax) cmax = cn[1];
    if (cn[2] > cmax) cmax = cn[2];
    if (cn[3] > cmax) cmax = cn[3];
    for (int k = 0; k < cmax; ++k) {
        uint2 uc[4]; float vc[4];
#pragma unroll
        for (int jj = 0; jj < 4; ++jj) { uc[jj] = u[jj]; vc[jj] = v[jj]; }
#pragma unroll
        for (int jj = 0; jj < 4; ++jj) {          // issue next loads (4 chains)
            if (k + 1 < cn[jj]) {
                int p = nidx[jbase + jj][k + 1];
                v[jj] = nval[jbase + jj][k + 1];
                u[jj] = X1bl[(size_t)p * 64];
            }
        }
#pragma unroll
        for (int jj = 0; jj < 4; ++jj) {          // accumulate current
            if (k < cn[jj]) {
                float f0 = __uint_as_float(uc[jj].x << 16);
                float f1 = __uint_as_float(uc[jj].x & 0xffff0000u);
                float f2 = __uint_as_float(uc[jj].y << 16);
                float f3 = __uint_as_float(uc[jj].y & 0xffff0000u);
                a0[jj] += vc[jj] * f0; a1[jj] += vc[jj] * f1;
                a2[jj] += vc[jj] * f2; a3[jj] += vc[jj] * f3;
            }
        }
    }
#pragma unroll
    for (int jj = 0; jj < 4; ++jj) {
        uint2 pk;
        pk.x = bfb(a0[jj]) | ((uint)bfb(a1[jj]) << 16);
        pk.y = bfb(a2[jj]) | ((uint)bfb(a3[jj]) << 16);
        *(uint2*)&agg[jbase + jj][lane * 4] = pk;
    }
    __syncthreads();
    // MFMA tail: D[j, n] = agg[16 x 256] @ w2[256 x 256]
    int col = lane & 15, rg = lane >> 4;
    s8v af[8];
#pragma unroll
    for (int kc = 0; kc < 8; ++kc)
        af[kc] = *(const s8v*)&agg[col][kc * 32 + rg * 8];
#pragma unroll
    for (int t = 0; t < 4; ++t) {
        int nt = w * 4 + t;
        f4v acc = (f4v){0.f, 0.f, 0.f, 0.f};
#pragma unroll
        for (int kc = 0; kc < 8; ++kc) {
            s8v bf = *(const s8v*)&w2f[(nt * 8 + kc) * 64 + lane];
            acc = __builtin_amdgcn_mfma_f32_16x16x32_bf16(af[kc], bf, acc, 0, 0, 0);
        }
        float bv = b2[nt * 16 + col];
        float* dst = X2 + ((size_t)b * CAP + j0) * 256 + nt * 16 + col;
#pragma unroll
        for (int i = 0; i < 4; ++i) {
            int row = rg * 4 + i;
            if (row < nj) {
                float vv = acc[i] + bv;
                dst[(size_t)row * 256] = vv > 0.f ? vv : 0.f;
            }
        }
    }
}

// ---------------- kernel 6: g[b] = relu((Ahat X2)[b,m_b] @ w3 + b3) --------
__global__ __launch_bounds__(256) void k_g(const int* __restrict__ cnt,
                                           const int* __restrict__ idxA,
                                           const float* __restrict__ valA,
                                           const int* __restrict__ sid_last,
                                           const float* __restrict__ X2,
                                           const float* __restrict__ w3,
                                           const float* __restrict__ b3,
                                           float* __restrict__ g) {
    int b = blockIdx.x, tid = threadIdx.x;
    int m = sid_last[b];
    int cj = cnt[m];
    __shared__ float g1[256];
    float acc = 0.f;
    for (int jj = 0; jj < cj; ++jj)
        acc += valA[m * CAP + jj] * X2[((size_t)b * CAP + jj) * 256 + tid];
    g1[tid] = acc;
    __syncthreads();
    for (int oo = tid; oo < 512; oo += 256) {
        float a2 = b3[oo];
#pragma unroll 4
        for (int f = 0; f < 256; ++f) a2 += g1[f] * w3[f * 512 + oo];
        g[(size_t)b * 512 + oo] = a2 > 0.f ? a2 : 0.f;
    }
}

// ---------------- kernel 7: hp0 = x_last[:, :15] @ w0 + b0 -----------------
__global__ __launch_bounds__(256) void k_fc0(const float* __restrict__ x,
                                             const float* __restrict__ w0,
                                             const float* __restrict__ b0,
                                             float* __restrict__ hp0) {
    int i = blockIdx.x * 256 + threadIdx.x;
    int b = i >> 9, o = i & 511;
    const float* xr = x + (size_t)b * XROW + (S - 1) * 17;
    float acc = b0[o];
#pragma unroll
    for (int f = 0; f < 15; ++f) acc += xr[f] * w0[f * 512 + o];
    hp0[i] = acc;
}

// ---------------- kernel 8/10: batch-norm stats (biased var) ---------------
__global__ __launch_bounds__(256) void k_bnstats(const float* __restrict__ h,
                                                 float* __restrict__ mu,
                                                 float* __restrict__ rstd) {
    int o = blockIdx.x * 256 + threadIdx.x;
    float s = 0.f, s2 = 0.f;
    for (int b = 0; b < B; ++b) { float v = h[b * 512 + o]; s += v; s2 += v * v; }
    float m = s * (1.f / B);
    float var = s2 * (1.f / B) - m * m;
    mu[o] = m;
    rstd[o] = rsqrtf(var + 1e-5f);
}

// ---------------- kernel 9: hp1 = [leaky(bn(hp0)), g] @ w1 + b1 ------------
__global__ __launch_bounds__(256) void k_fc1(const float* __restrict__ hp0,
                                             const float* __restrict__ mu0,
                                             const float* __restrict__ rstd0,
                                             const float* __restrict__ gam,
                                             const float* __restrict__ bet,
                                             const float* __restrict__ gbuf,
                                             const float* __restrict__ w1,
                                             const float* __restrict__ b1,
                                             float* __restrict__ hp1) {
    int b = blockIdx.x, ot = blockIdx.y, tid = threadIdx.x;
    __shared__ float h[1024];
    for (int o = tid; o < 512; o += 256) {
        float v = hp0[b * 512 + o];
        v = gam[o] * (v - mu0[o]) * rstd0[o] + bet[o];
        h[o] = v >= 0.f ? v : 0.01f * v;
        h[512 + o] = gbuf[(size_t)b * 512 + o];
    }
    __syncthreads();
    int q  = tid & 31;
    int kg = tid >> 5;
    const float4* w4 = (const float4*)w1;
    int wq = ot * 32 + q;
    float4 acc = {0.f, 0.f, 0.f, 0.f};
    for (int k = kg * 128; k < kg * 128 + 128; ++k) {
        float hk = h[k];
        float4 w = w4[(size_t)k * 128 + wq];
        acc.x += hk * w.x; acc.y += hk * w.y; acc.z += hk * w.z; acc.w += hk * w.w;
    }
    __shared__ float4 red[8][32];
    red[kg][q] = acc;
    __syncthreads();
    if (tid < 32) {
        float4 s = red[0][tid];
#pragma unroll
        for (int gr = 1; gr < 8; ++gr) {
            float4 r = red[gr][tid];
            s.x += r.x; s.y += r.y; s.z += r.z; s.w += r.w;
        }
        int ob = ot * 128 + tid * 4;
        s.x += b1[ob]; s.y += b1[ob + 1]; s.z += b1[ob + 2]; s.w += b1[ob + 3];
        *(float4*)&hp1[b * 512 + ob] = s;
    }
}

// ---------------- kernel 11: out = sigmoid(leaky(bn(hp1)) @ w2 + b2) -------
__global__ __launch_bounds__(64) void k_out(const float* __restrict__ hp1,
                                            const float* __restrict__ mu1,
                                            const float* __restrict__ rstd1,
                                            const float* __restrict__ gam,
                                            const float* __restrict__ bet,
                                            const float* __restrict__ w2,
                                            const float* __restrict__ b2,
                                            float* __restrict__ out) {
    int b = blockIdx.x, lane = threadIdx.x;
    float acc = 0.f;
    for (int o = lane; o < 512; o += 64) {
        float v = hp1[b * 512 + o];
        v = gam[o] * (v - mu1[o]) * rstd1[o] + bet[o];
        v = v >= 0.f ? v : 0.01f * v;
        acc += v * w2[o];
    }
    for (int off = 32; off > 0; off >>= 1) acc += __shfl_down(acc, off);
    if (lane == 0) out[b] = 1.f / (1.f + expf(-(acc + b2[0])));
}

static inline size_t align256(size_t x) { return (x + 255) & ~(size_t)255; }

extern "C" void kernel_launch(void* const* d_in, const int* in_sizes, int n_in,
                              void* d_out, int out_size, void* d_ws, size_t ws_size,
                              hipStream_t stream) {
    const float* x     = (const float*)d_in[0];
    const float* adj   = (const float*)d_in[1];
    const float* w_gc1 = (const float*)d_in[2];
    const float* b_gc1 = (const float*)d_in[3];
    const float* w_gc2 = (const float*)d_in[4];
    const float* b_gc2 = (const float*)d_in[5];
    const float* w_gc3 = (const float*)d_in[6];
    const float* b_gc3 = (const float*)d_in[7];
    const float* w_fc0 = (const float*)d_in[8];
    const float* b_fc0 = (const float*)d_in[9];
    const float* g_fc0 = (const float*)d_in[10];
    const float* be_fc0= (const float*)d_in[11];
    const float* w_fc1 = (const float*)d_in[12];
    const float* b_fc1 = (const float*)d_in[13];
    const float* g_fc1 = (const float*)d_in[14];
    const float* be_fc1= (const float*)d_in[15];
    const float* w_fc2 = (const float*)d_in[16];
    const float* b_fc2 = (const float*)d_in[17];

    char* wsp = (char*)d_ws;
    size_t off = 0;
    auto alloc = [&](size_t bytes) { void* p = wsp + off; off = align256(off + bytes); return p; };
    float* d_deg   = (float*)alloc((size_t)N * 4);
    int*   sid     = (int*)  alloc((size_t)B * 63 * 4);
    int*   sidl    = (int*)  alloc((size_t)B * 4);
    float* fes     = (float*)alloc((size_t)B * 63 * 16 * 4);
    uint4* wfrag   = (uint4*)alloc((size_t)1024 * 16);
    uint4* w2frag  = (uint4*)alloc((size_t)8192 * 16);
    int*   csr_cnt = (int*)  alloc((size_t)N * 4);
    int*   csr_idx = (int*)  alloc((size_t)N * CAP * 4);
    float* csr_val = (float*)alloc((size_t)N * CAP * 4);
    bf16*  X1      = (bf16*) alloc((size_t)B * N * 256 * 2);
    float* X2      = (float*)alloc((size_t)B * CAP * 256 * 4);
    float* gbuf    = (float*)alloc((size_t)B * 512 * 4);
    float* hp0     = (float*)alloc((size_t)B * 512 * 4);
    float* mu0     = (float*)alloc(512 * 4);
    float* rstd0   = (float*)alloc(512 * 4);
    float* hp1     = (float*)alloc((size_t)B * 512 * 4);
    float* mu1     = (float*)alloc(512 * 4);
    float* rstd1   = (float*)alloc(512 * 4);

    k_rowsum <<<N, 256, 0, stream>>>(adj, d_deg);
    k_csr    <<<N, 64, 0, stream>>>(adj, d_deg, csr_cnt, csr_idx, csr_val);
    k_extract<<<B, 256, 0, stream>>>(x, d_deg, sid, sidl, fes);
    k_wfrag  <<<4, 256, 0, stream>>>(w_gc1, wfrag);
    k_w2frag <<<32, 256, 0, stream>>>(w_gc2, w2frag);
    k_x1     <<<dim3(32, B), 256, 0, stream>>>(adj, d_deg, sid, fes, wfrag, b_gc1, X1);
    k_x2     <<<dim3(CAP / JT, B), 256, 0, stream>>>(csr_cnt, csr_idx, csr_val, sidl, X1, w2frag, b_gc2, X2);
    k_g      <<<B, 256, 0, stream>>>(csr_cnt, csr_idx, csr_val, sidl, X2, w_gc3, b_gc3, gbuf);
    k_fc0    <<<(B * 512) / 256, 256, 0, stream>>>(x, w_fc0, b_fc0, hp0);
    k_bnstats<<<2, 256, 0, stream>>>(hp0, mu0, rstd0);
    k_fc1    <<<dim3(B, 4), 256, 0, stream>>>(hp0, mu0, rstd0, g_fc0, be_fc0, gbuf, w_fc1, b_fc1, hp1);
    k_bnstats<<<2, 256, 0, stream>>>(hp1, mu1, rstd1);
    k_out    <<<B, 64, 0, stream>>>(hp1, mu1, rstd1, g_fc1, be_fc1, w_fc2, b_fc2, (float*)d_out);
}

// Round 8
// 241.606 us; speedup vs baseline: 1.2963x; 1.1059x over previous
//
#include <hip/hip_runtime.h>
#include <hip/hip_bf16.h>

typedef __hip_bfloat16 bf16;
typedef short s8v __attribute__((ext_vector_type(8)));
typedef float f4v __attribute__((ext_vector_type(4)));

#define B   128
#define N   2000
#define S   64
#define CAP 128          // max neighbors per row (mean ~65, 8-sigma safe)
#define JT  16           // neighbors per block in k_x2
#define XROW 1088        // S*17

__device__ inline ushort bfb(float v) {
    union { __hip_bfloat16 h; ushort u; } c; c.h = __float2bfloat16(v); return c.u;
}

// ---------------- kernel 1: d[m] = rsqrt(sum(adj[m,:]) + 1) ----------------
__global__ __launch_bounds__(256) void k_rowsum(const float* __restrict__ adj,
                                                float* __restrict__ d) {
    int m = blockIdx.x;
    const float* row = adj + (size_t)m * N;
    float s = 0.f;
    for (int c = threadIdx.x; c < N; c += 256) s += row[c];
    for (int o = 32; o > 0; o >>= 1) s += __shfl_down(s, o);
    __shared__ float red[4];
    int wave = threadIdx.x >> 6;
    if ((threadIdx.x & 63) == 0) red[wave] = s;
    __syncthreads();
    if (threadIdx.x == 0)
        d[m] = rsqrtf(red[0] + red[1] + red[2] + red[3] + 1.0f);
}

// ---------------- kernel 2: CSR of Ahat (ordered ballot compaction) --------
__global__ __launch_bounds__(64) void k_csr(const float* __restrict__ adj,
                                            const float* __restrict__ d,
                                            int* __restrict__ cnt,
                                            int* __restrict__ idx,
                                            float* __restrict__ val) {
    int m = blockIdx.x;
    int lane = threadIdx.x;
    const float* row = adj + (size_t)m * N;
    float dm = d[m];
    int base = 0;
    for (int c0 = 0; c0 < N; c0 += 64) {
        int c = c0 + lane;
        float a = 0.f;
        if (c < N) { a = row[c]; if (c == m) a += 1.0f; }
        bool pred = (a != 0.f);
        unsigned long long mask = __ballot(pred);
        int pos = base + __popcll(mask & ((1ull << lane) - 1ull));
        if (pred && pos < CAP) {
            idx[m * CAP + pos] = c;
            val[m * CAP + pos] = dm * d[c] * a;
        }
        base += (int)__popcll(mask);
    }
    if (lane == 0) cnt[m] = base < CAP ? base : CAP;
}

// ---------------- kernel 3: extract sids / sid_last / pack fe^T A-frags ----
// feA[(b*2+kc)*64 + l] : 8 bf16 of fes[t = kc*32 + (l>>4)*8 + j][f = l&15]
__global__ __launch_bounds__(256) void k_extract(const float* __restrict__ x,
                                                 const float* __restrict__ d,
                                                 int* __restrict__ sid,
                                                 int* __restrict__ sid_last,
                                                 uint4* __restrict__ feA) {
    int b = blockIdx.x, tid = threadIdx.x;
    const float* xb = x + (size_t)b * XROW;
    __shared__ float dss_sh[63];
    __shared__ float fe_sh[64][16];
    if (tid < S - 1) {
        int s_ = (int)xb[tid * 17 + 15];
        sid[b * (S - 1) + tid] = s_;
        dss_sh[tid] = d[s_];
    }
    if (tid == S - 1) sid_last[b] = (int)xb[(S - 1) * 17 + 15];
    if (tid >= 240 && tid < 256) fe_sh[63][tid - 240] = 0.f;   // zero pad row
    __syncthreads();
    for (int i = tid; i < (S - 1) * 16; i += 256) {
        int t = i >> 4, f = i & 15;
        fe_sh[t][f] = dss_sh[t] * xb[t * 17 + (f < 15 ? f : 16)];
    }
    __syncthreads();
    if (tid < 128) {
        int kc = tid >> 6, l = tid & 63;
        int f = l & 15, tg = l >> 4;
        ushort h[8];
#pragma unroll
        for (int j = 0; j < 8; ++j)
            h[j] = bfb(fe_sh[kc * 32 + tg * 8 + j][f]);
        uint4 r;
        r.x = h[0] | ((uint)h[1] << 16);
        r.y = h[2] | ((uint)h[3] << 16);
        r.z = h[4] | ((uint)h[5] << 16);
        r.w = h[6] | ((uint)h[7] << 16);
        feA[(b * 2 + kc) * 64 + l] = r;
    }
}

// ---------------- kernel 3bc: pack W1^T and W2 MFMA fragments --------------
__global__ __launch_bounds__(256) void k_packw(const float* __restrict__ w1,
                                               const float* __restrict__ w2,
                                               uint4* __restrict__ wf1,
                                               uint4* __restrict__ wf2) {
    int blk = blockIdx.x;
    if (blk < 4) {
        int e = blk * 256 + threadIdx.x;          // 0..1023
        int ct = e >> 6, l = e & 63;
        int kg = l >> 4, ch = ct * 16 + (l & 15);
        ushort h[8];
#pragma unroll
        for (int j = 0; j < 8; ++j) {
            int f = kg * 8 + j;
            h[j] = (f < 16) ? bfb(w1[f * 256 + ch]) : (ushort)0;
        }
        uint4 r;
        r.x = h[0] | ((uint)h[1] << 16);
        r.y = h[2] | ((uint)h[3] << 16);
        r.z = h[4] | ((uint)h[5] << 16);
        r.w = h[6] | ((uint)h[7] << 16);
        wf1[e] = r;
    } else {
        int e = (blk - 4) * 256 + threadIdx.x;    // 0..8191
        int l = e & 63;
        int kc = (e >> 6) & 7;
        int nt = e >> 9;
        int col = l & 15, kg = l >> 4;
        ushort h[8];
#pragma unroll
        for (int i = 0; i < 8; ++i) {
            int k = kc * 32 + kg * 8 + i;
            h[i] = bfb(w2[k * 256 + nt * 16 + col]);
        }
        uint4 r;
        r.x = h[0] | ((uint)h[1] << 16);
        r.y = h[2] | ((uint)h[3] << 16);
        r.z = h[4] | ((uint)h[5] << 16);
        r.w = h[6] | ((uint)h[7] << 16);
        wf2[e] = r;
    }
}

// ---------------- kernel 4: X1[b,p,:] = relu((Ahat X)[b,p] @ w1 + b1) ------
// phase 1 (all-MFMA): per wave, Y[16f x 16p] = feT_frag x adj_gather_frag via
//   2 mfma (k=64, t=63 zero-padded); scale rows by d[p]; bf16 -> Ylds.
// phase 2: D = W1^T x Y^T via 16 mfma (verified, unchanged).
__global__ __launch_bounds__(256) void k_x1(const float* __restrict__ adj,
                                            const float* __restrict__ d,
                                            const int* __restrict__ sid,
                                            const uint4* __restrict__ feA,
                                            const uint4* __restrict__ wfrag,
                                            const float* __restrict__ b1,
                                            bf16* __restrict__ X1) {
    __shared__ int sv[64];
    __shared__ __align__(16) ushort Ylds[64][40];   // 80B rows
    __shared__ float b1s[256];
    int b = blockIdx.y, p0 = blockIdx.x * 64, tid = threadIdx.x;
    b1s[tid] = b1[tid];
    if (tid < 63) sv[tid] = sid[b * 63 + tid];
    if (tid == 63) sv[63] = 0;
    __syncthreads();

    int l = tid & 63, wv = tid >> 6;
    int lm = l & 15, lg = l >> 4;
    int pt = p0 + wv * 16;
    int pcol = pt + lm;
    bool pv = (pcol < N);
    int pc = pv ? pcol : 0;

    // A1 frags: fe^T (bf16, t-padded), 2 x b128 global (L2-hot)
    s8v a1_0 = *(const s8v*)&feA[(b * 2 + 0) * 64 + l];
    s8v a1_1 = *(const s8v*)&feA[(b * 2 + 1) * 64 + l];

    // B1 gather: 16 independent vector-addressed adj loads
    int ss[16];
#pragma unroll
    for (int q = 0; q < 16; ++q)
        ss[q] = sv[(q >> 3) * 32 + lg * 8 + (q & 7)];
    float av[16];
#pragma unroll
    for (int q = 0; q < 16; ++q)
        av[q] = adj[(size_t)ss[q] * N + pc];
#pragma unroll
    for (int q = 0; q < 16; ++q) {
        av[q] = pv ? av[q] : 0.f;
        if (pcol == ss[q]) av[q] += 1.0f;
    }
    ushort h[16];
#pragma unroll
    for (int q = 0; q < 16; ++q) h[q] = bfb(av[q]);
    s8v b1f, b2f;
    {
        uint4 t0, t1;
        t0.x = h[0] | ((uint)h[1] << 16);  t0.y = h[2] | ((uint)h[3] << 16);
        t0.z = h[4] | ((uint)h[5] << 16);  t0.w = h[6] | ((uint)h[7] << 16);
        t1.x = h[8] | ((uint)h[9] << 16);  t1.y = h[10] | ((uint)h[11] << 16);
        t1.z = h[12] | ((uint)h[13] << 16); t1.w = h[14] | ((uint)h[15] << 16);
        b1f = *(s8v*)&t0; b2f = *(s8v*)&t1;
    }
    // gather MFMA: D1[f][p] (f=(l>>4)*4+reg, p=lm)
    f4v D1 = (f4v){0.f, 0.f, 0.f, 0.f};
    D1 = __builtin_amdgcn_mfma_f32_16x16x32_bf16(a1_0, b1f, D1, 0, 0, 0);
    D1 = __builtin_amdgcn_mfma_f32_16x16x32_bf16(a1_1, b2f, D1, 0, 0, 0);
    float dp = d[pc] * (pv ? 1.f : 0.f);
    uint2 pk;
    pk.x = bfb(D1[0] * dp) | ((uint)bfb(D1[1] * dp) << 16);
    pk.y = bfb(D1[2] * dp) | ((uint)bfb(D1[3] * dp) << 16);
    *(uint2*)&Ylds[wv * 16 + lm][lg * 4] = pk;
    *(uint2*)&Ylds[wv * 16 + lm][16 + lg * 4] = make_uint2(0u, 0u);  // K-pad
    __syncthreads();

    // ---- phase 2: MFMA ----
    s8v yf = *(const s8v*)&Ylds[wv * 16 + lm][lg * 8];      // B = Y^T frag
    f4v acc2[16];
#pragma unroll
    for (int ct = 0; ct < 16; ++ct) acc2[ct] = (f4v){0.f, 0.f, 0.f, 0.f};
#pragma unroll
    for (int ct = 0; ct < 16; ++ct) {
        s8v wfv = *(const s8v*)&wfrag[ct * 64 + l];         // A = W^T frag
        acc2[ct] = __builtin_amdgcn_mfma_f32_16x16x32_bf16(wfv, yf, acc2[ct], 0, 0, 0);
    }
    int pp = p0 + wv * 16 + lm;
    if (pp < N) {
        uint2* dst = (uint2*)X1 + ((size_t)b * N + pp) * 64;
#pragma unroll
        for (int ct = 0; ct < 16; ++ct) {
            float4 bz = *(float4*)&b1s[ct * 16 + lg * 4];
            float v0 = acc2[ct][0] + bz.x; v0 = v0 > 0.f ? v0 : 0.f;
            float v1 = acc2[ct][1] + bz.y; v1 = v1 > 0.f ? v1 : 0.f;
            float v2 = acc2[ct][2] + bz.z; v2 = v2 > 0.f ? v2 : 0.f;
            float v3 = acc2[ct][3] + bz.w; v3 = v3 > 0.f ? v3 : 0.f;
            uint2 pko;
            pko.x = bfb(v0) | ((uint)bfb(v1) << 16);
            pko.y = bfb(v2) | ((uint)bfb(v3) << 16);
            dst[ct * 4 + lg] = pko;
        }
    }
}

// ---------------- kernel 5: X2 at one-hop(m_b), JT=16 neighbors per block --
__global__ __launch_bounds__(256) void k_x2(const int* __restrict__ cnt,
                                            const int* __restrict__ idxA,
                                            const float* __restrict__ valA,
                                            const int* __restrict__ sid_last,
                                            const bf16* __restrict__ X1,
                                            const uint4* __restrict__ w2f,
                                            const float* __restrict__ b2,
                                            float* __restrict__ X2) {
    __shared__ int    nns[JT];
    __shared__ int    ncn_s[JT];
    __shared__ int    nidx[JT][CAP];
    __shared__ float  nval[JT][CAP];
    __shared__ ushort agg[JT][264];   // 528B row stride
    int b = blockIdx.y, j0 = blockIdx.x * JT, tid = threadIdx.x;
    int m = sid_last[b];
    int cj = cnt[m];
    if (j0 >= cj) return;
    int nj = cj - j0; if (nj > JT) nj = JT;
    if (tid < JT) {
        int n = idxA[m * CAP + j0 + (tid < nj ? tid : 0)];
        nns[tid] = n;
        ncn_s[tid] = (tid < nj) ? cnt[n] : 0;
    }
    __syncthreads();
    for (int i = tid; i < JT * CAP; i += 256) {
        int jj = i >> 7, k = i & (CAP - 1);
        int n = nns[jj];
        nidx[jj][k] = idxA[n * CAP + k];
        nval[jj][k] = valA[n * CAP + k];
    }
    __syncthreads();
    int lane = tid & 63;
    int w = __builtin_amdgcn_readfirstlane(tid >> 6);
    int jbase = w * 4;
    const uint2* X1bl = (const uint2*)X1 + (size_t)b * N * 64 + lane;

    float a0[4] = {0.f, 0.f, 0.f, 0.f};
    float a1[4] = {0.f, 0.f, 0.f, 0.f};
    float a2[4] = {0.f, 0.f, 0.f, 0.f};
    float a3[4] = {0.f, 0.f, 0.f, 0.f};
    int   cn[4];
    uint2 u[4];
    float v[4];
#pragma unroll
    for (int jj = 0; jj < 4; ++jj) {
        cn[jj] = ncn_s[jbase + jj];
        if (cn[jj] > 0) {
            int p = nidx[jbase + jj][0];
            v[jj] = nval[jbase + jj][0];
            u[jj] = X1bl[(size_t)p * 64];
        }
    }
    int cmax = cn[0];
    if (cn[1] > cmax) cmax = cn[1];
    if (cn[2] > cmax) cmax = cn[2];
    if (cn[3] > cmax) cmax = cn[3];
    for (int k = 0; k < cmax; ++k) {
        uint2 uc[4]; float vc[4];
#pragma unroll
        for (int jj = 0; jj < 4; ++jj) { uc[jj] = u[jj]; vc[jj] = v[jj]; }
#pragma unroll
        for (int jj = 0; jj < 4; ++jj) {          // issue next loads (4 chains)
            if (k + 1 < cn[jj]) {
                int p = nidx[jbase + jj][k + 1];
                v[jj] = nval[jbase + jj][k + 1];
                u[jj] = X1bl[(size_t)p * 64];
            }
        }
#pragma unroll
        for (int jj = 0; jj < 4; ++jj) {          // accumulate current
            if (k < cn[jj]) {
                float f0 = __uint_as_float(uc[jj].x << 16);
                float f1 = __uint_as_float(uc[jj].x & 0xffff0000u);
                float f2 = __uint_as_float(uc[jj].y << 16);
                float f3 = __uint_as_float(uc[jj].y & 0xffff0000u);
                a0[jj] += vc[jj] * f0; a1[jj] += vc[jj] * f1;
                a2[jj] += vc[jj] * f2; a3[jj] += vc[jj] * f3;
            }
        }
    }
#pragma unroll
    for (int jj = 0; jj < 4; ++jj) {
        uint2 pk;
        pk.x = bfb(a0[jj]) | ((uint)bfb(a1[jj]) << 16);
        pk.y = bfb(a2[jj]) | ((uint)bfb(a3[jj]) << 16);
        *(uint2*)&agg[jbase + jj][lane * 4] = pk;
    }
    __syncthreads();
    // MFMA tail: D[j, n] = agg[16 x 256] @ w2[256 x 256]
    int col = lane & 15, rg = lane >> 4;
    s8v af[8];
#pragma unroll
    for (int kc = 0; kc < 8; ++kc)
        af[kc] = *(const s8v*)&agg[col][kc * 32 + rg * 8];
#pragma unroll
    for (int t = 0; t < 4; ++t) {
        int nt = w * 4 + t;
        f4v acc = (f4v){0.f, 0.f, 0.f, 0.f};
#pragma unroll
        for (int kc = 0; kc < 8; ++kc) {
            s8v bf = *(const s8v*)&w2f[(nt * 8 + kc) * 64 + lane];
            acc = __builtin_amdgcn_mfma_f32_16x16x32_bf16(af[kc], bf, acc, 0, 0, 0);
        }
        float bv = b2[nt * 16 + col];
        float* dst = X2 + ((size_t)b * CAP + j0) * 256 + nt * 16 + col;
#pragma unroll
        for (int i = 0; i < 4; ++i) {
            int row = rg * 4 + i;
            if (row < nj) {
                float vv = acc[i] + bv;
                dst[(size_t)row * 256] = vv > 0.f ? vv : 0.f;
            }
        }
    }
}

// ---------------- kernel 6: g[b] = relu((Ahat X2)[b,m_b] @ w3 + b3) --------
__global__ __launch_bounds__(256) void k_g(const int* __restrict__ cnt,
                                           const int* __restrict__ idxA,
                                           const float* __restrict__ valA,
                                           const int* __restrict__ sid_last,
                                           const float* __restrict__ X2,
                                           const float* __restrict__ w3,
                                           const float* __restrict__ b3,
                                           float* __restrict__ g) {
    int b = blockIdx.x, tid = threadIdx.x;
    int m = sid_last[b];
    int cj = cnt[m];
    __shared__ float g1[256];
    float acc = 0.f;
    for (int jj = 0; jj < cj; ++jj)
        acc += valA[m * CAP + jj] * X2[((size_t)b * CAP + jj) * 256 + tid];
    g1[tid] = acc;
    __syncthreads();
    for (int oo = tid; oo < 512; oo += 256) {
        float a2 = b3[oo];
#pragma unroll 4
        for (int f = 0; f < 256; ++f) a2 += g1[f] * w3[f * 512 + oo];
        g[(size_t)b * 512 + oo] = a2 > 0.f ? a2 : 0.f;
    }
}

// ---------------- kernel 7: hp0 = x_last[:, :15] @ w0 + b0 -----------------
__global__ __launch_bounds__(256) void k_fc0(const float* __restrict__ x,
                                             const float* __restrict__ w0,
                                             const float* __restrict__ b0,
                                             float* __restrict__ hp0) {
    int i = blockIdx.x * 256 + threadIdx.x;
    int b = i >> 9, o = i & 511;
    const float* xr = x + (size_t)b * XROW + (S - 1) * 17;
    float acc = b0[o];
#pragma unroll
    for (int f = 0; f < 15; ++f) acc += xr[f] * w0[f * 512 + o];
    hp0[i] = acc;
}

// ---------------- kernel 8/10: batch-norm stats (biased var) ---------------
__global__ __launch_bounds__(256) void k_bnstats(const float* __restrict__ h,
                                                 float* __restrict__ mu,
                                                 float* __restrict__ rstd) {
    int o = blockIdx.x * 256 + threadIdx.x;
    float s = 0.f, s2 = 0.f;
    for (int b = 0; b < B; ++b) { float v = h[b * 512 + o]; s += v; s2 += v * v; }
    float m = s * (1.f / B);
    float var = s2 * (1.f / B) - m * m;
    mu[o] = m;
    rstd[o] = rsqrtf(var + 1e-5f);
}

// ---------------- kernel 9: hp1 = [leaky(bn(hp0)), g] @ w1 + b1 ------------
__global__ __launch_bounds__(256) void k_fc1(const float* __restrict__ hp0,
                                             const float* __restrict__ mu0,
                                             const float* __restrict__ rstd0,
                                             const float* __restrict__ gam,
                                             const float* __restrict__ bet,
                                             const float* __restrict__ gbuf,
                                             const float* __restrict__ w1,
                                             const float* __restrict__ b1,
                                             float* __restrict__ hp1) {
    int b = blockIdx.x, ot = blockIdx.y, tid = threadIdx.x;
    __shared__ float h[1024];
    for (int o = tid; o < 512; o += 256) {
        float v = hp0[b * 512 + o];
        v = gam[o] * (v - mu0[o]) * rstd0[o] + bet[o];
        h[o] = v >= 0.f ? v : 0.01f * v;
        h[512 + o] = gbuf[(size_t)b * 512 + o];
    }
    __syncthreads();
    int q  = tid & 31;
    int kg = tid >> 5;
    const float4* w4 = (const float4*)w1;
    int wq = ot * 32 + q;
    float4 acc = {0.f, 0.f, 0.f, 0.f};
    for (int k = kg * 128; k < kg * 128 + 128; ++k) {
        float hk = h[k];
        float4 w = w4[(size_t)k * 128 + wq];
        acc.x += hk * w.x; acc.y += hk * w.y; acc.z += hk * w.z; acc.w += hk * w.w;
    }
    __shared__ float4 red[8][32];
    red[kg][q] = acc;
    __syncthreads();
    if (tid < 32) {
        float4 s = red[0][tid];
#pragma unroll
        for (int gr = 1; gr < 8; ++gr) {
            float4 r = red[gr][tid];
            s.x += r.x; s.y += r.y; s.z += r.z; s.w += r.w;
        }
        int ob = ot * 128 + tid * 4;
        s.x += b1[ob]; s.y += b1[ob + 1]; s.z += b1[ob + 2]; s.w += b1[ob + 3];
        *(float4*)&hp1[b * 512 + ob] = s;
    }
}

// ---------------- kernel 11: out = sigmoid(leaky(bn(hp1)) @ w2 + b2) -------
__global__ __launch_bounds__(64) void k_out(const float* __restrict__ hp1,
                                            const float* __restrict__ mu1,
                                            const float* __restrict__ rstd1,
                                            const float* __restrict__ gam,
                                            const float* __restrict__ bet,
                                            const float* __restrict__ w2,
                                            const float* __restrict__ b2,
                                            float* __restrict__ out) {
    int b = blockIdx.x, lane = threadIdx.x;
    float acc = 0.f;
    for (int o = lane; o < 512; o += 64) {
        float v = hp1[b * 512 + o];
        v = gam[o] * (v - mu1[o]) * rstd1[o] + bet[o];
        v = v >= 0.f ? v : 0.01f * v;
        acc += v * w2[o];
    }
    for (int off = 32; off > 0; off >>= 1) acc += __shfl_down(acc, off);
    if (lane == 0) out[b] = 1.f / (1.f + expf(-(acc + b2[0])));
}

static inline size_t align256(size_t x) { return (x + 255) & ~(size_t)255; }

extern "C" void kernel_launch(void* const* d_in, const int* in_sizes, int n_in,
                              void* d_out, int out_size, void* d_ws, size_t ws_size,
                              hipStream_t stream) {
    const float* x     = (const float*)d_in[0];
    const float* adj   = (const float*)d_in[1];
    const float* w_gc1 = (const float*)d_in[2];
    const float* b_gc1 = (const float*)d_in[3];
    const float* w_gc2 = (const float*)d_in[4];
    const float* b_gc2 = (const float*)d_in[5];
    const float* w_gc3 = (const float*)d_in[6];
    const float* b_gc3 = (const float*)d_in[7];
    const float* w_fc0 = (const float*)d_in[8];
    const float* b_fc0 = (const float*)d_in[9];
    const float* g_fc0 = (const float*)d_in[10];
    const float* be_fc0= (const float*)d_in[11];
    const float* w_fc1 = (const float*)d_in[12];
    const float* b_fc1 = (const float*)d_in[13];
    const float* g_fc1 = (const float*)d_in[14];
    const float* be_fc1= (const float*)d_in[15];
    const float* w_fc2 = (const float*)d_in[16];
    const float* b_fc2 = (const float*)d_in[17];

    char* wsp = (char*)d_ws;
    size_t off = 0;
    auto alloc = [&](size_t bytes) { void* p = wsp + off; off = align256(off + bytes); return p; };
    float* d_deg   = (float*)alloc((size_t)N * 4);
    int*   sid     = (int*)  alloc((size_t)B * 63 * 4);
    int*   sidl    = (int*)  alloc((size_t)B * 4);
    uint4* feA     = (uint4*)alloc((size_t)B * 2 * 64 * 16);
    uint4* wfrag   = (uint4*)alloc((size_t)1024 * 16);
    uint4* w2frag  = (uint4*)alloc((size_t)8192 * 16);
    int*   csr_cnt = (int*)  alloc((size_t)N * 4);
    int*   csr_idx = (int*)  alloc((size_t)N * CAP * 4);
    float* csr_val = (float*)alloc((size_t)N * CAP * 4);
    bf16*  X1      = (bf16*) alloc((size_t)B * N * 256 * 2);
    float* X2      = (float*)alloc((size_t)B * CAP * 256 * 4);
    float* gbuf    = (float*)alloc((size_t)B * 512 * 4);
    float* hp0     = (float*)alloc((size_t)B * 512 * 4);
    float* mu0     = (float*)alloc(512 * 4);
    float* rstd0   = (float*)alloc(512 * 4);
    float* hp1     = (float*)alloc((size_t)B * 512 * 4);
    float* mu1     = (float*)alloc(512 * 4);
    float* rstd1   = (float*)alloc(512 * 4);

    k_rowsum <<<N, 256, 0, stream>>>(adj, d_deg);
    k_csr    <<<N, 64, 0, stream>>>(adj, d_deg, csr_cnt, csr_idx, csr_val);
    k_packw  <<<36, 256, 0, stream>>>(w_gc1, w_gc2, wfrag, w2frag);
    k_extract<<<B, 256, 0, stream>>>(x, d_deg, sid, sidl, feA);
    k_x1     <<<dim3(32, B), 256, 0, stream>>>(adj, d_deg, sid, feA, wfrag, b_gc1, X1);
    k_x2     <<<dim3(CAP / JT, B), 256, 0, stream>>>(csr_cnt, csr_idx, csr_val, sidl, X1, w2frag, b_gc2, X2);
    k_g      <<<B, 256, 0, stream>>>(csr_cnt, csr_idx, csr_val, sidl, X2, w_gc3, b_gc3, gbuf);
    k_fc0    <<<(B * 512) / 256, 256, 0, stream>>>(x, w_fc0, b_fc0, hp0);
    k_bnstats<<<2, 256, 0, stream>>>(hp0, mu0, rstd0);
    k_fc1    <<<dim3(B, 4), 256, 0, stream>>>(hp0, mu0, rstd0, g_fc0, be_fc0, gbuf, w_fc1, b_fc1, hp1);
    k_bnstats<<<2, 256, 0, stream>>>(hp1, mu1, rstd1);
    k_out    <<<B, 64, 0, stream>>>(hp1, mu1, rstd1, g_fc1, be_fc1, w_fc2, b_fc2, (float*)d_out);
}

// Round 9
// 221.531 us; speedup vs baseline: 1.4138x; 1.0906x over previous
//
#include <hip/hip_runtime.h>
#include <hip/hip_bf16.h>

typedef __hip_bfloat16 bf16;
typedef short s8v __attribute__((ext_vector_type(8)));
typedef float f4v __attribute__((ext_vector_type(4)));

#define B   128
#define N   2000
#define S   64
#define CAP 128          // max neighbors per row (mean ~65, 8-sigma safe)
#define JT  16           // neighbors per block in k_x2mm
#define JG  8            // j-rows per block in k_gather
#define XROW 1088        // S*17

__device__ inline ushort bfb(float v) {
    union { __hip_bfloat16 h; ushort u; } c; c.h = __float2bfloat16(v); return c.u;
}

// ---------------- kernel 1: d[m] = rsqrt(sum(adj[m,:]) + 1) ----------------
__global__ __launch_bounds__(256) void k_rowsum(const float* __restrict__ adj,
                                                float* __restrict__ d) {
    int m = blockIdx.x;
    const float* row = adj + (size_t)m * N;
    float s = 0.f;
    for (int c = threadIdx.x; c < N; c += 256) s += row[c];
    for (int o = 32; o > 0; o >>= 1) s += __shfl_down(s, o);
    __shared__ float red[4];
    int wave = threadIdx.x >> 6;
    if ((threadIdx.x & 63) == 0) red[wave] = s;
    __syncthreads();
    if (threadIdx.x == 0)
        d[m] = rsqrtf(red[0] + red[1] + red[2] + red[3] + 1.0f);
}

// ---------------- kernel 2: CSR of Ahat (ordered ballot compaction) --------
__global__ __launch_bounds__(64) void k_csr(const float* __restrict__ adj,
                                            const float* __restrict__ d,
                                            int* __restrict__ cnt,
                                            int* __restrict__ idx,
                                            float* __restrict__ val) {
    int m = blockIdx.x;
    int lane = threadIdx.x;
    const float* row = adj + (size_t)m * N;
    float dm = d[m];
    int base = 0;
    for (int c0 = 0; c0 < N; c0 += 64) {
        int c = c0 + lane;
        float a = 0.f;
        if (c < N) { a = row[c]; if (c == m) a += 1.0f; }
        bool pred = (a != 0.f);
        unsigned long long mask = __ballot(pred);
        int pos = base + __popcll(mask & ((1ull << lane) - 1ull));
        if (pred && pos < CAP) {
            idx[m * CAP + pos] = c;
            val[m * CAP + pos] = dm * d[c] * a;
        }
        base += (int)__popcll(mask);
    }
    if (lane == 0) cnt[m] = base < CAP ? base : CAP;
}

// ---------------- kernel 3: extract sids / sid_last / pack fe^T A-frags ----
__global__ __launch_bounds__(256) void k_extract(const float* __restrict__ x,
                                                 const float* __restrict__ d,
                                                 int* __restrict__ sid,
                                                 int* __restrict__ sid_last,
                                                 uint4* __restrict__ feA) {
    int b = blockIdx.x, tid = threadIdx.x;
    const float* xb = x + (size_t)b * XROW;
    __shared__ float dss_sh[63];
    __shared__ float fe_sh[64][16];
    if (tid < S - 1) {
        int s_ = (int)xb[tid * 17 + 15];
        sid[b * (S - 1) + tid] = s_;
        dss_sh[tid] = d[s_];
    }
    if (tid == S - 1) sid_last[b] = (int)xb[(S - 1) * 17 + 15];
    if (tid >= 240 && tid < 256) fe_sh[63][tid - 240] = 0.f;   // zero pad row
    __syncthreads();
    for (int i = tid; i < (S - 1) * 16; i += 256) {
        int t = i >> 4, f = i & 15;
        fe_sh[t][f] = dss_sh[t] * xb[t * 17 + (f < 15 ? f : 16)];
    }
    __syncthreads();
    if (tid < 128) {
        int kc = tid >> 6, l = tid & 63;
        int f = l & 15, tg = l >> 4;
        ushort h[8];
#pragma unroll
        for (int j = 0; j < 8; ++j)
            h[j] = bfb(fe_sh[kc * 32 + tg * 8 + j][f]);
        uint4 r;
        r.x = h[0] | ((uint)h[1] << 16);
        r.y = h[2] | ((uint)h[3] << 16);
        r.z = h[4] | ((uint)h[5] << 16);
        r.w = h[6] | ((uint)h[7] << 16);
        feA[(b * 2 + kc) * 64 + l] = r;
    }
}

// ---------------- kernel 3bc: pack W1^T and W2 MFMA fragments --------------
__global__ __launch_bounds__(256) void k_packw(const float* __restrict__ w1,
                                               const float* __restrict__ w2,
                                               uint4* __restrict__ wf1,
                                               uint4* __restrict__ wf2) {
    int blk = blockIdx.x;
    if (blk < 4) {
        int e = blk * 256 + threadIdx.x;          // 0..1023
        int ct = e >> 6, l = e & 63;
        int kg = l >> 4, ch = ct * 16 + (l & 15);
        ushort h[8];
#pragma unroll
        for (int j = 0; j < 8; ++j) {
            int f = kg * 8 + j;
            h[j] = (f < 16) ? bfb(w1[f * 256 + ch]) : (ushort)0;
        }
        uint4 r;
        r.x = h[0] | ((uint)h[1] << 16);
        r.y = h[2] | ((uint)h[3] << 16);
        r.z = h[4] | ((uint)h[5] << 16);
        r.w = h[6] | ((uint)h[7] << 16);
        wf1[e] = r;
    } else {
        int e = (blk - 4) * 256 + threadIdx.x;    // 0..8191
        int l = e & 63;
        int kc = (e >> 6) & 7;
        int nt = e >> 9;
        int col = l & 15, kg = l >> 4;
        ushort h[8];
#pragma unroll
        for (int i = 0; i < 8; ++i) {
            int k = kc * 32 + kg * 8 + i;
            h[i] = bfb(w2[k * 256 + nt * 16 + col]);
        }
        uint4 r;
        r.x = h[0] | ((uint)h[1] << 16);
        r.y = h[2] | ((uint)h[3] << 16);
        r.z = h[4] | ((uint)h[5] << 16);
        r.w = h[6] | ((uint)h[7] << 16);
        wf2[e] = r;
    }
}

// ---------------- kernel 4: X1[b,p,:] = relu((Ahat X)[b,p] @ w1 + b1) ------
__global__ __launch_bounds__(256) void k_x1(const float* __restrict__ adj,
                                            const float* __restrict__ d,
                                            const int* __restrict__ sid,
                                            const uint4* __restrict__ feA,
                                            const uint4* __restrict__ wfrag,
                                            const float* __restrict__ b1,
                                            bf16* __restrict__ X1) {
    __shared__ int sv[64];
    __shared__ __align__(16) ushort Ylds[64][40];   // 80B rows
    __shared__ float b1s[256];
    int b = blockIdx.y, p0 = blockIdx.x * 64, tid = threadIdx.x;
    b1s[tid] = b1[tid];
    if (tid < 63) sv[tid] = sid[b * 63 + tid];
    if (tid == 63) sv[63] = 0;
    __syncthreads();

    int l = tid & 63, wv = tid >> 6;
    int lm = l & 15, lg = l >> 4;
    int pt = p0 + wv * 16;
    int pcol = pt + lm;
    bool pv = (pcol < N);
    int pc = pv ? pcol : 0;

    s8v a1_0 = *(const s8v*)&feA[(b * 2 + 0) * 64 + l];
    s8v a1_1 = *(const s8v*)&feA[(b * 2 + 1) * 64 + l];

    int ss[16];
#pragma unroll
    for (int q = 0; q < 16; ++q)
        ss[q] = sv[(q >> 3) * 32 + lg * 8 + (q & 7)];
    float av[16];
#pragma unroll
    for (int q = 0; q < 16; ++q)
        av[q] = adj[(size_t)ss[q] * N + pc];
#pragma unroll
    for (int q = 0; q < 16; ++q) {
        av[q] = pv ? av[q] : 0.f;
        if (pcol == ss[q]) av[q] += 1.0f;
    }
    ushort h[16];
#pragma unroll
    for (int q = 0; q < 16; ++q) h[q] = bfb(av[q]);
    s8v b1f, b2f;
    {
        uint4 t0, t1;
        t0.x = h[0] | ((uint)h[1] << 16);  t0.y = h[2] | ((uint)h[3] << 16);
        t0.z = h[4] | ((uint)h[5] << 16);  t0.w = h[6] | ((uint)h[7] << 16);
        t1.x = h[8] | ((uint)h[9] << 16);  t1.y = h[10] | ((uint)h[11] << 16);
        t1.z = h[12] | ((uint)h[13] << 16); t1.w = h[14] | ((uint)h[15] << 16);
        b1f = *(s8v*)&t0; b2f = *(s8v*)&t1;
    }
    f4v D1 = (f4v){0.f, 0.f, 0.f, 0.f};
    D1 = __builtin_amdgcn_mfma_f32_16x16x32_bf16(a1_0, b1f, D1, 0, 0, 0);
    D1 = __builtin_amdgcn_mfma_f32_16x16x32_bf16(a1_1, b2f, D1, 0, 0, 0);
    float dp = d[pc] * (pv ? 1.f : 0.f);
    uint2 pk;
    pk.x = bfb(D1[0] * dp) | ((uint)bfb(D1[1] * dp) << 16);
    pk.y = bfb(D1[2] * dp) | ((uint)bfb(D1[3] * dp) << 16);
    *(uint2*)&Ylds[wv * 16 + lm][lg * 4] = pk;
    *(uint2*)&Ylds[wv * 16 + lm][16 + lg * 4] = make_uint2(0u, 0u);  // K-pad
    __syncthreads();

    s8v yf = *(const s8v*)&Ylds[wv * 16 + lm][lg * 8];      // B = Y^T frag
    f4v acc2[16];
#pragma unroll
    for (int ct = 0; ct < 16; ++ct) acc2[ct] = (f4v){0.f, 0.f, 0.f, 0.f};
#pragma unroll
    for (int ct = 0; ct < 16; ++ct) {
        s8v wfv = *(const s8v*)&wfrag[ct * 64 + l];         // A = W^T frag
        acc2[ct] = __builtin_amdgcn_mfma_f32_16x16x32_bf16(wfv, yf, acc2[ct], 0, 0, 0);
    }
    int pp = p0 + wv * 16 + lm;
    if (pp < N) {
        uint2* dst = (uint2*)X1 + ((size_t)b * N + pp) * 64;
#pragma unroll
        for (int ct = 0; ct < 16; ++ct) {
            float4 bz = *(float4*)&b1s[ct * 16 + lg * 4];
            float v0 = acc2[ct][0] + bz.x; v0 = v0 > 0.f ? v0 : 0.f;
            float v1 = acc2[ct][1] + bz.y; v1 = v1 > 0.f ? v1 : 0.f;
            float v2 = acc2[ct][2] + bz.z; v2 = v2 > 0.f ? v2 : 0.f;
            float v3 = acc2[ct][3] + bz.w; v3 = v3 > 0.f ? v3 : 0.f;
            uint2 pko;
            pko.x = bfb(v0) | ((uint)bfb(v1) << 16);
            pko.y = bfb(v2) | ((uint)bfb(v3) << 16);
            dst[ct * 4 + lg] = pko;
        }
    }
}

// ---------------- kernel 5a: k_gather — agg[b,j,:] = sum_k val*X1[b,idx,:] --
// grid (16,B): 8 j-rows/block, 2 chains/wave, branchless k-loop (clamped CSR)
__global__ __launch_bounds__(256) void k_gather(const int* __restrict__ cnt,
                                                const int* __restrict__ idxA,
                                                const float* __restrict__ valA,
                                                const int* __restrict__ sid_last,
                                                const bf16* __restrict__ X1,
                                                bf16* __restrict__ aggG) {
    __shared__ int   nns[JG];
    __shared__ int   ncn_s[JG];
    __shared__ int   nidx[JG][CAP];
    __shared__ float nval[JG][CAP];
    int b = blockIdx.y, j0 = blockIdx.x * JG, tid = threadIdx.x;
    int m = sid_last[b];
    int cj = cnt[m];
    if (tid < JG) {
        int j = j0 + tid;
        int n = idxA[m * CAP + (j < cj ? j : 0)];
        nns[tid] = n;
        ncn_s[tid] = (j < cj) ? cnt[n] : 0;
    }
    __syncthreads();
    for (int i = tid; i < JG * CAP; i += 256) {
        int jj = i >> 7, k = i & (CAP - 1);
        int n = nns[jj], c = ncn_s[jj];
        nidx[jj][k] = (k < c) ? idxA[n * CAP + k] : 0;
        nval[jj][k] = (k < c) ? valA[n * CAP + k] : 0.f;
    }
    __syncthreads();
    int lane = tid & 63;
    int w = __builtin_amdgcn_readfirstlane(tid >> 6);
    int la = w * 2, lb = la + 1;
    const uint2* X1bl = (const uint2*)X1 + (size_t)b * N * 64 + lane;
    int cA = ncn_s[la], cB = ncn_s[lb];
    int cmax = cA > cB ? cA : cB;
    float aA0 = 0.f, aA1 = 0.f, aA2 = 0.f, aA3 = 0.f;
    float aB0 = 0.f, aB1 = 0.f, aB2 = 0.f, aB3 = 0.f;
    if (cmax > 0) {
        uint2 uA = X1bl[(size_t)nidx[la][0] * 64]; float vA = nval[la][0];
        uint2 uB = X1bl[(size_t)nidx[lb][0] * 64]; float vB = nval[lb][0];
        for (int k = 0; k < cmax; ++k) {
            uint2 cuA = uA, cuB = uB;
            float cvA = vA, cvB = vB;
            int kn = (k + 1 < CAP) ? k + 1 : CAP - 1;
            uA = X1bl[(size_t)nidx[la][kn] * 64]; vA = nval[la][kn];
            uB = X1bl[(size_t)nidx[lb][kn] * 64]; vB = nval[lb][kn];
            aA0 += cvA * __uint_as_float(cuA.x << 16);
            aA1 += cvA * __uint_as_float(cuA.x & 0xffff0000u);
            aA2 += cvA * __uint_as_float(cuA.y << 16);
            aA3 += cvA * __uint_as_float(cuA.y & 0xffff0000u);
            aB0 += cvB * __uint_as_float(cuB.x << 16);
            aB1 += cvB * __uint_as_float(cuB.x & 0xffff0000u);
            aB2 += cvB * __uint_as_float(cuB.y << 16);
            aB3 += cvB * __uint_as_float(cuB.y & 0xffff0000u);
        }
    }
    uint2 pkA, pkB;
    pkA.x = bfb(aA0) | ((uint)bfb(aA1) << 16);
    pkA.y = bfb(aA2) | ((uint)bfb(aA3) << 16);
    pkB.x = bfb(aB0) | ((uint)bfb(aB1) << 16);
    pkB.y = bfb(aB2) | ((uint)bfb(aB3) << 16);
    uint2* ag = (uint2*)aggG;
    ag[((size_t)b * CAP + j0 + la) * 64 + lane] = pkA;
    ag[((size_t)b * CAP + j0 + lb) * 64 + lane] = pkB;
}

// ---------------- kernel 5b: k_x2mm — X2 = relu(agg @ w2 + b2) (MFMA) ------
__global__ __launch_bounds__(256) void k_x2mm(const int* __restrict__ cnt,
                                              const int* __restrict__ sid_last,
                                              const bf16* __restrict__ aggG,
                                              const uint4* __restrict__ w2f,
                                              const float* __restrict__ b2,
                                              float* __restrict__ X2) {
    __shared__ ushort agg[JT][264];   // 528B row stride
    int b = blockIdx.y, j0 = blockIdx.x * JT, tid = threadIdx.x;
    int m = sid_last[b];
    int cj = cnt[m];
    if (j0 >= cj) return;
    int nj = cj - j0; if (nj > JT) nj = JT;
    {
        const uint4* src = (const uint4*)(aggG + ((size_t)b * CAP + j0) * 256);
        for (int i = tid; i < 512; i += 256) {
            int row = i >> 5, col = i & 31;
            *(uint4*)&agg[row][col * 8] = src[i];
        }
    }
    __syncthreads();
    int lane = tid & 63;
    int w = __builtin_amdgcn_readfirstlane(tid >> 6);
    int col = lane & 15, rg = lane >> 4;
    s8v af[8];
#pragma unroll
    for (int kc = 0; kc < 8; ++kc)
        af[kc] = *(const s8v*)&agg[col][kc * 32 + rg * 8];
#pragma unroll
    for (int t = 0; t < 4; ++t) {
        int nt = w * 4 + t;
        f4v acc = (f4v){0.f, 0.f, 0.f, 0.f};
#pragma unroll
        for (int kc = 0; kc < 8; ++kc) {
            s8v bf = *(const s8v*)&w2f[(nt * 8 + kc) * 64 + lane];
            acc = __builtin_amdgcn_mfma_f32_16x16x32_bf16(af[kc], bf, acc, 0, 0, 0);
        }
        float bv = b2[nt * 16 + col];
        float* dst = X2 + ((size_t)b * CAP + j0) * 256 + nt * 16 + col;
#pragma unroll
        for (int i = 0; i < 4; ++i) {
            int row = rg * 4 + i;
            if (row < nj) {
                float vv = acc[i] + bv;
                dst[(size_t)row * 256] = vv > 0.f ? vv : 0.f;
            }
        }
    }
}

// ---------------- kernel 6: g[b] = relu((Ahat X2)[b,m_b] @ w3 + b3) --------
__global__ __launch_bounds__(256) void k_g(const int* __restrict__ cnt,
                                           const int* __restrict__ idxA,
                                           const float* __restrict__ valA,
                                           const int* __restrict__ sid_last,
                                           const float* __restrict__ X2,
                                           const float* __restrict__ w3,
                                           const float* __restrict__ b3,
                                           float* __restrict__ g) {
    int b = blockIdx.x, tid = threadIdx.x;
    int m = sid_last[b];
    int cj = cnt[m];
    __shared__ float g1[256];
    float acc = 0.f;
    for (int jj = 0; jj < cj; ++jj)
        acc += valA[m * CAP + jj] * X2[((size_t)b * CAP + jj) * 256 + tid];
    g1[tid] = acc;
    __syncthreads();
    for (int oo = tid; oo < 512; oo += 256) {
        float a2 = b3[oo];
#pragma unroll 4
        for (int f = 0; f < 256; ++f) a2 += g1[f] * w3[f * 512 + oo];
        g[(size_t)b * 512 + oo] = a2 > 0.f ? a2 : 0.f;
    }
}

// ---------------- kernel 7: hp0 = x_last[:, :15] @ w0 + b0 -----------------
__global__ __launch_bounds__(256) void k_fc0(const float* __restrict__ x,
                                             const float* __restrict__ w0,
                                             const float* __restrict__ b0,
                                             float* __restrict__ hp0) {
    int i = blockIdx.x * 256 + threadIdx.x;
    int b = i >> 9, o = i & 511;
    const float* xr = x + (size_t)b * XROW + (S - 1) * 17;
    float acc = b0[o];
#pragma unroll
    for (int f = 0; f < 15; ++f) acc += xr[f] * w0[f * 512 + o];
    hp0[i] = acc;
}

// ---------------- kernel 8/10: batch-norm stats (biased var) ---------------
__global__ __launch_bounds__(256) void k_bnstats(const float* __restrict__ h,
                                                 float* __restrict__ mu,
                                                 float* __restrict__ rstd) {
    int o = blockIdx.x * 256 + threadIdx.x;
    float s = 0.f, s2 = 0.f;
    for (int b = 0; b < B; ++b) { float v = h[b * 512 + o]; s += v; s2 += v * v; }
    float m = s * (1.f / B);
    float var = s2 * (1.f / B) - m * m;
    mu[o] = m;
    rstd[o] = rsqrtf(var + 1e-5f);
}

// ---------------- kernel 9: hp1 = [leaky(bn(hp0)), g] @ w1 + b1 ------------
__global__ __launch_bounds__(256) void k_fc1(const float* __restrict__ hp0,
                                             const float* __restrict__ mu0,
                                             const float* __restrict__ rstd0,
                                             const float* __restrict__ gam,
                                             const float* __restrict__ bet,
                                             const float* __restrict__ gbuf,
                                             const float* __restrict__ w1,
                                             const float* __restrict__ b1,
                                             float* __restrict__ hp1) {
    int b = blockIdx.x, ot = blockIdx.y, tid = threadIdx.x;
    __shared__ float h[1024];
    for (int o = tid; o < 512; o += 256) {
        float v = hp0[b * 512 + o];
        v = gam[o] * (v - mu0[o]) * rstd0[o] + bet[o];
        h[o] = v >= 0.f ? v : 0.01f * v;
        h[512 + o] = gbuf[(size_t)b * 512 + o];
    }
    __syncthreads();
    int q  = tid & 31;
    int kg = tid >> 5;
    const float4* w4 = (const float4*)w1;
    int wq = ot * 32 + q;
    float4 acc = {0.f, 0.f, 0.f, 0.f};
    for (int k = kg * 128; k < kg * 128 + 128; ++k) {
        float hk = h[k];
        float4 w = w4[(size_t)k * 128 + wq];
        acc.x += hk * w.x; acc.y += hk * w.y; acc.z += hk * w.z; acc.w += hk * w.w;
    }
    __shared__ float4 red[8][32];
    red[kg][q] = acc;
    __syncthreads();
    if (tid < 32) {
        float4 s = red[0][tid];
#pragma unroll
        for (int gr = 1; gr < 8; ++gr) {
            float4 r = red[gr][tid];
            s.x += r.x; s.y += r.y; s.z += r.z; s.w += r.w;
        }
        int ob = ot * 128 + tid * 4;
        s.x += b1[ob]; s.y += b1[ob + 1]; s.z += b1[ob + 2]; s.w += b1[ob + 3];
        *(float4*)&hp1[b * 512 + ob] = s;
    }
}

// ---------------- kernel 11: out = sigmoid(leaky(bn(hp1)) @ w2 + b2) -------
__global__ __launch_bounds__(64) void k_out(const float* __restrict__ hp1,
                                            const float* __restrict__ mu1,
                                            const float* __restrict__ rstd1,
                                            const float* __restrict__ gam,
                                            const float* __restrict__ bet,
                                            const float* __restrict__ w2,
                                            const float* __restrict__ b2,
                                            float* __restrict__ out) {
    int b = blockIdx.x, lane = threadIdx.x;
    float acc = 0.f;
    for (int o = lane; o < 512; o += 64) {
        float v = hp1[b * 512 + o];
        v = gam[o] * (v - mu1[o]) * rstd1[o] + bet[o];
        v = v >= 0.f ? v : 0.01f * v;
        acc += v * w2[o];
    }
    for (int off = 32; off > 0; off >>= 1) acc += __shfl_down(acc, off);
    if (lane == 0) out[b] = 1.f / (1.f + expf(-(acc + b2[0])));
}

static inline size_t align256(size_t x) { return (x + 255) & ~(size_t)255; }

extern "C" void kernel_launch(void* const* d_in, const int* in_sizes, int n_in,
                              void* d_out, int out_size, void* d_ws, size_t ws_size,
                              hipStream_t stream) {
    const float* x     = (const float*)d_in[0];
    const float* adj   = (const float*)d_in[1];
    const float* w_gc1 = (const float*)d_in[2];
    const float* b_gc1 = (const float*)d_in[3];
    const float* w_gc2 = (const float*)d_in[4];
    const float* b_gc2 = (const float*)d_in[5];
    const float* w_gc3 = (const float*)d_in[6];
    const float* b_gc3 = (const float*)d_in[7];
    const float* w_fc0 = (const float*)d_in[8];
    const float* b_fc0 = (const float*)d_in[9];
    const float* g_fc0 = (const float*)d_in[10];
    const float* be_fc0= (const float*)d_in[11];
    const float* w_fc1 = (const float*)d_in[12];
    const float* b_fc1 = (const float*)d_in[13];
    const float* g_fc1 = (const float*)d_in[14];
    const float* be_fc1= (const float*)d_in[15];
    const float* w_fc2 = (const float*)d_in[16];
    const float* b_fc2 = (const float*)d_in[17];

    char* wsp = (char*)d_ws;
    size_t off = 0;
    auto alloc = [&](size_t bytes) { void* p = wsp + off; off = align256(off + bytes); return p; };
    float* d_deg   = (float*)alloc((size_t)N * 4);
    int*   sid     = (int*)  alloc((size_t)B * 63 * 4);
    int*   sidl    = (int*)  alloc((size_t)B * 4);
    uint4* feA     = (uint4*)alloc((size_t)B * 2 * 64 * 16);
    uint4* wfrag   = (uint4*)alloc((size_t)1024 * 16);
    uint4* w2frag  = (uint4*)alloc((size_t)8192 * 16);
    int*   csr_cnt = (int*)  alloc((size_t)N * 4);
    int*   csr_idx = (int*)  alloc((size_t)N * CAP * 4);
    float* csr_val = (float*)alloc((size_t)N * CAP * 4);
    bf16*  X1      = (bf16*) alloc((size_t)B * N * 256 * 2);
    bf16*  aggG    = (bf16*) alloc((size_t)B * CAP * 256 * 2);
    float* X2      = (float*)alloc((size_t)B * CAP * 256 * 4);
    float* gbuf    = (float*)alloc((size_t)B * 512 * 4);
    float* hp0     = (float*)alloc((size_t)B * 512 * 4);
    float* mu0     = (float*)alloc(512 * 4);
    float* rstd0   = (float*)alloc(512 * 4);
    float* hp1     = (float*)alloc((size_t)B * 512 * 4);
    float* mu1     = (float*)alloc(512 * 4);
    float* rstd1   = (float*)alloc(512 * 4);

    k_rowsum <<<N, 256, 0, stream>>>(adj, d_deg);
    k_csr    <<<N, 64, 0, stream>>>(adj, d_deg, csr_cnt, csr_idx, csr_val);
    k_packw  <<<36, 256, 0, stream>>>(w_gc1, w_gc2, wfrag, w2frag);
    k_extract<<<B, 256, 0, stream>>>(x, d_deg, sid, sidl, feA);
    k_x1     <<<dim3(32, B), 256, 0, stream>>>(adj, d_deg, sid, feA, wfrag, b_gc1, X1);
    k_gather <<<dim3(CAP / JG, B), 256, 0, stream>>>(csr_cnt, csr_idx, csr_val, sidl, X1, aggG);
    k_x2mm   <<<dim3(CAP / JT, B), 256, 0, stream>>>(csr_cnt, sidl, aggG, w2frag, b_gc2, X2);
    k_g      <<<B, 256, 0, stream>>>(csr_cnt, csr_idx, csr_val, sidl, X2, w_gc3, b_gc3, gbuf);
    k_fc0    <<<(B * 512) / 256, 256, 0, stream>>>(x, w_fc0, b_fc0, hp0);
    k_bnstats<<<2, 256, 0, stream>>>(hp0, mu0, rstd0);
    k_fc1    <<<dim3(B, 4), 256, 0, stream>>>(hp0, mu0, rstd0, g_fc0, be_fc0, gbuf, w_fc1, b_fc1, hp1);
    k_bnstats<<<2, 256, 0, stream>>>(hp1, mu1, rstd1);
    k_out    <<<B, 64, 0, stream>>>(hp1, mu1, rstd1, g_fc1, be_fc1, w_fc2, b_fc2, (float*)d_out);
}

// Round 10
// 187.253 us; speedup vs baseline: 1.6725x; 1.1831x over previous
//
#include <hip/hip_runtime.h>
#include <hip/hip_bf16.h>

typedef __hip_bfloat16 bf16;
typedef short s8v __attribute__((ext_vector_type(8)));
typedef float f4v __attribute__((ext_vector_type(4)));

#define B   128
#define N   2000
#define S   64
#define CAP 128          // max neighbors per row (mean ~65, 8-sigma safe)
#define JT  16           // neighbors per block in k_x2mm
#define JG  8            // j-rows per block in k_gather
#define XROW 1088        // S*17

__device__ inline ushort bfb(float v) {
    union { __hip_bfloat16 h; ushort u; } c; c.h = __float2bfloat16(v); return c.u;
}

// ---------------- kernel 1: d[m] = rsqrt(sum(adj[m,:]) + 1) ----------------
__global__ __launch_bounds__(256) void k_rowsum(const float* __restrict__ adj,
                                                float* __restrict__ d) {
    int m = blockIdx.x;
    const float* row = adj + (size_t)m * N;
    float s = 0.f;
    for (int c = threadIdx.x; c < N; c += 256) s += row[c];
    for (int o = 32; o > 0; o >>= 1) s += __shfl_down(s, o);
    __shared__ float red[4];
    int wave = threadIdx.x >> 6;
    if ((threadIdx.x & 63) == 0) red[wave] = s;
    __syncthreads();
    if (threadIdx.x == 0)
        d[m] = rsqrtf(red[0] + red[1] + red[2] + red[3] + 1.0f);
}

// ---------------- kernel 2: CSR of Ahat (ordered ballot compaction) --------
__global__ __launch_bounds__(64) void k_csr(const float* __restrict__ adj,
                                            const float* __restrict__ d,
                                            int* __restrict__ cnt,
                                            int* __restrict__ idx,
                                            float* __restrict__ val) {
    int m = blockIdx.x;
    int lane = threadIdx.x;
    const float* row = adj + (size_t)m * N;
    float dm = d[m];
    int base = 0;
    for (int c0 = 0; c0 < N; c0 += 64) {
        int c = c0 + lane;
        float a = 0.f;
        if (c < N) { a = row[c]; if (c == m) a += 1.0f; }
        bool pred = (a != 0.f);
        unsigned long long mask = __ballot(pred);
        int pos = base + __popcll(mask & ((1ull << lane) - 1ull));
        if (pred && pos < CAP) {
            idx[m * CAP + pos] = c;
            val[m * CAP + pos] = dm * d[c] * a;
        }
        base += (int)__popcll(mask);
    }
    if (lane == 0) cnt[m] = base < CAP ? base : CAP;
}

// ---------------- kernel 3: extract sids / sid_last / pack fe^T A-frags ----
__global__ __launch_bounds__(256) void k_extract(const float* __restrict__ x,
                                                 const float* __restrict__ d,
                                                 int* __restrict__ sid,
                                                 int* __restrict__ sid_last,
                                                 uint4* __restrict__ feA) {
    int b = blockIdx.x, tid = threadIdx.x;
    const float* xb = x + (size_t)b * XROW;
    __shared__ float dss_sh[63];
    __shared__ float fe_sh[64][16];
    if (tid < S - 1) {
        int s_ = (int)xb[tid * 17 + 15];
        sid[b * (S - 1) + tid] = s_;
        dss_sh[tid] = d[s_];
    }
    if (tid == S - 1) sid_last[b] = (int)xb[(S - 1) * 17 + 15];
    if (tid >= 240 && tid < 256) fe_sh[63][tid - 240] = 0.f;   // zero pad row
    __syncthreads();
    for (int i = tid; i < (S - 1) * 16; i += 256) {
        int t = i >> 4, f = i & 15;
        fe_sh[t][f] = dss_sh[t] * xb[t * 17 + (f < 15 ? f : 16)];
    }
    __syncthreads();
    if (tid < 128) {
        int kc = tid >> 6, l = tid & 63;
        int f = l & 15, tg = l >> 4;
        ushort h[8];
#pragma unroll
        for (int j = 0; j < 8; ++j)
            h[j] = bfb(fe_sh[kc * 32 + tg * 8 + j][f]);
        uint4 r;
        r.x = h[0] | ((uint)h[1] << 16);
        r.y = h[2] | ((uint)h[3] << 16);
        r.z = h[4] | ((uint)h[5] << 16);
        r.w = h[6] | ((uint)h[7] << 16);
        feA[(b * 2 + kc) * 64 + l] = r;
    }
}

// ---------------- kernel 3bc: pack W1^T and W2 MFMA fragments --------------
__global__ __launch_bounds__(256) void k_packw(const float* __restrict__ w1,
                                               const float* __restrict__ w2,
                                               uint4* __restrict__ wf1,
                                               uint4* __restrict__ wf2) {
    int blk = blockIdx.x;
    if (blk < 4) {
        int e = blk * 256 + threadIdx.x;          // 0..1023
        int ct = e >> 6, l = e & 63;
        int kg = l >> 4, ch = ct * 16 + (l & 15);
        ushort h[8];
#pragma unroll
        for (int j = 0; j < 8; ++j) {
            int f = kg * 8 + j;
            h[j] = (f < 16) ? bfb(w1[f * 256 + ch]) : (ushort)0;
        }
        uint4 r;
        r.x = h[0] | ((uint)h[1] << 16);
        r.y = h[2] | ((uint)h[3] << 16);
        r.z = h[4] | ((uint)h[5] << 16);
        r.w = h[6] | ((uint)h[7] << 16);
        wf1[e] = r;
    } else {
        int e = (blk - 4) * 256 + threadIdx.x;    // 0..8191
        int l = e & 63;
        int kc = (e >> 6) & 7;
        int nt = e >> 9;
        int col = l & 15, kg = l >> 4;
        ushort h[8];
#pragma unroll
        for (int i = 0; i < 8; ++i) {
            int k = kc * 32 + kg * 8 + i;
            h[i] = bfb(w2[k * 256 + nt * 16 + col]);
        }
        uint4 r;
        r.x = h[0] | ((uint)h[1] << 16);
        r.y = h[2] | ((uint)h[3] << 16);
        r.z = h[4] | ((uint)h[5] << 16);
        r.w = h[6] | ((uint)h[7] << 16);
        wf2[e] = r;
    }
}

// ---------------- kernel 4: X1[b,p,:] = relu((Ahat X)[b,p] @ w1 + b1) ------
__global__ __launch_bounds__(256) void k_x1(const float* __restrict__ adj,
                                            const float* __restrict__ d,
                                            const int* __restrict__ sid,
                                            const uint4* __restrict__ feA,
                                            const uint4* __restrict__ wfrag,
                                            const float* __restrict__ b1,
                                            bf16* __restrict__ X1) {
    __shared__ int sv[64];
    __shared__ __align__(16) ushort Ylds[64][40];   // 80B rows
    __shared__ float b1s[256];
    int b = blockIdx.y, p0 = blockIdx.x * 64, tid = threadIdx.x;
    b1s[tid] = b1[tid];
    if (tid < 63) sv[tid] = sid[b * 63 + tid];
    if (tid == 63) sv[63] = 0;
    __syncthreads();

    int l = tid & 63, wv = tid >> 6;
    int lm = l & 15, lg = l >> 4;
    int pt = p0 + wv * 16;
    int pcol = pt + lm;
    bool pv = (pcol < N);
    int pc = pv ? pcol : 0;

    s8v a1_0 = *(const s8v*)&feA[(b * 2 + 0) * 64 + l];
    s8v a1_1 = *(const s8v*)&feA[(b * 2 + 1) * 64 + l];

    int ss[16];
#pragma unroll
    for (int q = 0; q < 16; ++q)
        ss[q] = sv[(q >> 3) * 32 + lg * 8 + (q & 7)];
    float av[16];
#pragma unroll
    for (int q = 0; q < 16; ++q)
        av[q] = adj[(size_t)ss[q] * N + pc];
#pragma unroll
    for (int q = 0; q < 16; ++q) {
        av[q] = pv ? av[q] : 0.f;
        if (pcol == ss[q]) av[q] += 1.0f;
    }
    ushort h[16];
#pragma unroll
    for (int q = 0; q < 16; ++q) h[q] = bfb(av[q]);
    s8v b1f, b2f;
    {
        uint4 t0, t1;
        t0.x = h[0] | ((uint)h[1] << 16);  t0.y = h[2] | ((uint)h[3] << 16);
        t0.z = h[4] | ((uint)h[5] << 16);  t0.w = h[6] | ((uint)h[7] << 16);
        t1.x = h[8] | ((uint)h[9] << 16);  t1.y = h[10] | ((uint)h[11] << 16);
        t1.z = h[12] | ((uint)h[13] << 16); t1.w = h[14] | ((uint)h[15] << 16);
        b1f = *(s8v*)&t0; b2f = *(s8v*)&t1;
    }
    f4v D1 = (f4v){0.f, 0.f, 0.f, 0.f};
    D1 = __builtin_amdgcn_mfma_f32_16x16x32_bf16(a1_0, b1f, D1, 0, 0, 0);
    D1 = __builtin_amdgcn_mfma_f32_16x16x32_bf16(a1_1, b2f, D1, 0, 0, 0);
    float dp = d[pc] * (pv ? 1.f : 0.f);
    uint2 pk;
    pk.x = bfb(D1[0] * dp) | ((uint)bfb(D1[1] * dp) << 16);
    pk.y = bfb(D1[2] * dp) | ((uint)bfb(D1[3] * dp) << 16);
    *(uint2*)&Ylds[wv * 16 + lm][lg * 4] = pk;
    *(uint2*)&Ylds[wv * 16 + lm][16 + lg * 4] = make_uint2(0u, 0u);  // K-pad
    __syncthreads();

    s8v yf = *(const s8v*)&Ylds[wv * 16 + lm][lg * 8];      // B = Y^T frag
    f4v acc2[16];
#pragma unroll
    for (int ct = 0; ct < 16; ++ct) acc2[ct] = (f4v){0.f, 0.f, 0.f, 0.f};
#pragma unroll
    for (int ct = 0; ct < 16; ++ct) {
        s8v wfv = *(const s8v*)&wfrag[ct * 64 + l];         // A = W^T frag
        acc2[ct] = __builtin_amdgcn_mfma_f32_16x16x32_bf16(wfv, yf, acc2[ct], 0, 0, 0);
    }
    int pp = p0 + wv * 16 + lm;
    if (pp < N) {
        uint2* dst = (uint2*)X1 + ((size_t)b * N + pp) * 64;
#pragma unroll
        for (int ct = 0; ct < 16; ++ct) {
            float4 bz = *(float4*)&b1s[ct * 16 + lg * 4];
            float v0 = acc2[ct][0] + bz.x; v0 = v0 > 0.f ? v0 : 0.f;
            float v1 = acc2[ct][1] + bz.y; v1 = v1 > 0.f ? v1 : 0.f;
            float v2 = acc2[ct][2] + bz.z; v2 = v2 > 0.f ? v2 : 0.f;
            float v3 = acc2[ct][3] + bz.w; v3 = v3 > 0.f ? v3 : 0.f;
            uint2 pko;
            pko.x = bfb(v0) | ((uint)bfb(v1) << 16);
            pko.y = bfb(v2) | ((uint)bfb(v3) << 16);
            dst[ct * 4 + lg] = pko;
        }
    }
}

// ---------------- kernel 5a: k_gather — agg[b,j,:] = sum_k val*X1[b,idx,:] --
__global__ __launch_bounds__(256) void k_gather(const int* __restrict__ cnt,
                                                const int* __restrict__ idxA,
                                                const float* __restrict__ valA,
                                                const int* __restrict__ sid_last,
                                                const bf16* __restrict__ X1,
                                                bf16* __restrict__ aggG) {
    __shared__ int   nns[JG];
    __shared__ int   ncn_s[JG];
    __shared__ int   nidx[JG][CAP];
    __shared__ float nval[JG][CAP];
    int b = blockIdx.y, j0 = blockIdx.x * JG, tid = threadIdx.x;
    int m = sid_last[b];
    int cj = cnt[m];
    if (tid < JG) {
        int j = j0 + tid;
        int n = idxA[m * CAP + (j < cj ? j : 0)];
        nns[tid] = n;
        ncn_s[tid] = (j < cj) ? cnt[n] : 0;
    }
    __syncthreads();
    for (int i = tid; i < JG * CAP; i += 256) {
        int jj = i >> 7, k = i & (CAP - 1);
        int n = nns[jj], c = ncn_s[jj];
        nidx[jj][k] = (k < c) ? idxA[n * CAP + k] : 0;
        nval[jj][k] = (k < c) ? valA[n * CAP + k] : 0.f;
    }
    __syncthreads();
    int lane = tid & 63;
    int w = __builtin_amdgcn_readfirstlane(tid >> 6);
    int la = w * 2, lb = la + 1;
    const uint2* X1bl = (const uint2*)X1 + (size_t)b * N * 64 + lane;
    int cA = ncn_s[la], cB = ncn_s[lb];
    int cmax = cA > cB ? cA : cB;
    float aA0 = 0.f, aA1 = 0.f, aA2 = 0.f, aA3 = 0.f;
    float aB0 = 0.f, aB1 = 0.f, aB2 = 0.f, aB3 = 0.f;
    if (cmax > 0) {
        uint2 uA = X1bl[(size_t)nidx[la][0] * 64]; float vA = nval[la][0];
        uint2 uB = X1bl[(size_t)nidx[lb][0] * 64]; float vB = nval[lb][0];
        for (int k = 0; k < cmax; ++k) {
            uint2 cuA = uA, cuB = uB;
            float cvA = vA, cvB = vB;
            int kn = (k + 1 < CAP) ? k + 1 : CAP - 1;
            uA = X1bl[(size_t)nidx[la][kn] * 64]; vA = nval[la][kn];
            uB = X1bl[(size_t)nidx[lb][kn] * 64]; vB = nval[lb][kn];
            aA0 += cvA * __uint_as_float(cuA.x << 16);
            aA1 += cvA * __uint_as_float(cuA.x & 0xffff0000u);
            aA2 += cvA * __uint_as_float(cuA.y << 16);
            aA3 += cvA * __uint_as_float(cuA.y & 0xffff0000u);
            aB0 += cvB * __uint_as_float(cuB.x << 16);
            aB1 += cvB * __uint_as_float(cuB.x & 0xffff0000u);
            aB2 += cvB * __uint_as_float(cuB.y << 16);
            aB3 += cvB * __uint_as_float(cuB.y & 0xffff0000u);
        }
    }
    uint2 pkA, pkB;
    pkA.x = bfb(aA0) | ((uint)bfb(aA1) << 16);
    pkA.y = bfb(aA2) | ((uint)bfb(aA3) << 16);
    pkB.x = bfb(aB0) | ((uint)bfb(aB1) << 16);
    pkB.y = bfb(aB2) | ((uint)bfb(aB3) << 16);
    uint2* ag = (uint2*)aggG;
    ag[((size_t)b * CAP + j0 + la) * 64 + lane] = pkA;
    ag[((size_t)b * CAP + j0 + lb) * 64 + lane] = pkB;
}

// ---------------- kernel 5b: k_x2mm — X2 = relu(agg @ w2 + b2) (MFMA) ------
__global__ __launch_bounds__(256) void k_x2mm(const int* __restrict__ cnt,
                                              const int* __restrict__ sid_last,
                                              const bf16* __restrict__ aggG,
                                              const uint4* __restrict__ w2f,
                                              const float* __restrict__ b2,
                                              float* __restrict__ X2) {
    __shared__ ushort agg[JT][264];   // 528B row stride
    int b = blockIdx.y, j0 = blockIdx.x * JT, tid = threadIdx.x;
    int m = sid_last[b];
    int cj = cnt[m];
    if (j0 >= cj) return;
    int nj = cj - j0; if (nj > JT) nj = JT;
    {
        const uint4* src = (const uint4*)(aggG + ((size_t)b * CAP + j0) * 256);
        for (int i = tid; i < 512; i += 256) {
            int row = i >> 5, col = i & 31;
            *(uint4*)&agg[row][col * 8] = src[i];
        }
    }
    __syncthreads();
    int lane = tid & 63;
    int w = __builtin_amdgcn_readfirstlane(tid >> 6);
    int col = lane & 15, rg = lane >> 4;
    s8v af[8];
#pragma unroll
    for (int kc = 0; kc < 8; ++kc)
        af[kc] = *(const s8v*)&agg[col][kc * 32 + rg * 8];
#pragma unroll
    for (int t = 0; t < 4; ++t) {
        int nt = w * 4 + t;
        f4v acc = (f4v){0.f, 0.f, 0.f, 0.f};
#pragma unroll
        for (int kc = 0; kc < 8; ++kc) {
            s8v bf = *(const s8v*)&w2f[(nt * 8 + kc) * 64 + lane];
            acc = __builtin_amdgcn_mfma_f32_16x16x32_bf16(af[kc], bf, acc, 0, 0, 0);
        }
        float bv = b2[nt * 16 + col];
        float* dst = X2 + ((size_t)b * CAP + j0) * 256 + nt * 16 + col;
#pragma unroll
        for (int i = 0; i < 4; ++i) {
            int row = rg * 4 + i;
            if (row < nj) {
                float vv = acc[i] + bv;
                dst[(size_t)row * 256] = vv > 0.f ? vv : 0.f;
            }
        }
    }
}

// ---------------- kernel 6a: k_gagg — agg1[b,:] = sum_j val*X2[b,j,:] ------
__global__ __launch_bounds__(256) void k_gagg(const int* __restrict__ cnt,
                                              const float* __restrict__ valA,
                                              const int* __restrict__ sid_last,
                                              const float* __restrict__ X2,
                                              float* __restrict__ gagg) {
    int b = blockIdx.x, tid = threadIdx.x;
    int m = sid_last[b];
    int cj = cnt[m];
    const float* vp = valA + m * CAP;
    const float* xp = X2 + (size_t)b * CAP * 256 + tid;
    float a0 = 0.f, a1 = 0.f, a2 = 0.f, a3 = 0.f;
    int jj = 0;
    for (; jj + 4 <= cj; jj += 4) {
        a0 += vp[jj]     * xp[(size_t)(jj)     * 256];
        a1 += vp[jj + 1] * xp[(size_t)(jj + 1) * 256];
        a2 += vp[jj + 2] * xp[(size_t)(jj + 2) * 256];
        a3 += vp[jj + 3] * xp[(size_t)(jj + 3) * 256];
    }
    for (; jj < cj; ++jj) a0 += vp[jj] * xp[(size_t)jj * 256];
    gagg[b * 256 + tid] = (a0 + a1) + (a2 + a3);
}

// ---------------- kernel 6b: k_gmm — g = relu(gagg @ w3 + b3) --------------
// grid (B, 4): 128 outputs/block, 8-way K-split, float4 w3 loads + LDS reduce
__global__ __launch_bounds__(256) void k_gmm(const float* __restrict__ gagg,
                                             const float* __restrict__ w3,
                                             const float* __restrict__ b3,
                                             float* __restrict__ g) {
    int b = blockIdx.x, ot = blockIdx.y, tid = threadIdx.x;
    __shared__ float h[256];
    h[tid] = gagg[b * 256 + tid];
    __syncthreads();
    int q  = tid & 31;       // output quad
    int kg = tid >> 5;       // 0..7, K-group of 32
    const float4* w4 = (const float4*)w3;     // 128 quads per k-row
    int wq = ot * 32 + q;
    float4 acc = {0.f, 0.f, 0.f, 0.f};
    for (int k = kg * 32; k < kg * 32 + 32; ++k) {
        float hk = h[k];
        float4 w = w4[(size_t)k * 128 + wq];
        acc.x += hk * w.x; acc.y += hk * w.y; acc.z += hk * w.z; acc.w += hk * w.w;
    }
    __shared__ float4 red[8][32];
    red[kg][q] = acc;
    __syncthreads();
    if (tid < 32) {
        float4 s = red[0][tid];
#pragma unroll
        for (int gr = 1; gr < 8; ++gr) {
            float4 r = red[gr][tid];
            s.x += r.x; s.y += r.y; s.z += r.z; s.w += r.w;
        }
        int ob = ot * 128 + tid * 4;
        s.x += b3[ob];     s.x = s.x > 0.f ? s.x : 0.f;
        s.y += b3[ob + 1]; s.y = s.y > 0.f ? s.y : 0.f;
        s.z += b3[ob + 2]; s.z = s.z > 0.f ? s.z : 0.f;
        s.w += b3[ob + 3]; s.w = s.w > 0.f ? s.w : 0.f;
        *(float4*)&g[(size_t)b * 512 + ob] = s;
    }
}

// ---------------- kernel 7: hp0 = x_last[:, :15] @ w0 + b0 -----------------
__global__ __launch_bounds__(256) void k_fc0(const float* __restrict__ x,
                                             const float* __restrict__ w0,
                                             const float* __restrict__ b0,
                                             float* __restrict__ hp0) {
    int i = blockIdx.x * 256 + threadIdx.x;
    int b = i >> 9, o = i & 511;
    const float* xr = x + (size_t)b * XROW + (S - 1) * 17;
    float acc = b0[o];
#pragma unroll
    for (int f = 0; f < 15; ++f) acc += xr[f] * w0[f * 512 + o];
    hp0[i] = acc;
}

// ---------------- kernel 8/10: batch-norm stats (biased var) ---------------
__global__ __launch_bounds__(256) void k_bnstats(const float* __restrict__ h,
                                                 float* __restrict__ mu,
                                                 float* __restrict__ rstd) {
    int o = blockIdx.x * 256 + threadIdx.x;
    float s = 0.f, s2 = 0.f;
    for (int b = 0; b < B; ++b) { float v = h[b * 512 + o]; s += v; s2 += v * v; }
    float m = s * (1.f / B);
    float var = s2 * (1.f / B) - m * m;
    mu[o] = m;
    rstd[o] = rsqrtf(var + 1e-5f);
}

// ---------------- kernel 9: hp1 = [leaky(bn(hp0)), g] @ w1 + b1 ------------
__global__ __launch_bounds__(256) void k_fc1(const float* __restrict__ hp0,
                                             const float* __restrict__ mu0,
                                             const float* __restrict__ rstd0,
                                             const float* __restrict__ gam,
                                             const float* __restrict__ bet,
                                             const float* __restrict__ gbuf,
                                             const float* __restrict__ w1,
                                             const float* __restrict__ b1,
                                             float* __restrict__ hp1) {
    int b = blockIdx.x, ot = blockIdx.y, tid = threadIdx.x;
    __shared__ float h[1024];
    for (int o = tid; o < 512; o += 256) {
        float v = hp0[b * 512 + o];
        v = gam[o] * (v - mu0[o]) * rstd0[o] + bet[o];
        h[o] = v >= 0.f ? v : 0.01f * v;
        h[512 + o] = gbuf[(size_t)b * 512 + o];
    }
    __syncthreads();
    int q  = tid & 31;
    int kg = tid >> 5;
    const float4* w4 = (const float4*)w1;
    int wq = ot * 32 + q;
    float4 acc = {0.f, 0.f, 0.f, 0.f};
    for (int k = kg * 128; k < kg * 128 + 128; ++k) {
        float hk = h[k];
        float4 w = w4[(size_t)k * 128 + wq];
        acc.x += hk * w.x; acc.y += hk * w.y; acc.z += hk * w.z; acc.w += hk * w.w;
    }
    __shared__ float4 red[8][32];
    red[kg][q] = acc;
    __syncthreads();
    if (tid < 32) {
        float4 s = red[0][tid];
#pragma unroll
        for (int gr = 1; gr < 8; ++gr) {
            float4 r = red[gr][tid];
            s.x += r.x; s.y += r.y; s.z += r.z; s.w += r.w;
        }
        int ob = ot * 128 + tid * 4;
        s.x += b1[ob]; s.y += b1[ob + 1]; s.z += b1[ob + 2]; s.w += b1[ob + 3];
        *(float4*)&hp1[b * 512 + ob] = s;
    }
}

// ---------------- kernel 11: out = sigmoid(leaky(bn(hp1)) @ w2 + b2) -------
__global__ __launch_bounds__(64) void k_out(const float* __restrict__ hp1,
                                            const float* __restrict__ mu1,
                                            const float* __restrict__ rstd1,
                                            const float* __restrict__ gam,
                                            const float* __restrict__ bet,
                                            const float* __restrict__ w2,
                                            const float* __restrict__ b2,
                                            float* __restrict__ out) {
    int b = blockIdx.x, lane = threadIdx.x;
    float acc = 0.f;
    for (int o = lane; o < 512; o += 64) {
        float v = hp1[b * 512 + o];
        v = gam[o] * (v - mu1[o]) * rstd1[o] + bet[o];
        v = v >= 0.f ? v : 0.01f * v;
        acc += v * w2[o];
    }
    for (int off = 32; off > 0; off >>= 1) acc += __shfl_down(acc, off);
    if (lane == 0) out[b] = 1.f / (1.f + expf(-(acc + b2[0])));
}

static inline size_t align256(size_t x) { return (x + 255) & ~(size_t)255; }

extern "C" void kernel_launch(void* const* d_in, const int* in_sizes, int n_in,
                              void* d_out, int out_size, void* d_ws, size_t ws_size,
                              hipStream_t stream) {
    const float* x     = (const float*)d_in[0];
    const float* adj   = (const float*)d_in[1];
    const float* w_gc1 = (const float*)d_in[2];
    const float* b_gc1 = (const float*)d_in[3];
    const float* w_gc2 = (const float*)d_in[4];
    const float* b_gc2 = (const float*)d_in[5];
    const float* w_gc3 = (const float*)d_in[6];
    const float* b_gc3 = (const float*)d_in[7];
    const float* w_fc0 = (const float*)d_in[8];
    const float* b_fc0 = (const float*)d_in[9];
    const float* g_fc0 = (const float*)d_in[10];
    const float* be_fc0= (const float*)d_in[11];
    const float* w_fc1 = (const float*)d_in[12];
    const float* b_fc1 = (const float*)d_in[13];
    const float* g_fc1 = (const float*)d_in[14];
    const float* be_fc1= (const float*)d_in[15];
    const float* w_fc2 = (const float*)d_in[16];
    const float* b_fc2 = (const float*)d_in[17];

    char* wsp = (char*)d_ws;
    size_t off = 0;
    auto alloc = [&](size_t bytes) { void* p = wsp + off; off = align256(off + bytes); return p; };
    float* d_deg   = (float*)alloc((size_t)N * 4);
    int*   sid     = (int*)  alloc((size_t)B * 63 * 4);
    int*   sidl    = (int*)  alloc((size_t)B * 4);
    uint4* feA     = (uint4*)alloc((size_t)B * 2 * 64 * 16);
    uint4* wfrag   = (uint4*)alloc((size_t)1024 * 16);
    uint4* w2frag  = (uint4*)alloc((size_t)8192 * 16);
    int*   csr_cnt = (int*)  alloc((size_t)N * 4);
    int*   csr_idx = (int*)  alloc((size_t)N * CAP * 4);
    float* csr_val = (float*)alloc((size_t)N * CAP * 4);
    bf16*  X1      = (bf16*) alloc((size_t)B * N * 256 * 2);
    bf16*  aggG    = (bf16*) alloc((size_t)B * CAP * 256 * 2);
    float* X2      = (float*)alloc((size_t)B * CAP * 256 * 4);
    float* gagg    = (float*)alloc((size_t)B * 256 * 4);
    float* gbuf    = (float*)alloc((size_t)B * 512 * 4);
    float* hp0     = (float*)alloc((size_t)B * 512 * 4);
    float* mu0     = (float*)alloc(512 * 4);
    float* rstd0   = (float*)alloc(512 * 4);
    float* hp1     = (float*)alloc((size_t)B * 512 * 4);
    float* mu1     = (float*)alloc(512 * 4);
    float* rstd1   = (float*)alloc(512 * 4);

    k_rowsum <<<N, 256, 0, stream>>>(adj, d_deg);
    k_csr    <<<N, 64, 0, stream>>>(adj, d_deg, csr_cnt, csr_idx, csr_val);
    k_packw  <<<36, 256, 0, stream>>>(w_gc1, w_gc2, wfrag, w2frag);
    k_extract<<<B, 256, 0, stream>>>(x, d_deg, sid, sidl, feA);
    k_x1     <<<dim3(32, B), 256, 0, stream>>>(adj, d_deg, sid, feA, wfrag, b_gc1, X1);
    k_gather <<<dim3(CAP / JG, B), 256, 0, stream>>>(csr_cnt, csr_idx, csr_val, sidl, X1, aggG);
    k_x2mm   <<<dim3(CAP / JT, B), 256, 0, stream>>>(csr_cnt, sidl, aggG, w2frag, b_gc2, X2);
    k_gagg   <<<B, 256, 0, stream>>>(csr_cnt, csr_val, sidl, X2, gagg);
    k_gmm    <<<dim3(B, 4), 256, 0, stream>>>(gagg, w_gc3, b_gc3, gbuf);
    k_fc0    <<<(B * 512) / 256, 256, 0, stream>>>(x, w_fc0, b_fc0, hp0);
    k_bnstats<<<2, 256, 0, stream>>>(hp0, mu0, rstd0);
    k_fc1    <<<dim3(B, 4), 256, 0, stream>>>(hp0, mu0, rstd0, g_fc0, be_fc0, gbuf, w_fc1, b_fc1, hp1);
    k_bnstats<<<2, 256, 0, stream>>>(hp1, mu1, rstd1);
    k_out    <<<B, 64, 0, stream>>>(hp1, mu1, rstd1, g_fc1, be_fc1, w_fc2, b_fc2, (float*)d_out);
}

// Round 11
// 164.111 us; speedup vs baseline: 1.9084x; 1.1410x over previous
//
#include <hip/hip_runtime.h>
#include <hip/hip_bf16.h>

typedef __hip_bfloat16 bf16;
typedef short s8v __attribute__((ext_vector_type(8)));
typedef float f4v __attribute__((ext_vector_type(4)));
typedef float f2v __attribute__((ext_vector_type(2)));

#define B   128
#define N   2000
#define S   64
#define CAP 128          // max neighbors per row (mean ~65, 8-sigma safe)
#define JT  16           // neighbors per block in k_x2mm
#define JG  8            // j-rows per block in k_gather
#define XROW 1088        // S*17

__device__ inline ushort bfb(float v) {
    union { __hip_bfloat16 h; ushort u; } c; c.h = __float2bfloat16(v); return c.u;
}

// ---------------- kernel 1: d[m] = rsqrt(sum(adj[m,:]) + 1) ----------------
__global__ __launch_bounds__(256) void k_rowsum(const float* __restrict__ adj,
                                                float* __restrict__ d) {
    int m = blockIdx.x;
    const float* row = adj + (size_t)m * N;
    float s = 0.f;
    for (int c = threadIdx.x; c < N; c += 256) s += row[c];
    for (int o = 32; o > 0; o >>= 1) s += __shfl_down(s, o);
    __shared__ float red[4];
    int wave = threadIdx.x >> 6;
    if ((threadIdx.x & 63) == 0) red[wave] = s;
    __syncthreads();
    if (threadIdx.x == 0)
        d[m] = rsqrtf(red[0] + red[1] + red[2] + red[3] + 1.0f);
}

// ---------------- kernel 2: CSR of Ahat (ordered ballot compaction) --------
__global__ __launch_bounds__(64) void k_csr(const float* __restrict__ adj,
                                            const float* __restrict__ d,
                                            int* __restrict__ cnt,
                                            int* __restrict__ idx,
                                            float* __restrict__ val) {
    int m = blockIdx.x;
    int lane = threadIdx.x;
    const float* row = adj + (size_t)m * N;
    float dm = d[m];
    int base = 0;
    for (int c0 = 0; c0 < N; c0 += 64) {
        int c = c0 + lane;
        float a = 0.f;
        if (c < N) { a = row[c]; if (c == m) a += 1.0f; }
        bool pred = (a != 0.f);
        unsigned long long mask = __ballot(pred);
        int pos = base + __popcll(mask & ((1ull << lane) - 1ull));
        if (pred && pos < CAP) {
            idx[m * CAP + pos] = c;
            val[m * CAP + pos] = dm * d[c] * a;
        }
        base += (int)__popcll(mask);
    }
    if (lane == 0) cnt[m] = base < CAP ? base : CAP;
}

// ---------------- kernel 3: extract sids / sid_last / pack fe^T A-frags ----
__global__ __launch_bounds__(256) void k_extract(const float* __restrict__ x,
                                                 const float* __restrict__ d,
                                                 int* __restrict__ sid,
                                                 int* __restrict__ sid_last,
                                                 uint4* __restrict__ feA) {
    int b = blockIdx.x, tid = threadIdx.x;
    const float* xb = x + (size_t)b * XROW;
    __shared__ float dss_sh[63];
    __shared__ float fe_sh[64][16];
    if (tid < S - 1) {
        int s_ = (int)xb[tid * 17 + 15];
        sid[b * (S - 1) + tid] = s_;
        dss_sh[tid] = d[s_];
    }
    if (tid == S - 1) sid_last[b] = (int)xb[(S - 1) * 17 + 15];
    if (tid >= 240 && tid < 256) fe_sh[63][tid - 240] = 0.f;   // zero pad row
    __syncthreads();
    for (int i = tid; i < (S - 1) * 16; i += 256) {
        int t = i >> 4, f = i & 15;
        fe_sh[t][f] = dss_sh[t] * xb[t * 17 + (f < 15 ? f : 16)];
    }
    __syncthreads();
    if (tid < 128) {
        int kc = tid >> 6, l = tid & 63;
        int f = l & 15, tg = l >> 4;
        ushort h[8];
#pragma unroll
        for (int j = 0; j < 8; ++j)
            h[j] = bfb(fe_sh[kc * 32 + tg * 8 + j][f]);
        uint4 r;
        r.x = h[0] | ((uint)h[1] << 16);
        r.y = h[2] | ((uint)h[3] << 16);
        r.z = h[4] | ((uint)h[5] << 16);
        r.w = h[6] | ((uint)h[7] << 16);
        feA[(b * 2 + kc) * 64 + l] = r;
    }
}

// ---------------- kernel 3bc: pack W1^T and W2 MFMA fragments --------------
__global__ __launch_bounds__(256) void k_packw(const float* __restrict__ w1,
                                               const float* __restrict__ w2,
                                               uint4* __restrict__ wf1,
                                               uint4* __restrict__ wf2) {
    int blk = blockIdx.x;
    if (blk < 4) {
        int e = blk * 256 + threadIdx.x;          // 0..1023
        int ct = e >> 6, l = e & 63;
        int kg = l >> 4, ch = ct * 16 + (l & 15);
        ushort h[8];
#pragma unroll
        for (int j = 0; j < 8; ++j) {
            int f = kg * 8 + j;
            h[j] = (f < 16) ? bfb(w1[f * 256 + ch]) : (ushort)0;
        }
        uint4 r;
        r.x = h[0] | ((uint)h[1] << 16);
        r.y = h[2] | ((uint)h[3] << 16);
        r.z = h[4] | ((uint)h[5] << 16);
        r.w = h[6] | ((uint)h[7] << 16);
        wf1[e] = r;
    } else {
        int e = (blk - 4) * 256 + threadIdx.x;    // 0..8191
        int l = e & 63;
        int kc = (e >> 6) & 7;
        int nt = e >> 9;
        int col = l & 15, kg = l >> 4;
        ushort h[8];
#pragma unroll
        for (int i = 0; i < 8; ++i) {
            int k = kc * 32 + kg * 8 + i;
            h[i] = bfb(w2[k * 256 + nt * 16 + col]);
        }
        uint4 r;
        r.x = h[0] | ((uint)h[1] << 16);
        r.y = h[2] | ((uint)h[3] << 16);
        r.z = h[4] | ((uint)h[5] << 16);
        r.w = h[6] | ((uint)h[7] << 16);
        wf2[e] = r;
    }
}

// ---------------- kernel 4: X1[b,p,:] = relu((Ahat X)[b,p] @ w1 + b1) ------
// X1 stored as fp8 e4m3 (halves write traffic + downstream gather reads)
__global__ __launch_bounds__(256) void k_x1(const float* __restrict__ adj,
                                            const float* __restrict__ d,
                                            const int* __restrict__ sid,
                                            const uint4* __restrict__ feA,
                                            const uint4* __restrict__ wfrag,
                                            const float* __restrict__ b1,
                                            unsigned char* __restrict__ X1) {
    __shared__ int sv[64];
    __shared__ __align__(16) ushort Ylds[64][40];   // 80B rows
    __shared__ float b1s[256];
    int b = blockIdx.y, p0 = blockIdx.x * 64, tid = threadIdx.x;
    b1s[tid] = b1[tid];
    if (tid < 63) sv[tid] = sid[b * 63 + tid];
    if (tid == 63) sv[63] = 0;
    __syncthreads();

    int l = tid & 63, wv = tid >> 6;
    int lm = l & 15, lg = l >> 4;
    int pt = p0 + wv * 16;
    int pcol = pt + lm;
    bool pv = (pcol < N);
    int pc = pv ? pcol : 0;

    s8v a1_0 = *(const s8v*)&feA[(b * 2 + 0) * 64 + l];
    s8v a1_1 = *(const s8v*)&feA[(b * 2 + 1) * 64 + l];

    int ss[16];
#pragma unroll
    for (int q = 0; q < 16; ++q)
        ss[q] = sv[(q >> 3) * 32 + lg * 8 + (q & 7)];
    float av[16];
#pragma unroll
    for (int q = 0; q < 16; ++q)
        av[q] = adj[(size_t)ss[q] * N + pc];
#pragma unroll
    for (int q = 0; q < 16; ++q) {
        av[q] = pv ? av[q] : 0.f;
        if (pcol == ss[q]) av[q] += 1.0f;
    }
    ushort h[16];
#pragma unroll
    for (int q = 0; q < 16; ++q) h[q] = bfb(av[q]);
    s8v b1f, b2f;
    {
        uint4 t0, t1;
        t0.x = h[0] | ((uint)h[1] << 16);  t0.y = h[2] | ((uint)h[3] << 16);
        t0.z = h[4] | ((uint)h[5] << 16);  t0.w = h[6] | ((uint)h[7] << 16);
        t1.x = h[8] | ((uint)h[9] << 16);  t1.y = h[10] | ((uint)h[11] << 16);
        t1.z = h[12] | ((uint)h[13] << 16); t1.w = h[14] | ((uint)h[15] << 16);
        b1f = *(s8v*)&t0; b2f = *(s8v*)&t1;
    }
    f4v D1 = (f4v){0.f, 0.f, 0.f, 0.f};
    D1 = __builtin_amdgcn_mfma_f32_16x16x32_bf16(a1_0, b1f, D1, 0, 0, 0);
    D1 = __builtin_amdgcn_mfma_f32_16x16x32_bf16(a1_1, b2f, D1, 0, 0, 0);
    float dp = d[pc] * (pv ? 1.f : 0.f);
    uint2 pk;
    pk.x = bfb(D1[0] * dp) | ((uint)bfb(D1[1] * dp) << 16);
    pk.y = bfb(D1[2] * dp) | ((uint)bfb(D1[3] * dp) << 16);
    *(uint2*)&Ylds[wv * 16 + lm][lg * 4] = pk;
    *(uint2*)&Ylds[wv * 16 + lm][16 + lg * 4] = make_uint2(0u, 0u);  // K-pad
    __syncthreads();

    s8v yf = *(const s8v*)&Ylds[wv * 16 + lm][lg * 8];      // B = Y^T frag
    f4v acc2[16];
#pragma unroll
    for (int ct = 0; ct < 16; ++ct) acc2[ct] = (f4v){0.f, 0.f, 0.f, 0.f};
#pragma unroll
    for (int ct = 0; ct < 16; ++ct) {
        s8v wfv = *(const s8v*)&wfrag[ct * 64 + l];         // A = W^T frag
        acc2[ct] = __builtin_amdgcn_mfma_f32_16x16x32_bf16(wfv, yf, acc2[ct], 0, 0, 0);
    }
    int pp = p0 + wv * 16 + lm;
    if (pp < N) {
        uint* dst = (uint*)X1 + ((size_t)b * N + pp) * 64;
#pragma unroll
        for (int ct = 0; ct < 16; ++ct) {
            float4 bz = *(float4*)&b1s[ct * 16 + lg * 4];
            float v0 = acc2[ct][0] + bz.x; v0 = v0 > 0.f ? v0 : 0.f;
            float v1 = acc2[ct][1] + bz.y; v1 = v1 > 0.f ? v1 : 0.f;
            float v2 = acc2[ct][2] + bz.z; v2 = v2 > 0.f ? v2 : 0.f;
            float v3 = acc2[ct][3] + bz.w; v3 = v3 > 0.f ? v3 : 0.f;
            uint pk8 = (uint)__builtin_amdgcn_cvt_pk_fp8_f32(v0, v1, 0, false);
            pk8 = (uint)__builtin_amdgcn_cvt_pk_fp8_f32(v2, v3, (int)pk8, true);
            dst[ct * 4 + lg] = pk8;
        }
    }
}

// ---------------- kernel 5a: k_gather — agg[b,j,:] = sum_k val*X1[b,idx,:] --
// X1 is fp8: 256 B/row, unpacked via v_cvt_pk_f32_fp8
__global__ __launch_bounds__(256) void k_gather(const int* __restrict__ cnt,
                                                const int* __restrict__ idxA,
                                                const float* __restrict__ valA,
                                                const int* __restrict__ sid_last,
                                                const unsigned char* __restrict__ X1,
                                                bf16* __restrict__ aggG) {
    __shared__ int   nns[JG];
    __shared__ int   ncn_s[JG];
    __shared__ int   nidx[JG][CAP];
    __shared__ float nval[JG][CAP];
    int b = blockIdx.y, j0 = blockIdx.x * JG, tid = threadIdx.x;
    int m = sid_last[b];
    int cj = cnt[m];
    if (tid < JG) {
        int j = j0 + tid;
        int n = idxA[m * CAP + (j < cj ? j : 0)];
        nns[tid] = n;
        ncn_s[tid] = (j < cj) ? cnt[n] : 0;
    }
    __syncthreads();
    for (int i = tid; i < JG * CAP; i += 256) {
        int jj = i >> 7, k = i & (CAP - 1);
        int n = nns[jj], c = ncn_s[jj];
        nidx[jj][k] = (k < c) ? idxA[n * CAP + k] : 0;
        nval[jj][k] = (k < c) ? valA[n * CAP + k] : 0.f;
    }
    __syncthreads();
    int lane = tid & 63;
    int w = __builtin_amdgcn_readfirstlane(tid >> 6);
    int la = w * 2, lb = la + 1;
    const uint* X1bl = (const uint*)X1 + (size_t)b * N * 64 + lane;
    int cA = ncn_s[la], cB = ncn_s[lb];
    int cmax = cA > cB ? cA : cB;
    float aA0 = 0.f, aA1 = 0.f, aA2 = 0.f, aA3 = 0.f;
    float aB0 = 0.f, aB1 = 0.f, aB2 = 0.f, aB3 = 0.f;
    if (cmax > 0) {
        uint uA = X1bl[(size_t)nidx[la][0] * 64]; float vA = nval[la][0];
        uint uB = X1bl[(size_t)nidx[lb][0] * 64]; float vB = nval[lb][0];
        for (int k = 0; k < cmax; ++k) {
            uint cuA = uA, cuB = uB;
            float cvA = vA, cvB = vB;
            int kn = (k + 1 < CAP) ? k + 1 : CAP - 1;
            uA = X1bl[(size_t)nidx[la][kn] * 64]; vA = nval[la][kn];
            uB = X1bl[(size_t)nidx[lb][kn] * 64]; vB = nval[lb][kn];
            f2v loA = __builtin_amdgcn_cvt_pk_f32_fp8((int)cuA, false);
            f2v hiA = __builtin_amdgcn_cvt_pk_f32_fp8((int)cuA, true);
            f2v loB = __builtin_amdgcn_cvt_pk_f32_fp8((int)cuB, false);
            f2v hiB = __builtin_amdgcn_cvt_pk_f32_fp8((int)cuB, true);
            aA0 += cvA * loA.x; aA1 += cvA * loA.y;
            aA2 += cvA * hiA.x; aA3 += cvA * hiA.y;
            aB0 += cvB * loB.x; aB1 += cvB * loB.y;
            aB2 += cvB * hiB.x; aB3 += cvB * hiB.y;
        }
    }
    uint2 pkA, pkB;
    pkA.x = bfb(aA0) | ((uint)bfb(aA1) << 16);
    pkA.y = bfb(aA2) | ((uint)bfb(aA3) << 16);
    pkB.x = bfb(aB0) | ((uint)bfb(aB1) << 16);
    pkB.y = bfb(aB2) | ((uint)bfb(aB3) << 16);
    uint2* ag = (uint2*)aggG;
    ag[((size_t)b * CAP + j0 + la) * 64 + lane] = pkA;
    ag[((size_t)b * CAP + j0 + lb) * 64 + lane] = pkB;
}

// ---------------- kernel 5b: k_x2mm — X2 = relu(agg @ w2 + b2) (MFMA) ------
__global__ __launch_bounds__(256) void k_x2mm(const int* __restrict__ cnt,
                                              const int* __restrict__ sid_last,
                                              const bf16* __restrict__ aggG,
                                              const uint4* __restrict__ w2f,
                                              const float* __restrict__ b2,
                                              float* __restrict__ X2) {
    __shared__ ushort agg[JT][264];   // 528B row stride
    int b = blockIdx.y, j0 = blockIdx.x * JT, tid = threadIdx.x;
    int m = sid_last[b];
    int cj = cnt[m];
    if (j0 >= cj) return;
    int nj = cj - j0; if (nj > JT) nj = JT;
    {
        const uint4* src = (const uint4*)(aggG + ((size_t)b * CAP + j0) * 256);
        for (int i = tid; i < 512; i += 256) {
            int row = i >> 5, col = i & 31;
            *(uint4*)&agg[row][col * 8] = src[i];
        }
    }
    __syncthreads();
    int lane = tid & 63;
    int w = __builtin_amdgcn_readfirstlane(tid >> 6);
    int col = lane & 15, rg = lane >> 4;
    s8v af[8];
#pragma unroll
    for (int kc = 0; kc < 8; ++kc)
        af[kc] = *(const s8v*)&agg[col][kc * 32 + rg * 8];
#pragma unroll
    for (int t = 0; t < 4; ++t) {
        int nt = w * 4 + t;
        f4v acc = (f4v){0.f, 0.f, 0.f, 0.f};
#pragma unroll
        for (int kc = 0; kc < 8; ++kc) {
            s8v bf = *(const s8v*)&w2f[(nt * 8 + kc) * 64 + lane];
            acc = __builtin_amdgcn_mfma_f32_16x16x32_bf16(af[kc], bf, acc, 0, 0, 0);
        }
        float bv = b2[nt * 16 + col];
        float* dst = X2 + ((size_t)b * CAP + j0) * 256 + nt * 16 + col;
#pragma unroll
        for (int i = 0; i < 4; ++i) {
            int row = rg * 4 + i;
            if (row < nj) {
                float vv = acc[i] + bv;
                dst[(size_t)row * 256] = vv > 0.f ? vv : 0.f;
            }
        }
    }
}

// ---------------- kernel 6a: k_gagg — agg1[b,:] = sum_j val*X2[b,j,:] ------
__global__ __launch_bounds__(256) void k_gagg(const int* __restrict__ cnt,
                                              const float* __restrict__ valA,
                                              const int* __restrict__ sid_last,
                                              const float* __restrict__ X2,
                                              float* __restrict__ gagg) {
    int b = blockIdx.x, tid = threadIdx.x;
    int m = sid_last[b];
    int cj = cnt[m];
    const float* vp = valA + m * CAP;
    const float* xp = X2 + (size_t)b * CAP * 256 + tid;
    float a0 = 0.f, a1 = 0.f, a2 = 0.f, a3 = 0.f;
    int jj = 0;
    for (; jj + 4 <= cj; jj += 4) {
        a0 += vp[jj]     * xp[(size_t)(jj)     * 256];
        a1 += vp[jj + 1] * xp[(size_t)(jj + 1) * 256];
        a2 += vp[jj + 2] * xp[(size_t)(jj + 2) * 256];
        a3 += vp[jj + 3] * xp[(size_t)(jj + 3) * 256];
    }
    for (; jj < cj; ++jj) a0 += vp[jj] * xp[(size_t)jj * 256];
    gagg[b * 256 + tid] = (a0 + a1) + (a2 + a3);
}

// ---------------- kernel 6b: k_gmm — g = relu(gagg @ w3 + b3) --------------
__global__ __launch_bounds__(256) void k_gmm(const float* __restrict__ gagg,
                                             const float* __restrict__ w3,
                                             const float* __restrict__ b3,
                                             float* __restrict__ g) {
    int b = blockIdx.x, ot = blockIdx.y, tid = threadIdx.x;
    __shared__ float h[256];
    h[tid] = gagg[b * 256 + tid];
    __syncthreads();
    int q  = tid & 31;       // output quad
    int kg = tid >> 5;       // 0..7, K-group of 32
    const float4* w4 = (const float4*)w3;     // 128 quads per k-row
    int wq = ot * 32 + q;
    float4 acc = {0.f, 0.f, 0.f, 0.f};
    for (int k = kg * 32; k < kg * 32 + 32; ++k) {
        float hk = h[k];
        float4 w = w4[(size_t)k * 128 + wq];
        acc.x += hk * w.x; acc.y += hk * w.y; acc.z += hk * w.z; acc.w += hk * w.w;
    }
    __shared__ float4 red[8][32];
    red[kg][q] = acc;
    __syncthreads();
    if (tid < 32) {
        float4 s = red[0][tid];
#pragma unroll
        for (int gr = 1; gr < 8; ++gr) {
            float4 r = red[gr][tid];
            s.x += r.x; s.y += r.y; s.z += r.z; s.w += r.w;
        }
        int ob = ot * 128 + tid * 4;
        s.x += b3[ob];     s.x = s.x > 0.f ? s.x : 0.f;
        s.y += b3[ob + 1]; s.y = s.y > 0.f ? s.y : 0.f;
        s.z += b3[ob + 2]; s.z = s.z > 0.f ? s.z : 0.f;
        s.w += b3[ob + 3]; s.w = s.w > 0.f ? s.w : 0.f;
        *(float4*)&g[(size_t)b * 512 + ob] = s;
    }
}

// ---------------- kernel 7: hp0 = x_last[:, :15] @ w0 + b0 -----------------
__global__ __launch_bounds__(256) void k_fc0(const float* __restrict__ x,
                                             const float* __restrict__ w0,
                                             const float* __restrict__ b0,
                                             float* __restrict__ hp0) {
    int i = blockIdx.x * 256 + threadIdx.x;
    int b = i >> 9, o = i & 511;
    const float* xr = x + (size_t)b * XROW + (S - 1) * 17;
    float acc = b0[o];
#pragma unroll
    for (int f = 0; f < 15; ++f) acc += xr[f] * w0[f * 512 + o];
    hp0[i] = acc;
}

// ---------------- kernel 8/10: batch-norm stats (biased var) ---------------
__global__ __launch_bounds__(256) void k_bnstats(const float* __restrict__ h,
                                                 float* __restrict__ mu,
                                                 float* __restrict__ rstd) {
    int o = blockIdx.x * 256 + threadIdx.x;
    float s = 0.f, s2 = 0.f;
    for (int b = 0; b < B; ++b) { float v = h[b * 512 + o]; s += v; s2 += v * v; }
    float m = s * (1.f / B);
    float var = s2 * (1.f / B) - m * m;
    mu[o] = m;
    rstd[o] = rsqrtf(var + 1e-5f);
}

// ---------------- kernel 9: hp1 = [leaky(bn(hp0)), g] @ w1 + b1 ------------
__global__ __launch_bounds__(256) void k_fc1(const float* __restrict__ hp0,
                                             const float* __restrict__ mu0,
                                             const float* __restrict__ rstd0,
                                             const float* __restrict__ gam,
                                             const float* __restrict__ bet,
                                             const float* __restrict__ gbuf,
                                             const float* __restrict__ w1,
                                             const float* __restrict__ b1,
                                             float* __restrict__ hp1) {
    int b = blockIdx.x, ot = blockIdx.y, tid = threadIdx.x;
    __shared__ float h[1024];
    for (int o = tid; o < 512; o += 256) {
        float v = hp0[b * 512 + o];
        v = gam[o] * (v - mu0[o]) * rstd0[o] + bet[o];
        h[o] = v >= 0.f ? v : 0.01f * v;
        h[512 + o] = gbuf[(size_t)b * 512 + o];
    }
    __syncthreads();
    int q  = tid & 31;
    int kg = tid >> 5;
    const float4* w4 = (const float4*)w1;
    int wq = ot * 32 + q;
    float4 acc = {0.f, 0.f, 0.f, 0.f};
    for (int k = kg * 128; k < kg * 128 + 128; ++k) {
        float hk = h[k];
        float4 w = w4[(size_t)k * 128 + wq];
        acc.x += hk * w.x; acc.y += hk * w.y; acc.z += hk * w.z; acc.w += hk * w.w;
    }
    __shared__ float4 red[8][32];
    red[kg][q] = acc;
    __syncthreads();
    if (tid < 32) {
        float4 s = red[0][tid];
#pragma unroll
        for (int gr = 1; gr < 8; ++gr) {
            float4 r = red[gr][tid];
            s.x += r.x; s.y += r.y; s.z += r.z; s.w += r.w;
        }
        int ob = ot * 128 + tid * 4;
        s.x += b1[ob]; s.y += b1[ob + 1]; s.z += b1[ob + 2]; s.w += b1[ob + 3];
        *(float4*)&hp1[b * 512 + ob] = s;
    }
}

// ---------------- kernel 11: out = sigmoid(leaky(bn(hp1)) @ w2 + b2) -------
__global__ __launch_bounds__(64) void k_out(const float* __restrict__ hp1,
                                            const float* __restrict__ mu1,
                                            const float* __restrict__ rstd1,
                                            const float* __restrict__ gam,
                                            const float* __restrict__ bet,
                                            const float* __restrict__ w2,
                                            const float* __restrict__ b2,
                                            float* __restrict__ out) {
    int b = blockIdx.x, lane = threadIdx.x;
    float acc = 0.f;
    for (int o = lane; o < 512; o += 64) {
        float v = hp1[b * 512 + o];
        v = gam[o] * (v - mu1[o]) * rstd1[o] + bet[o];
        v = v >= 0.f ? v : 0.01f * v;
        acc += v * w2[o];
    }
    for (int off = 32; off > 0; off >>= 1) acc += __shfl_down(acc, off);
    if (lane == 0) out[b] = 1.f / (1.f + expf(-(acc + b2[0])));
}

static inline size_t align256(size_t x) { return (x + 255) & ~(size_t)255; }

extern "C" void kernel_launch(void* const* d_in, const int* in_sizes, int n_in,
                              void* d_out, int out_size, void* d_ws, size_t ws_size,
                              hipStream_t stream) {
    const float* x     = (const float*)d_in[0];
    const float* adj   = (const float*)d_in[1];
    const float* w_gc1 = (const float*)d_in[2];
    const float* b_gc1 = (const float*)d_in[3];
    const float* w_gc2 = (const float*)d_in[4];
    const float* b_gc2 = (const float*)d_in[5];
    const float* w_gc3 = (const float*)d_in[6];
    const float* b_gc3 = (const float*)d_in[7];
    const float* w_fc0 = (const float*)d_in[8];
    const float* b_fc0 = (const float*)d_in[9];
    const float* g_fc0 = (const float*)d_in[10];
    const float* be_fc0= (const float*)d_in[11];
    const float* w_fc1 = (const float*)d_in[12];
    const float* b_fc1 = (const float*)d_in[13];
    const float* g_fc1 = (const float*)d_in[14];
    const float* be_fc1= (const float*)d_in[15];
    const float* w_fc2 = (const float*)d_in[16];
    const float* b_fc2 = (const float*)d_in[17];

    char* wsp = (char*)d_ws;
    size_t off = 0;
    auto alloc = [&](size_t bytes) { void* p = wsp + off; off = align256(off + bytes); return p; };
    float* d_deg   = (float*)alloc((size_t)N * 4);
    int*   sid     = (int*)  alloc((size_t)B * 63 * 4);
    int*   sidl    = (int*)  alloc((size_t)B * 4);
    uint4* feA     = (uint4*)alloc((size_t)B * 2 * 64 * 16);
    uint4* wfrag   = (uint4*)alloc((size_t)1024 * 16);
    uint4* w2frag  = (uint4*)alloc((size_t)8192 * 16);
    int*   csr_cnt = (int*)  alloc((size_t)N * 4);
    int*   csr_idx = (int*)  alloc((size_t)N * CAP * 4);
    float* csr_val = (float*)alloc((size_t)N * CAP * 4);
    unsigned char* X1 = (unsigned char*)alloc((size_t)B * N * 256);
    bf16*  aggG    = (bf16*) alloc((size_t)B * CAP * 256 * 2);
    float* X2      = (float*)alloc((size_t)B * CAP * 256 * 4);
    float* gagg    = (float*)alloc((size_t)B * 256 * 4);
    float* gbuf    = (float*)alloc((size_t)B * 512 * 4);
    float* hp0     = (float*)alloc((size_t)B * 512 * 4);
    float* mu0     = (float*)alloc(512 * 4);
    float* rstd0   = (float*)alloc(512 * 4);
    float* hp1     = (float*)alloc((size_t)B * 512 * 4);
    float* mu1     = (float*)alloc(512 * 4);
    float* rstd1   = (float*)alloc(512 * 4);

    k_rowsum <<<N, 256, 0, stream>>>(adj, d_deg);
    k_csr    <<<N, 64, 0, stream>>>(adj, d_deg, csr_cnt, csr_idx, csr_val);
    k_packw  <<<36, 256, 0, stream>>>(w_gc1, w_gc2, wfrag, w2frag);
    k_extract<<<B, 256, 0, stream>>>(x, d_deg, sid, sidl, feA);
    k_x1     <<<dim3(32, B), 256, 0, stream>>>(adj, d_deg, sid, feA, wfrag, b_gc1, X1);
    k_gather <<<dim3(CAP / JG, B), 256, 0, stream>>>(csr_cnt, csr_idx, csr_val, sidl, X1, aggG);
    k_x2mm   <<<dim3(CAP / JT, B), 256, 0, stream>>>(csr_cnt, sidl, aggG, w2frag, b_gc2, X2);
    k_gagg   <<<B, 256, 0, stream>>>(csr_cnt, csr_val, sidl, X2, gagg);
    k_gmm    <<<dim3(B, 4), 256, 0, stream>>>(gagg, w_gc3, b_gc3, gbuf);
    k_fc0    <<<(B * 512) / 256, 256, 0, stream>>>(x, w_fc0, b_fc0, hp0);
    k_bnstats<<<2, 256, 0, stream>>>(hp0, mu0, rstd0);
    k_fc1    <<<dim3(B, 4), 256, 0, stream>>>(hp0, mu0, rstd0, g_fc0, be_fc0, gbuf, w_fc1, b_fc1, hp1);
    k_bnstats<<<2, 256, 0, stream>>>(hp1, mu1, rstd1);
    k_out    <<<B, 64, 0, stream>>>(hp1, mu1, rstd1, g_fc1, be_fc1, w_fc2, b_fc2, (float*)d_out);
}

// Round 12
// 145.078 us; speedup vs baseline: 2.1588x; 1.1312x over previous
//
#include <hip/hip_runtime.h>
#include <hip/hip_bf16.h>

typedef __hip_bfloat16 bf16;
typedef short s8v __attribute__((ext_vector_type(8)));
typedef float f4v __attribute__((ext_vector_type(4)));
typedef float f2v __attribute__((ext_vector_type(2)));

#define B   128
#define N   2000
#define S   64
#define CAP 128          // max neighbors per row (mean ~65, 8-sigma safe)
#define JT  16           // neighbors per block in k_x2mm
#define JG  8            // j-rows per block in k_gather
#define XROW 1088        // S*17

__device__ inline ushort bfb(float v) {
    union { __hip_bfloat16 h; ushort u; } c; c.h = __float2bfloat16(v); return c.u;
}

// ---------------- kernel 1: d[m] = rsqrt(sum(adj[m,:]) + 1) ----------------
__global__ __launch_bounds__(256) void k_rowsum(const float* __restrict__ adj,
                                                float* __restrict__ d) {
    int m = blockIdx.x;
    const float* row = adj + (size_t)m * N;
    float s = 0.f;
    for (int c = threadIdx.x; c < N; c += 256) s += row[c];
    for (int o = 32; o > 0; o >>= 1) s += __shfl_down(s, o);
    __shared__ float red[4];
    int wave = threadIdx.x >> 6;
    if ((threadIdx.x & 63) == 0) red[wave] = s;
    __syncthreads();
    if (threadIdx.x == 0)
        d[m] = rsqrtf(red[0] + red[1] + red[2] + red[3] + 1.0f);
}

// ---------------- kernel 2: CSR of Ahat (ordered ballot compaction) --------
__global__ __launch_bounds__(64) void k_csr(const float* __restrict__ adj,
                                            const float* __restrict__ d,
                                            int* __restrict__ cnt,
                                            int* __restrict__ idx,
                                            float* __restrict__ val) {
    int m = blockIdx.x;
    int lane = threadIdx.x;
    const float* row = adj + (size_t)m * N;
    float dm = d[m];
    int base = 0;
    for (int c0 = 0; c0 < N; c0 += 64) {
        int c = c0 + lane;
        float a = 0.f;
        if (c < N) { a = row[c]; if (c == m) a += 1.0f; }
        bool pred = (a != 0.f);
        unsigned long long mask = __ballot(pred);
        int pos = base + __popcll(mask & ((1ull << lane) - 1ull));
        if (pred && pos < CAP) {
            idx[m * CAP + pos] = c;
            val[m * CAP + pos] = dm * d[c] * a;
        }
        base += (int)__popcll(mask);
    }
    if (lane == 0) cnt[m] = base < CAP ? base : CAP;
}

// ---------------- kernel 3: extract sids / sid_last / pack fe^T A-frags ----
__global__ __launch_bounds__(256) void k_extract(const float* __restrict__ x,
                                                 const float* __restrict__ d,
                                                 int* __restrict__ sid,
                                                 int* __restrict__ sid_last,
                                                 uint4* __restrict__ feA) {
    int b = blockIdx.x, tid = threadIdx.x;
    const float* xb = x + (size_t)b * XROW;
    __shared__ float dss_sh[63];
    __shared__ float fe_sh[64][16];
    if (tid < S - 1) {
        int s_ = (int)xb[tid * 17 + 15];
        sid[b * (S - 1) + tid] = s_;
        dss_sh[tid] = d[s_];
    }
    if (tid == S - 1) sid_last[b] = (int)xb[(S - 1) * 17 + 15];
    if (tid >= 240 && tid < 256) fe_sh[63][tid - 240] = 0.f;   // zero pad row
    __syncthreads();
    for (int i = tid; i < (S - 1) * 16; i += 256) {
        int t = i >> 4, f = i & 15;
        fe_sh[t][f] = dss_sh[t] * xb[t * 17 + (f < 15 ? f : 16)];
    }
    __syncthreads();
    if (tid < 128) {
        int kc = tid >> 6, l = tid & 63;
        int f = l & 15, tg = l >> 4;
        ushort h[8];
#pragma unroll
        for (int j = 0; j < 8; ++j)
            h[j] = bfb(fe_sh[kc * 32 + tg * 8 + j][f]);
        uint4 r;
        r.x = h[0] | ((uint)h[1] << 16);
        r.y = h[2] | ((uint)h[3] << 16);
        r.z = h[4] | ((uint)h[5] << 16);
        r.w = h[6] | ((uint)h[7] << 16);
        feA[(b * 2 + kc) * 64 + l] = r;
    }
}

// ---------------- kernel 3bc: pack W1^T and W2 MFMA fragments --------------
__global__ __launch_bounds__(256) void k_packw(const float* __restrict__ w1,
                                               const float* __restrict__ w2,
                                               uint4* __restrict__ wf1,
                                               uint4* __restrict__ wf2) {
    int blk = blockIdx.x;
    if (blk < 4) {
        int e = blk * 256 + threadIdx.x;          // 0..1023
        int ct = e >> 6, l = e & 63;
        int kg = l >> 4, ch = ct * 16 + (l & 15);
        ushort h[8];
#pragma unroll
        for (int j = 0; j < 8; ++j) {
            int f = kg * 8 + j;
            h[j] = (f < 16) ? bfb(w1[f * 256 + ch]) : (ushort)0;
        }
        uint4 r;
        r.x = h[0] | ((uint)h[1] << 16);
        r.y = h[2] | ((uint)h[3] << 16);
        r.z = h[4] | ((uint)h[5] << 16);
        r.w = h[6] | ((uint)h[7] << 16);
        wf1[e] = r;
    } else {
        int e = (blk - 4) * 256 + threadIdx.x;    // 0..8191
        int l = e & 63;
        int kc = (e >> 6) & 7;
        int nt = e >> 9;
        int col = l & 15, kg = l >> 4;
        ushort h[8];
#pragma unroll
        for (int i = 0; i < 8; ++i) {
            int k = kc * 32 + kg * 8 + i;
            h[i] = bfb(w2[k * 256 + nt * 16 + col]);
        }
        uint4 r;
        r.x = h[0] | ((uint)h[1] << 16);
        r.y = h[2] | ((uint)h[3] << 16);
        r.z = h[4] | ((uint)h[5] << 16);
        r.w = h[6] | ((uint)h[7] << 16);
        wf2[e] = r;
    }
}

// ---------------- kernel 4: X1[b,p,:] = relu((Ahat X)[b,p] @ w1 + b1) ------
// X1 stored fp8 e4m3; epilogue LDS-bounce transpose -> 4x uint4 coalesced
// stores per thread (1KB per wave-instruction)
__global__ __launch_bounds__(256) void k_x1(const float* __restrict__ adj,
                                            const float* __restrict__ d,
                                            const int* __restrict__ sid,
                                            const uint4* __restrict__ feA,
                                            const uint4* __restrict__ wfrag,
                                            const float* __restrict__ b1,
                                            unsigned char* __restrict__ X1) {
    __shared__ int sv[64];
    __shared__ __align__(16) ushort Ylds[64][40];   // 80B rows
    __shared__ float b1s[256];
    __shared__ __align__(16) uint Xs[4][16][68];    // pad 68: 2-way writes
    int b = blockIdx.y, p0 = blockIdx.x * 64, tid = threadIdx.x;
    b1s[tid] = b1[tid];
    if (tid < 63) sv[tid] = sid[b * 63 + tid];
    if (tid == 63) sv[63] = 0;
    __syncthreads();

    int l = tid & 63, wv = tid >> 6;
    int lm = l & 15, lg = l >> 4;
    int pt = p0 + wv * 16;
    int pcol = pt + lm;
    bool pv = (pcol < N);
    int pc = pv ? pcol : 0;

    s8v a1_0 = *(const s8v*)&feA[(b * 2 + 0) * 64 + l];
    s8v a1_1 = *(const s8v*)&feA[(b * 2 + 1) * 64 + l];

    int ss[16];
#pragma unroll
    for (int q = 0; q < 16; ++q)
        ss[q] = sv[(q >> 3) * 32 + lg * 8 + (q & 7)];
    float av[16];
#pragma unroll
    for (int q = 0; q < 16; ++q)
        av[q] = adj[(size_t)ss[q] * N + pc];
#pragma unroll
    for (int q = 0; q < 16; ++q) {
        av[q] = pv ? av[q] : 0.f;
        if (pcol == ss[q]) av[q] += 1.0f;
    }
    ushort h[16];
#pragma unroll
    for (int q = 0; q < 16; ++q) h[q] = bfb(av[q]);
    s8v b1f, b2f;
    {
        uint4 t0, t1;
        t0.x = h[0] | ((uint)h[1] << 16);  t0.y = h[2] | ((uint)h[3] << 16);
        t0.z = h[4] | ((uint)h[5] << 16);  t0.w = h[6] | ((uint)h[7] << 16);
        t1.x = h[8] | ((uint)h[9] << 16);  t1.y = h[10] | ((uint)h[11] << 16);
        t1.z = h[12] | ((uint)h[13] << 16); t1.w = h[14] | ((uint)h[15] << 16);
        b1f = *(s8v*)&t0; b2f = *(s8v*)&t1;
    }
    f4v D1 = (f4v){0.f, 0.f, 0.f, 0.f};
    D1 = __builtin_amdgcn_mfma_f32_16x16x32_bf16(a1_0, b1f, D1, 0, 0, 0);
    D1 = __builtin_amdgcn_mfma_f32_16x16x32_bf16(a1_1, b2f, D1, 0, 0, 0);
    float dp = d[pc] * (pv ? 1.f : 0.f);
    uint2 pk;
    pk.x = bfb(D1[0] * dp) | ((uint)bfb(D1[1] * dp) << 16);
    pk.y = bfb(D1[2] * dp) | ((uint)bfb(D1[3] * dp) << 16);
    *(uint2*)&Ylds[wv * 16 + lm][lg * 4] = pk;
    *(uint2*)&Ylds[wv * 16 + lm][16 + lg * 4] = make_uint2(0u, 0u);  // K-pad
    __syncthreads();

    s8v yf = *(const s8v*)&Ylds[wv * 16 + lm][lg * 8];      // B = Y^T frag
    f4v acc2[16];
#pragma unroll
    for (int ct = 0; ct < 16; ++ct) acc2[ct] = (f4v){0.f, 0.f, 0.f, 0.f};
#pragma unroll
    for (int ct = 0; ct < 16; ++ct) {
        s8v wfv = *(const s8v*)&wfrag[ct * 64 + l];         // A = W^T frag
        acc2[ct] = __builtin_amdgcn_mfma_f32_16x16x32_bf16(wfv, yf, acc2[ct], 0, 0, 0);
    }
    // epilogue: bias+relu+fp8-pack into per-wave LDS tile (transpose)
#pragma unroll
    for (int ct = 0; ct < 16; ++ct) {
        float4 bz = *(float4*)&b1s[ct * 16 + lg * 4];
        float v0 = acc2[ct][0] + bz.x; v0 = v0 > 0.f ? v0 : 0.f;
        float v1 = acc2[ct][1] + bz.y; v1 = v1 > 0.f ? v1 : 0.f;
        float v2 = acc2[ct][2] + bz.z; v2 = v2 > 0.f ? v2 : 0.f;
        float v3 = acc2[ct][3] + bz.w; v3 = v3 > 0.f ? v3 : 0.f;
        uint pk8 = (uint)__builtin_amdgcn_cvt_pk_fp8_f32(v0, v1, 0, false);
        pk8 = (uint)__builtin_amdgcn_cvt_pk_fp8_f32(v2, v3, (int)pk8, true);
        Xs[wv][lm][ct * 4 + lg] = pk8;
    }
    __syncthreads();
    // coalesced store: 4 x uint4 per thread, 1KB per wave-instruction
    {
        uint4* dstb = (uint4*)((uint*)X1 + ((size_t)b * N + p0 + wv * 16) * 64);
#pragma unroll
        for (int i = 0; i < 4; ++i) {
            int g = l + 64 * i;            // uint4 index within wave tile
            int r = g >> 4, c4 = g & 15;
            if (p0 + wv * 16 + r < N)
                dstb[g] = *(uint4*)&Xs[wv][r][c4 * 4];
        }
    }
}

// ---------------- kernel 5a: k_gather — agg[b,j,:] = sum_k val*X1[b,idx,:] --
__global__ __launch_bounds__(256) void k_gather(const int* __restrict__ cnt,
                                                const int* __restrict__ idxA,
                                                const float* __restrict__ valA,
                                                const int* __restrict__ sid_last,
                                                const unsigned char* __restrict__ X1,
                                                bf16* __restrict__ aggG) {
    __shared__ int   nns[JG];
    __shared__ int   ncn_s[JG];
    __shared__ int   nidx[JG][CAP];
    __shared__ float nval[JG][CAP];
    int b = blockIdx.y, j0 = blockIdx.x * JG, tid = threadIdx.x;
    int m = sid_last[b];
    int cj = cnt[m];
    if (tid < JG) {
        int j = j0 + tid;
        int n = idxA[m * CAP + (j < cj ? j : 0)];
        nns[tid] = n;
        ncn_s[tid] = (j < cj) ? cnt[n] : 0;
    }
    __syncthreads();
    for (int i = tid; i < JG * CAP; i += 256) {
        int jj = i >> 7, k = i & (CAP - 1);
        int n = nns[jj], c = ncn_s[jj];
        nidx[jj][k] = (k < c) ? idxA[n * CAP + k] : 0;
        nval[jj][k] = (k < c) ? valA[n * CAP + k] : 0.f;
    }
    __syncthreads();
    int lane = tid & 63;
    int w = __builtin_amdgcn_readfirstlane(tid >> 6);
    int la = w * 2, lb = la + 1;
    const uint* X1bl = (const uint*)X1 + (size_t)b * N * 64 + lane;
    int cA = ncn_s[la], cB = ncn_s[lb];
    int cmax = cA > cB ? cA : cB;
    float aA0 = 0.f, aA1 = 0.f, aA2 = 0.f, aA3 = 0.f;
    float aB0 = 0.f, aB1 = 0.f, aB2 = 0.f, aB3 = 0.f;
    if (cmax > 0) {
        uint uA = X1bl[(size_t)nidx[la][0] * 64]; float vA = nval[la][0];
        uint uB = X1bl[(size_t)nidx[lb][0] * 64]; float vB = nval[lb][0];
        for (int k = 0; k < cmax; ++k) {
            uint cuA = uA, cuB = uB;
            float cvA = vA, cvB = vB;
            int kn = (k + 1 < CAP) ? k + 1 : CAP - 1;
            uA = X1bl[(size_t)nidx[la][kn] * 64]; vA = nval[la][kn];
            uB = X1bl[(size_t)nidx[lb][kn] * 64]; vB = nval[lb][kn];
            f2v loA = __builtin_amdgcn_cvt_pk_f32_fp8((int)cuA, false);
            f2v hiA = __builtin_amdgcn_cvt_pk_f32_fp8((int)cuA, true);
            f2v loB = __builtin_amdgcn_cvt_pk_f32_fp8((int)cuB, false);
            f2v hiB = __builtin_amdgcn_cvt_pk_f32_fp8((int)cuB, true);
            aA0 += cvA * loA.x; aA1 += cvA * loA.y;
            aA2 += cvA * hiA.x; aA3 += cvA * hiA.y;
            aB0 += cvB * loB.x; aB1 += cvB * loB.y;
            aB2 += cvB * hiB.x; aB3 += cvB * hiB.y;
        }
    }
    uint2 pkA, pkB;
    pkA.x = bfb(aA0) | ((uint)bfb(aA1) << 16);
    pkA.y = bfb(aA2) | ((uint)bfb(aA3) << 16);
    pkB.x = bfb(aB0) | ((uint)bfb(aB1) << 16);
    pkB.y = bfb(aB2) | ((uint)bfb(aB3) << 16);
    uint2* ag = (uint2*)aggG;
    ag[((size_t)b * CAP + j0 + la) * 64 + lane] = pkA;
    ag[((size_t)b * CAP + j0 + lb) * 64 + lane] = pkB;
}

// ---------------- kernel 5b: k_x2mm — X2 = relu(agg @ w2 + b2) (MFMA) ------
__global__ __launch_bounds__(256) void k_x2mm(const int* __restrict__ cnt,
                                              const int* __restrict__ sid_last,
                                              const bf16* __restrict__ aggG,
                                              const uint4* __restrict__ w2f,
                                              const float* __restrict__ b2,
                                              float* __restrict__ X2) {
    __shared__ ushort agg[JT][264];   // 528B row stride
    int b = blockIdx.y, j0 = blockIdx.x * JT, tid = threadIdx.x;
    int m = sid_last[b];
    int cj = cnt[m];
    if (j0 >= cj) return;
    int nj = cj - j0; if (nj > JT) nj = JT;
    {
        const uint4* src = (const uint4*)(aggG + ((size_t)b * CAP + j0) * 256);
        for (int i = tid; i < 512; i += 256) {
            int row = i >> 5, col = i & 31;
            *(uint4*)&agg[row][col * 8] = src[i];
        }
    }
    __syncthreads();
    int lane = tid & 63;
    int w = __builtin_amdgcn_readfirstlane(tid >> 6);
    int col = lane & 15, rg = lane >> 4;
    s8v af[8];
#pragma unroll
    for (int kc = 0; kc < 8; ++kc)
        af[kc] = *(const s8v*)&agg[col][kc * 32 + rg * 8];
#pragma unroll
    for (int t = 0; t < 4; ++t) {
        int nt = w * 4 + t;
        f4v acc = (f4v){0.f, 0.f, 0.f, 0.f};
#pragma unroll
        for (int kc = 0; kc < 8; ++kc) {
            s8v bf = *(const s8v*)&w2f[(nt * 8 + kc) * 64 + lane];
            acc = __builtin_amdgcn_mfma_f32_16x16x32_bf16(af[kc], bf, acc, 0, 0, 0);
        }
        float bv = b2[nt * 16 + col];
        float* dst = X2 + ((size_t)b * CAP + j0) * 256 + nt * 16 + col;
#pragma unroll
        for (int i = 0; i < 4; ++i) {
            int row = rg * 4 + i;
            if (row < nj) {
                float vv = acc[i] + bv;
                dst[(size_t)row * 256] = vv > 0.f ? vv : 0.f;
            }
        }
    }
}

// ---------------- kernel 6a: k_gagg — agg1[b,:] = sum_j val*X2[b,j,:] ------
__global__ __launch_bounds__(256) void k_gagg(const int* __restrict__ cnt,
                                              const float* __restrict__ valA,
                                              const int* __restrict__ sid_last,
                                              const float* __restrict__ X2,
                                              float* __restrict__ gagg) {
    int b = blockIdx.x, tid = threadIdx.x;
    int m = sid_last[b];
    int cj = cnt[m];
    const float* vp = valA + m * CAP;
    const float* xp = X2 + (size_t)b * CAP * 256 + tid;
    float a0 = 0.f, a1 = 0.f, a2 = 0.f, a3 = 0.f;
    int jj = 0;
    for (; jj + 4 <= cj; jj += 4) {
        a0 += vp[jj]     * xp[(size_t)(jj)     * 256];
        a1 += vp[jj + 1] * xp[(size_t)(jj + 1) * 256];
        a2 += vp[jj + 2] * xp[(size_t)(jj + 2) * 256];
        a3 += vp[jj + 3] * xp[(size_t)(jj + 3) * 256];
    }
    for (; jj < cj; ++jj) a0 += vp[jj] * xp[(size_t)jj * 256];
    gagg[b * 256 + tid] = (a0 + a1) + (a2 + a3);
}

// ---------------- kernel 6b: k_gmm — g = relu(gagg @ w3 + b3) --------------
__global__ __launch_bounds__(256) void k_gmm(const float* __restrict__ gagg,
                                             const float* __restrict__ w3,
                                             const float* __restrict__ b3,
                                             float* __restrict__ g) {
    int b = blockIdx.x, ot = blockIdx.y, tid = threadIdx.x;
    __shared__ float h[256];
    h[tid] = gagg[b * 256 + tid];
    __syncthreads();
    int q  = tid & 31;       // output quad
    int kg = tid >> 5;       // 0..7, K-group of 32
    const float4* w4 = (const float4*)w3;     // 128 quads per k-row
    int wq = ot * 32 + q;
    float4 acc = {0.f, 0.f, 0.f, 0.f};
    for (int k = kg * 32; k < kg * 32 + 32; ++k) {
        float hk = h[k];
        float4 w = w4[(size_t)k * 128 + wq];
        acc.x += hk * w.x; acc.y += hk * w.y; acc.z += hk * w.z; acc.w += hk * w.w;
    }
    __shared__ float4 red[8][32];
    red[kg][q] = acc;
    __syncthreads();
    if (tid < 32) {
        float4 s = red[0][tid];
#pragma unroll
        for (int gr = 1; gr < 8; ++gr) {
            float4 r = red[gr][tid];
            s.x += r.x; s.y += r.y; s.z += r.z; s.w += r.w;
        }
        int ob = ot * 128 + tid * 4;
        s.x += b3[ob];     s.x = s.x > 0.f ? s.x : 0.f;
        s.y += b3[ob + 1]; s.y = s.y > 0.f ? s.y : 0.f;
        s.z += b3[ob + 2]; s.z = s.z > 0.f ? s.z : 0.f;
        s.w += b3[ob + 3]; s.w = s.w > 0.f ? s.w : 0.f;
        *(float4*)&g[(size_t)b * 512 + ob] = s;
    }
}

// ---------------- kernel 7: hp0 = x_last[:, :15] @ w0 + b0 -----------------
__global__ __launch_bounds__(256) void k_fc0(const float* __restrict__ x,
                                             const float* __restrict__ w0,
                                             const float* __restrict__ b0,
                                             float* __restrict__ hp0) {
    int i = blockIdx.x * 256 + threadIdx.x;
    int b = i >> 9, o = i & 511;
    const float* xr = x + (size_t)b * XROW + (S - 1) * 17;
    float acc = b0[o];
#pragma unroll
    for (int f = 0; f < 15; ++f) acc += xr[f] * w0[f * 512 + o];
    hp0[i] = acc;
}

// ---------------- kernel 8/10: batch-norm stats (biased var) ---------------
__global__ __launch_bounds__(256) void k_bnstats(const float* __restrict__ h,
                                                 float* __restrict__ mu,
                                                 float* __restrict__ rstd) {
    int o = blockIdx.x * 256 + threadIdx.x;
    float s = 0.f, s2 = 0.f;
    for (int b = 0; b < B; ++b) { float v = h[b * 512 + o]; s += v; s2 += v * v; }
    float m = s * (1.f / B);
    float var = s2 * (1.f / B) - m * m;
    mu[o] = m;
    rstd[o] = rsqrtf(var + 1e-5f);
}

// ---------------- kernel 9: hp1 = [leaky(bn(hp0)), g] @ w1 + b1 ------------
__global__ __launch_bounds__(256) void k_fc1(const float* __restrict__ hp0,
                                             const float* __restrict__ mu0,
                                             const float* __restrict__ rstd0,
                                             const float* __restrict__ gam,
                                             const float* __restrict__ bet,
                                             const float* __restrict__ gbuf,
                                             const float* __restrict__ w1,
                                             const float* __restrict__ b1,
                                             float* __restrict__ hp1) {
    int b = blockIdx.x, ot = blockIdx.y, tid = threadIdx.x;
    __shared__ float h[1024];
    for (int o = tid; o < 512; o += 256) {
        float v = hp0[b * 512 + o];
        v = gam[o] * (v - mu0[o]) * rstd0[o] + bet[o];
        h[o] = v >= 0.f ? v : 0.01f * v;
        h[512 + o] = gbuf[(size_t)b * 512 + o];
    }
    __syncthreads();
    int q  = tid & 31;
    int kg = tid >> 5;
    const float4* w4 = (const float4*)w1;
    int wq = ot * 32 + q;
    float4 acc = {0.f, 0.f, 0.f, 0.f};
    for (int k = kg * 128; k < kg * 128 + 128; ++k) {
        float hk = h[k];
        float4 w = w4[(size_t)k * 128 + wq];
        acc.x += hk * w.x; acc.y += hk * w.y; acc.z += hk * w.z; acc.w += hk * w.w;
    }
    __shared__ float4 red[8][32];
    red[kg][q] = acc;
    __syncthreads();
    if (tid < 32) {
        float4 s = red[0][tid];
#pragma unroll
        for (int gr = 1; gr < 8; ++gr) {
            float4 r = red[gr][tid];
            s.x += r.x; s.y += r.y; s.z += r.z; s.w += r.w;
        }
        int ob = ot * 128 + tid * 4;
        s.x += b1[ob]; s.y += b1[ob + 1]; s.z += b1[ob + 2]; s.w += b1[ob + 3];
        *(float4*)&hp1[b * 512 + ob] = s;
    }
}

// ---------------- kernel 11: out = sigmoid(leaky(bn(hp1)) @ w2 + b2) -------
__global__ __launch_bounds__(64) void k_out(const float* __restrict__ hp1,
                                            const float* __restrict__ mu1,
                                            const float* __restrict__ rstd1,
                                            const float* __restrict__ gam,
                                            const float* __restrict__ bet,
                                            const float* __restrict__ w2,
                                            const float* __restrict__ b2,
                                            float* __restrict__ out) {
    int b = blockIdx.x, lane = threadIdx.x;
    float acc = 0.f;
    for (int o = lane; o < 512; o += 64) {
        float v = hp1[b * 512 + o];
        v = gam[o] * (v - mu1[o]) * rstd1[o] + bet[o];
        v = v >= 0.f ? v : 0.01f * v;
        acc += v * w2[o];
    }
    for (int off = 32; off > 0; off >>= 1) acc += __shfl_down(acc, off);
    if (lane == 0) out[b] = 1.f / (1.f + expf(-(acc + b2[0])));
}

static inline size_t align256(size_t x) { return (x + 255) & ~(size_t)255; }

extern "C" void kernel_launch(void* const* d_in, const int* in_sizes, int n_in,
                              void* d_out, int out_size, void* d_ws, size_t ws_size,
                              hipStream_t stream) {
    const float* x     = (const float*)d_in[0];
    const float* adj   = (const float*)d_in[1];
    const float* w_gc1 = (const float*)d_in[2];
    const float* b_gc1 = (const float*)d_in[3];
    const float* w_gc2 = (const float*)d_in[4];
    const float* b_gc2 = (const float*)d_in[5];
    const float* w_gc3 = (const float*)d_in[6];
    const float* b_gc3 = (const float*)d_in[7];
    const float* w_fc0 = (const float*)d_in[8];
    const float* b_fc0 = (const float*)d_in[9];
    const float* g_fc0 = (const float*)d_in[10];
    const float* be_fc0= (const float*)d_in[11];
    const float* w_fc1 = (const float*)d_in[12];
    const float* b_fc1 = (const float*)d_in[13];
    const float* g_fc1 = (const float*)d_in[14];
    const float* be_fc1= (const float*)d_in[15];
    const float* w_fc2 = (const float*)d_in[16];
    const float* b_fc2 = (const float*)d_in[17];

    char* wsp = (char*)d_ws;
    size_t off = 0;
    auto alloc = [&](size_t bytes) { void* p = wsp + off; off = align256(off + bytes); return p; };
    float* d_deg   = (float*)alloc((size_t)N * 4);
    int*   sid     = (int*)  alloc((size_t)B * 63 * 4);
    int*   sidl    = (int*)  alloc((size_t)B * 4);
    uint4* feA     = (uint4*)alloc((size_t)B * 2 * 64 * 16);
    uint4* wfrag   = (uint4*)alloc((size_t)1024 * 16);
    uint4* w2frag  = (uint4*)alloc((size_t)8192 * 16);
    int*   csr_cnt = (int*)  alloc((size_t)N * 4);
    int*   csr_idx = (int*)  alloc((size_t)N * CAP * 4);
    float* csr_val = (float*)alloc((size_t)N * CAP * 4);
    unsigned char* X1 = (unsigned char*)alloc((size_t)B * N * 256);
    bf16*  aggG    = (bf16*) alloc((size_t)B * CAP * 256 * 2);
    float* X2      = (float*)alloc((size_t)B * CAP * 256 * 4);
    float* gagg    = (float*)alloc((size_t)B * 256 * 4);
    float* gbuf    = (float*)alloc((size_t)B * 512 * 4);
    float* hp0     = (float*)alloc((size_t)B * 512 * 4);
    float* mu0     = (float*)alloc(512 * 4);
    float* rstd0   = (float*)alloc(512 * 4);
    float* hp1     = (float*)alloc((size_t)B * 512 * 4);
    float* mu1     = (float*)alloc(512 * 4);
    float* rstd1   = (float*)alloc(512 * 4);

    k_rowsum <<<N, 256, 0, stream>>>(adj, d_deg);
    k_csr    <<<N, 64, 0, stream>>>(adj, d_deg, csr_cnt, csr_idx, csr_val);
    k_packw  <<<36, 256, 0, stream>>>(w_gc1, w_gc2, wfrag, w2frag);
    k_extract<<<B, 256, 0, stream>>>(x, d_deg, sid, sidl, feA);
    k_x1     <<<dim3(32, B), 256, 0, stream>>>(adj, d_deg, sid, feA, wfrag, b_gc1, X1);
    k_gather <<<dim3(CAP / JG, B), 256, 0, stream>>>(csr_cnt, csr_idx, csr_val, sidl, X1, aggG);
    k_x2mm   <<<dim3(CAP / JT, B), 256, 0, stream>>>(csr_cnt, sidl, aggG, w2frag, b_gc2, X2);
    k_gagg   <<<B, 256, 0, stream>>>(csr_cnt, csr_val, sidl, X2, gagg);
    k_gmm    <<<dim3(B, 4), 256, 0, stream>>>(gagg, w_gc3, b_gc3, gbuf);
    k_fc0    <<<(B * 512) / 256, 256, 0, stream>>>(x, w_fc0, b_fc0, hp0);
    k_bnstats<<<2, 256, 0, stream>>>(hp0, mu0, rstd0);
    k_fc1    <<<dim3(B, 4), 256, 0, stream>>>(hp0, mu0, rstd0, g_fc0, be_fc0, gbuf, w_fc1, b_fc1, hp1);
    k_bnstats<<<2, 256, 0, stream>>>(hp1, mu1, rstd1);
    k_out    <<<B, 64, 0, stream>>>(hp1, mu1, rstd1, g_fc1, be_fc1, w_fc2, b_fc2, (float*)d_out);
}

// Round 13
// 134.706 us; speedup vs baseline: 2.3250x; 1.0770x over previous
//
#include <hip/hip_runtime.h>
#include <hip/hip_bf16.h>

typedef __hip_bfloat16 bf16;
typedef short s8v __attribute__((ext_vector_type(8)));
typedef float f4v __attribute__((ext_vector_type(4)));
typedef float f2v __attribute__((ext_vector_type(2)));

#define B   128
#define N   2000
#define S   64
#define CAP 128          // max neighbors per row (mean ~65, 8-sigma safe)
#define JT  16           // neighbors per block in k_x2mm
#define JG  8            // j-rows per block in k_gather
#define XROW 1088        // S*17

__device__ inline ushort bfb(float v) {
    union { __hip_bfloat16 h; ushort u; } c; c.h = __float2bfloat16(v); return c.u;
}

// ---------------- k_prep0: rowsum (blk<N) + pack W frags (blk>=N) ----------
__global__ __launch_bounds__(256) void k_prep0(const float* __restrict__ adj,
                                               float* __restrict__ d,
                                               const float* __restrict__ w1,
                                               const float* __restrict__ w2,
                                               uint4* __restrict__ wf1,
                                               uint4* __restrict__ wf2) {
    int blk = blockIdx.x;
    if (blk < N) {
        int m = blk;
        const float* row = adj + (size_t)m * N;
        float s = 0.f;
        for (int c = threadIdx.x; c < N; c += 256) s += row[c];
        for (int o = 32; o > 0; o >>= 1) s += __shfl_down(s, o);
        __shared__ float red[4];
        int wave = threadIdx.x >> 6;
        if ((threadIdx.x & 63) == 0) red[wave] = s;
        __syncthreads();
        if (threadIdx.x == 0)
            d[m] = rsqrtf(red[0] + red[1] + red[2] + red[3] + 1.0f);
    } else {
        int blk2 = blk - N;
        if (blk2 < 4) {
            int e = blk2 * 256 + threadIdx.x;          // 0..1023
            int ct = e >> 6, l = e & 63;
            int kg = l >> 4, ch = ct * 16 + (l & 15);
            ushort h[8];
#pragma unroll
            for (int j = 0; j < 8; ++j) {
                int f = kg * 8 + j;
                h[j] = (f < 16) ? bfb(w1[f * 256 + ch]) : (ushort)0;
            }
            uint4 r;
            r.x = h[0] | ((uint)h[1] << 16);
            r.y = h[2] | ((uint)h[3] << 16);
            r.z = h[4] | ((uint)h[5] << 16);
            r.w = h[6] | ((uint)h[7] << 16);
            wf1[e] = r;
        } else {
            int e = (blk2 - 4) * 256 + threadIdx.x;    // 0..8191
            int l = e & 63;
            int kc = (e >> 6) & 7;
            int nt = e >> 9;
            int col = l & 15, kg = l >> 4;
            ushort h[8];
#pragma unroll
            for (int i = 0; i < 8; ++i) {
                int k = kc * 32 + kg * 8 + i;
                h[i] = bfb(w2[k * 256 + nt * 16 + col]);
            }
            uint4 r;
            r.x = h[0] | ((uint)h[1] << 16);
            r.y = h[2] | ((uint)h[3] << 16);
            r.z = h[4] | ((uint)h[5] << 16);
            r.w = h[6] | ((uint)h[7] << 16);
            wf2[e] = r;
        }
    }
}

// ---------------- k_prep1: CSR x4 rows/block (blk<500) + extract (>=500) ---
__global__ __launch_bounds__(256) void k_prep1(const float* __restrict__ adj,
                                               const float* __restrict__ d,
                                               const float* __restrict__ x,
                                               int* __restrict__ cnt,
                                               int* __restrict__ idx,
                                               float* __restrict__ val,
                                               int* __restrict__ sid,
                                               int* __restrict__ sid_last,
                                               uint4* __restrict__ feA) {
    int blk = blockIdx.x;
    if (blk < 500) {
        int m = blk * 4 + (threadIdx.x >> 6);
        int lane = threadIdx.x & 63;
        const float* row = adj + (size_t)m * N;
        float dm = d[m];
        int base = 0;
        for (int c0 = 0; c0 < N; c0 += 64) {
            int c = c0 + lane;
            float a = 0.f;
            if (c < N) { a = row[c]; if (c == m) a += 1.0f; }
            bool pred = (a != 0.f);
            unsigned long long mask = __ballot(pred);
            int pos = base + __popcll(mask & ((1ull << lane) - 1ull));
            if (pred && pos < CAP) {
                idx[m * CAP + pos] = c;
                val[m * CAP + pos] = dm * d[c] * a;
            }
            base += (int)__popcll(mask);
        }
        if (lane == 0) cnt[m] = base < CAP ? base : CAP;
    } else {
        int b = blk - 500, tid = threadIdx.x;
        const float* xb = x + (size_t)b * XROW;
        __shared__ float dss_sh[63];
        __shared__ float fe_sh[64][16];
        if (tid < S - 1) {
            int s_ = (int)xb[tid * 17 + 15];
            sid[b * (S - 1) + tid] = s_;
            dss_sh[tid] = d[s_];
        }
        if (tid == S - 1) sid_last[b] = (int)xb[(S - 1) * 17 + 15];
        if (tid >= 240 && tid < 256) fe_sh[63][tid - 240] = 0.f;   // zero pad
        __syncthreads();
        for (int i = tid; i < (S - 1) * 16; i += 256) {
            int t = i >> 4, f = i & 15;
            fe_sh[t][f] = dss_sh[t] * xb[t * 17 + (f < 15 ? f : 16)];
        }
        __syncthreads();
        if (tid < 128) {
            int kc = tid >> 6, l = tid & 63;
            int f = l & 15, tg = l >> 4;
            ushort h[8];
#pragma unroll
            for (int j = 0; j < 8; ++j)
                h[j] = bfb(fe_sh[kc * 32 + tg * 8 + j][f]);
            uint4 r;
            r.x = h[0] | ((uint)h[1] << 16);
            r.y = h[2] | ((uint)h[3] << 16);
            r.z = h[4] | ((uint)h[5] << 16);
            r.w = h[6] | ((uint)h[7] << 16);
            feA[(b * 2 + kc) * 64 + l] = r;
        }
    }
}

// ---------------- kernel 4: X1[b,p,:] = relu((Ahat X)[b,p] @ w1 + b1) ------
// fp8 X1; LDS-bounce transpose -> 4x uint4 coalesced stores/thread
__global__ __launch_bounds__(256) void k_x1(const float* __restrict__ adj,
                                            const float* __restrict__ d,
                                            const int* __restrict__ sid,
                                            const uint4* __restrict__ feA,
                                            const uint4* __restrict__ wfrag,
                                            const float* __restrict__ b1,
                                            unsigned char* __restrict__ X1) {
    __shared__ int sv[64];
    __shared__ __align__(16) ushort Ylds[64][40];   // 80B rows
    __shared__ float b1s[256];
    __shared__ __align__(16) uint Xs[4][16][68];    // pad 68: 2-way writes
    int b = blockIdx.y, p0 = blockIdx.x * 64, tid = threadIdx.x;
    b1s[tid] = b1[tid];
    if (tid < 63) sv[tid] = sid[b * 63 + tid];
    if (tid == 63) sv[63] = 0;
    __syncthreads();

    int l = tid & 63, wv = tid >> 6;
    int lm = l & 15, lg = l >> 4;
    int pt = p0 + wv * 16;
    int pcol = pt + lm;
    bool pv = (pcol < N);
    int pc = pv ? pcol : 0;

    s8v a1_0 = *(const s8v*)&feA[(b * 2 + 0) * 64 + l];
    s8v a1_1 = *(const s8v*)&feA[(b * 2 + 1) * 64 + l];

    int ss[16];
#pragma unroll
    for (int q = 0; q < 16; ++q)
        ss[q] = sv[(q >> 3) * 32 + lg * 8 + (q & 7)];
    float av[16];
#pragma unroll
    for (int q = 0; q < 16; ++q)
        av[q] = adj[(size_t)ss[q] * N + pc];
#pragma unroll
    for (int q = 0; q < 16; ++q) {
        av[q] = pv ? av[q] : 0.f;
        if (pcol == ss[q]) av[q] += 1.0f;
    }
    ushort h[16];
#pragma unroll
    for (int q = 0; q < 16; ++q) h[q] = bfb(av[q]);
    s8v b1f, b2f;
    {
        uint4 t0, t1;
        t0.x = h[0] | ((uint)h[1] << 16);  t0.y = h[2] | ((uint)h[3] << 16);
        t0.z = h[4] | ((uint)h[5] << 16);  t0.w = h[6] | ((uint)h[7] << 16);
        t1.x = h[8] | ((uint)h[9] << 16);  t1.y = h[10] | ((uint)h[11] << 16);
        t1.z = h[12] | ((uint)h[13] << 16); t1.w = h[14] | ((uint)h[15] << 16);
        b1f = *(s8v*)&t0; b2f = *(s8v*)&t1;
    }
    f4v D1 = (f4v){0.f, 0.f, 0.f, 0.f};
    D1 = __builtin_amdgcn_mfma_f32_16x16x32_bf16(a1_0, b1f, D1, 0, 0, 0);
    D1 = __builtin_amdgcn_mfma_f32_16x16x32_bf16(a1_1, b2f, D1, 0, 0, 0);
    float dp = d[pc] * (pv ? 1.f : 0.f);
    uint2 pk;
    pk.x = bfb(D1[0] * dp) | ((uint)bfb(D1[1] * dp) << 16);
    pk.y = bfb(D1[2] * dp) | ((uint)bfb(D1[3] * dp) << 16);
    *(uint2*)&Ylds[wv * 16 + lm][lg * 4] = pk;
    *(uint2*)&Ylds[wv * 16 + lm][16 + lg * 4] = make_uint2(0u, 0u);  // K-pad
    __syncthreads();

    s8v yf = *(const s8v*)&Ylds[wv * 16 + lm][lg * 8];      // B = Y^T frag
    f4v acc2[16];
#pragma unroll
    for (int ct = 0; ct < 16; ++ct) acc2[ct] = (f4v){0.f, 0.f, 0.f, 0.f};
#pragma unroll
    for (int ct = 0; ct < 16; ++ct) {
        s8v wfv = *(const s8v*)&wfrag[ct * 64 + l];         // A = W^T frag
        acc2[ct] = __builtin_amdgcn_mfma_f32_16x16x32_bf16(wfv, yf, acc2[ct], 0, 0, 0);
    }
    // epilogue: bias+relu+fp8-pack into per-wave LDS tile (transpose)
#pragma unroll
    for (int ct = 0; ct < 16; ++ct) {
        float4 bz = *(float4*)&b1s[ct * 16 + lg * 4];
        float v0 = acc2[ct][0] + bz.x; v0 = v0 > 0.f ? v0 : 0.f;
        float v1 = acc2[ct][1] + bz.y; v1 = v1 > 0.f ? v1 : 0.f;
        float v2 = acc2[ct][2] + bz.z; v2 = v2 > 0.f ? v2 : 0.f;
        float v3 = acc2[ct][3] + bz.w; v3 = v3 > 0.f ? v3 : 0.f;
        uint pk8 = (uint)__builtin_amdgcn_cvt_pk_fp8_f32(v0, v1, 0, false);
        pk8 = (uint)__builtin_amdgcn_cvt_pk_fp8_f32(v2, v3, (int)pk8, true);
        Xs[wv][lm][ct * 4 + lg] = pk8;
    }
    __syncthreads();
    {
        uint4* dstb = (uint4*)((uint*)X1 + ((size_t)b * N + p0 + wv * 16) * 64);
#pragma unroll
        for (int i = 0; i < 4; ++i) {
            int g = l + 64 * i;
            int r = g >> 4, c4 = g & 15;
            if (p0 + wv * 16 + r < N)
                dstb[g] = *(uint4*)&Xs[wv][r][c4 * 4];
        }
    }
}

// ---------------- kernel 5a: k_gather — 2 rows/wave, 2-deep prefetch -------
__global__ __launch_bounds__(256) void k_gather(const int* __restrict__ cnt,
                                                const int* __restrict__ idxA,
                                                const float* __restrict__ valA,
                                                const int* __restrict__ sid_last,
                                                const unsigned char* __restrict__ X1,
                                                bf16* __restrict__ aggG) {
    __shared__ int   nns[JG];
    __shared__ int   ncn_s[JG];
    __shared__ int   nidx[JG][CAP];
    __shared__ float nval[JG][CAP];
    int b = blockIdx.y, j0 = blockIdx.x * JG, tid = threadIdx.x;
    int m = sid_last[b];
    int cj = cnt[m];
    if (tid < JG) {
        int j = j0 + tid;
        int n = idxA[m * CAP + (j < cj ? j : 0)];
        nns[tid] = n;
        ncn_s[tid] = (j < cj) ? cnt[n] : 0;
    }
    __syncthreads();
    for (int i = tid; i < JG * CAP; i += 256) {
        int jj = i >> 7, k = i & (CAP - 1);
        int n = nns[jj], c = ncn_s[jj];
        nidx[jj][k] = (k < c) ? idxA[n * CAP + k] : 0;
        nval[jj][k] = (k < c) ? valA[n * CAP + k] : 0.f;
    }
    __syncthreads();
    int lane = tid & 63;
    int w = __builtin_amdgcn_readfirstlane(tid >> 6);
    int la = w * 2, lb = la + 1;
    const uint* X1bl = (const uint*)X1 + (size_t)b * N * 64 + lane;
    int cA = ncn_s[la], cB = ncn_s[lb];
    int cmax = cA > cB ? cA : cB;
    float aA0 = 0.f, aA1 = 0.f, aA2 = 0.f, aA3 = 0.f;
    float aB0 = 0.f, aB1 = 0.f, aB2 = 0.f, aB3 = 0.f;
    if (cmax > 0) {
        uint uA0 = X1bl[(size_t)nidx[la][0] * 64]; float vA0 = nval[la][0];
        uint uA1 = X1bl[(size_t)nidx[la][1] * 64]; float vA1 = nval[la][1];
        uint uB0 = X1bl[(size_t)nidx[lb][0] * 64]; float vB0 = nval[lb][0];
        uint uB1 = X1bl[(size_t)nidx[lb][1] * 64]; float vB1 = nval[lb][1];
        int c2 = (cmax + 1) & ~1;
        for (int k = 0; k < c2; k += 2) {
            int k2 = k + 2; k2 = k2 < CAP ? k2 : CAP - 1;
            int k3 = k + 3; k3 = k3 < CAP ? k3 : CAP - 1;
            uint cA0 = uA0, cA1 = uA1, cB0 = uB0, cB1 = uB1;
            float wA0 = vA0, wA1 = vA1, wB0 = vB0, wB1 = vB1;
            uA0 = X1bl[(size_t)nidx[la][k2] * 64]; vA0 = nval[la][k2];
            uA1 = X1bl[(size_t)nidx[la][k3] * 64]; vA1 = nval[la][k3];
            uB0 = X1bl[(size_t)nidx[lb][k2] * 64]; vB0 = nval[lb][k2];
            uB1 = X1bl[(size_t)nidx[lb][k3] * 64]; vB1 = nval[lb][k3];
            f2v lo, hi;
            lo = __builtin_amdgcn_cvt_pk_f32_fp8((int)cA0, false);
            hi = __builtin_amdgcn_cvt_pk_f32_fp8((int)cA0, true);
            aA0 += wA0 * lo.x; aA1 += wA0 * lo.y; aA2 += wA0 * hi.x; aA3 += wA0 * hi.y;
            lo = __builtin_amdgcn_cvt_pk_f32_fp8((int)cA1, false);
            hi = __builtin_amdgcn_cvt_pk_f32_fp8((int)cA1, true);
            aA0 += wA1 * lo.x; aA1 += wA1 * lo.y; aA2 += wA1 * hi.x; aA3 += wA1 * hi.y;
            lo = __builtin_amdgcn_cvt_pk_f32_fp8((int)cB0, false);
            hi = __builtin_amdgcn_cvt_pk_f32_fp8((int)cB0, true);
            aB0 += wB0 * lo.x; aB1 += wB0 * lo.y; aB2 += wB0 * hi.x; aB3 += wB0 * hi.y;
            lo = __builtin_amdgcn_cvt_pk_f32_fp8((int)cB1, false);
            hi = __builtin_amdgcn_cvt_pk_f32_fp8((int)cB1, true);
            aB0 += wB1 * lo.x; aB1 += wB1 * lo.y; aB2 += wB1 * hi.x; aB3 += wB1 * hi.y;
        }
    }
    uint2 pkA, pkB;
    pkA.x = bfb(aA0) | ((uint)bfb(aA1) << 16);
    pkA.y = bfb(aA2) | ((uint)bfb(aA3) << 16);
    pkB.x = bfb(aB0) | ((uint)bfb(aB1) << 16);
    pkB.y = bfb(aB2) | ((uint)bfb(aB3) << 16);
    uint2* ag = (uint2*)aggG;
    ag[((size_t)b * CAP + j0 + la) * 64 + lane] = pkA;
    ag[((size_t)b * CAP + j0 + lb) * 64 + lane] = pkB;
}

// ---------------- kernel 5b: k_x2mm — X2 = relu(agg @ w2 + b2) (MFMA) ------
__global__ __launch_bounds__(256) void k_x2mm(const int* __restrict__ cnt,
                                              const int* __restrict__ sid_last,
                                              const bf16* __restrict__ aggG,
                                              const uint4* __restrict__ w2f,
                                              const float* __restrict__ b2,
                                              float* __restrict__ X2) {
    __shared__ ushort agg[JT][264];   // 528B row stride
    int b = blockIdx.y, j0 = blockIdx.x * JT, tid = threadIdx.x;
    int m = sid_last[b];
    int cj = cnt[m];
    if (j0 >= cj) return;
    int nj = cj - j0; if (nj > JT) nj = JT;
    {
        const uint4* src = (const uint4*)(aggG + ((size_t)b * CAP + j0) * 256);
        for (int i = tid; i < 512; i += 256) {
            int row = i >> 5, col = i & 31;
            *(uint4*)&agg[row][col * 8] = src[i];
        }
    }
    __syncthreads();
    int lane = tid & 63;
    int w = __builtin_amdgcn_readfirstlane(tid >> 6);
    int col = lane & 15, rg = lane >> 4;
    s8v af[8];
#pragma unroll
    for (int kc = 0; kc < 8; ++kc)
        af[kc] = *(const s8v*)&agg[col][kc * 32 + rg * 8];
#pragma unroll
    for (int t = 0; t < 4; ++t) {
        int nt = w * 4 + t;
        f4v acc = (f4v){0.f, 0.f, 0.f, 0.f};
#pragma unroll
        for (int kc = 0; kc < 8; ++kc) {
            s8v bf = *(const s8v*)&w2f[(nt * 8 + kc) * 64 + lane];
            acc = __builtin_amdgcn_mfma_f32_16x16x32_bf16(af[kc], bf, acc, 0, 0, 0);
        }
        float bv = b2[nt * 16 + col];
        float* dst = X2 + ((size_t)b * CAP + j0) * 256 + nt * 16 + col;
#pragma unroll
        for (int i = 0; i < 4; ++i) {
            int row = rg * 4 + i;
            if (row < nj) {
                float vv = acc[i] + bv;
                dst[(size_t)row * 256] = vv > 0.f ? vv : 0.f;
            }
        }
    }
}

// ---------------- kernel 6a: k_gagg — 4-way j-split partials ---------------
__global__ __launch_bounds__(256) void k_gagg(const int* __restrict__ cnt,
                                              const float* __restrict__ valA,
                                              const int* __restrict__ sid_last,
                                              const float* __restrict__ X2,
                                              float* __restrict__ gaggP) {
    int b = blockIdx.x, q = blockIdx.y, tid = threadIdx.x;
    int m = sid_last[b];
    int cj = cnt[m];
    int jlo = q * 32, jhi = jlo + 32 < cj ? jlo + 32 : cj;
    const float* vp = valA + m * CAP;
    const float* xp = X2 + (size_t)b * CAP * 256 + tid;
    float a0 = 0.f, a1 = 0.f, a2 = 0.f, a3 = 0.f;
    int jj = jlo;
    for (; jj + 4 <= jhi; jj += 4) {
        a0 += vp[jj]     * xp[(size_t)(jj)     * 256];
        a1 += vp[jj + 1] * xp[(size_t)(jj + 1) * 256];
        a2 += vp[jj + 2] * xp[(size_t)(jj + 2) * 256];
        a3 += vp[jj + 3] * xp[(size_t)(jj + 3) * 256];
    }
    for (; jj < jhi; ++jj) a0 += vp[jj] * xp[(size_t)jj * 256];
    gaggP[((size_t)b * 4 + q) * 256 + tid] = (a0 + a1) + (a2 + a3);
}

// ---------------- kernel 6b: k_gmm — g = relu(sum(gaggP) @ w3 + b3) --------
__global__ __launch_bounds__(256) void k_gmm(const float* __restrict__ gaggP,
                                             const float* __restrict__ w3,
                                             const float* __restrict__ b3,
                                             float* __restrict__ g) {
    int b = blockIdx.x, ot = blockIdx.y, tid = threadIdx.x;
    __shared__ float h[256];
    {
        const float* p = gaggP + (size_t)b * 4 * 256 + tid;
        h[tid] = p[0] + p[256] + p[512] + p[768];
    }
    __syncthreads();
    int q  = tid & 31;       // output quad
    int kg = tid >> 5;       // 0..7, K-group of 32
    const float4* w4 = (const float4*)w3;     // 128 quads per k-row
    int wq = ot * 32 + q;
    float4 acc = {0.f, 0.f, 0.f, 0.f};
    for (int k = kg * 32; k < kg * 32 + 32; ++k) {
        float hk = h[k];
        float4 w = w4[(size_t)k * 128 + wq];
        acc.x += hk * w.x; acc.y += hk * w.y; acc.z += hk * w.z; acc.w += hk * w.w;
    }
    __shared__ float4 red[8][32];
    red[kg][q] = acc;
    __syncthreads();
    if (tid < 32) {
        float4 s = red[0][tid];
#pragma unroll
        for (int gr = 1; gr < 8; ++gr) {
            float4 r = red[gr][tid];
            s.x += r.x; s.y += r.y; s.z += r.z; s.w += r.w;
        }
        int ob = ot * 128 + tid * 4;
        s.x += b3[ob];     s.x = s.x > 0.f ? s.x : 0.f;
        s.y += b3[ob + 1]; s.y = s.y > 0.f ? s.y : 0.f;
        s.z += b3[ob + 2]; s.z = s.z > 0.f ? s.z : 0.f;
        s.w += b3[ob + 3]; s.w = s.w > 0.f ? s.w : 0.f;
        *(float4*)&g[(size_t)b * 512 + ob] = s;
    }
}

// ---------------- k_fc0s: hp0 = x_last @ w0 + b0, fused batch stats --------
// grid 256: block = 2 channels x 128 batch (tid = c*128 + b)
__global__ __launch_bounds__(256) void k_fc0s(const float* __restrict__ x,
                                              const float* __restrict__ w0,
                                              const float* __restrict__ b0,
                                              float* __restrict__ hp0,
                                              float* __restrict__ mu0,
                                              float* __restrict__ rstd0) {
    int tid = threadIdx.x;
    int c = tid >> 7, b = tid & 127;
    int o = blockIdx.x * 2 + c;
    const float* xr = x + (size_t)b * XROW + (S - 1) * 17;
    float acc = b0[o];
#pragma unroll
    for (int f = 0; f < 15; ++f) acc += xr[f] * w0[f * 512 + o];
    hp0[b * 512 + o] = acc;
    float s = acc, s2 = acc * acc;
    for (int off = 32; off > 0; off >>= 1) {
        s += __shfl_down(s, off);
        s2 += __shfl_down(s2, off);
    }
    __shared__ float rs[4], rs2[4];
    int wv = tid >> 6;
    if ((tid & 63) == 0) { rs[wv] = s; rs2[wv] = s2; }
    __syncthreads();
    if ((tid & 127) == 0) {
        float S1 = rs[c * 2] + rs[c * 2 + 1];
        float S2 = rs2[c * 2] + rs2[c * 2 + 1];
        float m = S1 * (1.f / B);
        float var = S2 * (1.f / B) - m * m;
        mu0[o] = m;
        rstd0[o] = rsqrtf(var + 1e-5f);
    }
}

// ---------------- k_bn1w: widened batch-norm stats for hp1 (grid 16) -------
__global__ __launch_bounds__(256) void k_bn1w(const float* __restrict__ h,
                                              float* __restrict__ mu,
                                              float* __restrict__ rstd) {
    int tid = threadIdx.x;
    int o = blockIdx.x * 32 + (tid & 31);
    int bg = tid >> 5;   // 0..7
    float s = 0.f, s2 = 0.f;
    for (int b = bg * 16; b < bg * 16 + 16; ++b) {
        float v = h[b * 512 + o];
        s += v; s2 += v * v;
    }
    __shared__ float rs[8][32], rs2[8][32];
    rs[bg][tid & 31] = s; rs2[bg][tid & 31] = s2;
    __syncthreads();
    if (tid < 32) {
        float S1 = 0.f, S2 = 0.f;
#pragma unroll
        for (int g2 = 0; g2 < 8; ++g2) { S1 += rs[g2][tid]; S2 += rs2[g2][tid]; }
        float m = S1 * (1.f / B);
        float var = S2 * (1.f / B) - m * m;
        mu[blockIdx.x * 32 + tid] = m;
        rstd[blockIdx.x * 32 + tid] = rsqrtf(var + 1e-5f);
    }
}

// ---------------- kernel 9: hp1 = [leaky(bn(hp0)), g] @ w1 + b1 ------------
__global__ __launch_bounds__(256) void k_fc1(const float* __restrict__ hp0,
                                             const float* __restrict__ mu0,
                                             const float* __restrict__ rstd0,
                                             const float* __restrict__ gam,
                                             const float* __restrict__ bet,
                                             const float* __restrict__ gbuf,
                                             const float* __restrict__ w1,
                                             const float* __restrict__ b1,
                                             float* __restrict__ hp1) {
    int b = blockIdx.x, ot = blockIdx.y, tid = threadIdx.x;
    __shared__ float h[1024];
    for (int o = tid; o < 512; o += 256) {
        float v = hp0[b * 512 + o];
        v = gam[o] * (v - mu0[o]) * rstd0[o] + bet[o];
        h[o] = v >= 0.f ? v : 0.01f * v;
        h[512 + o] = gbuf[(size_t)b * 512 + o];
    }
    __syncthreads();
    int q  = tid & 31;
    int kg = tid >> 5;
    const float4* w4 = (const float4*)w1;
    int wq = ot * 32 + q;
    float4 acc = {0.f, 0.f, 0.f, 0.f};
    for (int k = kg * 128; k < kg * 128 + 128; ++k) {
        float hk = h[k];
        float4 w = w4[(size_t)k * 128 + wq];
        acc.x += hk * w.x; acc.y += hk * w.y; acc.z += hk * w.z; acc.w += hk * w.w;
    }
    __shared__ float4 red[8][32];
    red[kg][q] = acc;
    __syncthreads();
    if (tid < 32) {
        float4 s = red[0][tid];
#pragma unroll
        for (int gr = 1; gr < 8; ++gr) {
            float4 r = red[gr][tid];
            s.x += r.x; s.y += r.y; s.z += r.z; s.w += r.w;
        }
        int ob = ot * 128 + tid * 4;
        s.x += b1[ob]; s.y += b1[ob + 1]; s.z += b1[ob + 2]; s.w += b1[ob + 3];
        *(float4*)&hp1[b * 512 + ob] = s;
    }
}

// ---------------- kernel 11: out = sigmoid(leaky(bn(hp1)) @ w2 + b2) -------
__global__ __launch_bounds__(64) void k_out(const float* __restrict__ hp1,
                                            const float* __restrict__ mu1,
                                            const float* __restrict__ rstd1,
                                            const float* __restrict__ gam,
                                            const float* __restrict__ bet,
                                            const float* __restrict__ w2,
                                            const float* __restrict__ b2,
                                            float* __restrict__ out) {
    int b = blockIdx.x, lane = threadIdx.x;
    float acc = 0.f;
    for (int o = lane; o < 512; o += 64) {
        float v = hp1[b * 512 + o];
        v = gam[o] * (v - mu1[o]) * rstd1[o] + bet[o];
        v = v >= 0.f ? v : 0.01f * v;
        acc += v * w2[o];
    }
    for (int off = 32; off > 0; off >>= 1) acc += __shfl_down(acc, off);
    if (lane == 0) out[b] = 1.f / (1.f + expf(-(acc + b2[0])));
}

static inline size_t align256(size_t x) { return (x + 255) & ~(size_t)255; }

extern "C" void kernel_launch(void* const* d_in, const int* in_sizes, int n_in,
                              void* d_out, int out_size, void* d_ws, size_t ws_size,
                              hipStream_t stream) {
    const float* x     = (const float*)d_in[0];
    const float* adj   = (const float*)d_in[1];
    const float* w_gc1 = (const float*)d_in[2];
    const float* b_gc1 = (const float*)d_in[3];
    const float* w_gc2 = (const float*)d_in[4];
    const float* b_gc2 = (const float*)d_in[5];
    const float* w_gc3 = (const float*)d_in[6];
    const float* b_gc3 = (const float*)d_in[7];
    const float* w_fc0 = (const float*)d_in[8];
    const float* b_fc0 = (const float*)d_in[9];
    const float* g_fc0 = (const float*)d_in[10];
    const float* be_fc0= (const float*)d_in[11];
    const float* w_fc1 = (const float*)d_in[12];
    const float* b_fc1 = (const float*)d_in[13];
    const float* g_fc1 = (const float*)d_in[14];
    const float* be_fc1= (const float*)d_in[15];
    const float* w_fc2 = (const float*)d_in[16];
    const float* b_fc2 = (const float*)d_in[17];

    char* wsp = (char*)d_ws;
    size_t off = 0;
    auto alloc = [&](size_t bytes) { void* p = wsp + off; off = align256(off + bytes); return p; };
    float* d_deg   = (float*)alloc((size_t)N * 4);
    int*   sid     = (int*)  alloc((size_t)B * 63 * 4);
    int*   sidl    = (int*)  alloc((size_t)B * 4);
    uint4* feA     = (uint4*)alloc((size_t)B * 2 * 64 * 16);
    uint4* wfrag   = (uint4*)alloc((size_t)1024 * 16);
    uint4* w2frag  = (uint4*)alloc((size_t)8192 * 16);
    int*   csr_cnt = (int*)  alloc((size_t)N * 4);
    int*   csr_idx = (int*)  alloc((size_t)N * CAP * 4);
    float* csr_val = (float*)alloc((size_t)N * CAP * 4);
    unsigned char* X1 = (unsigned char*)alloc((size_t)B * N * 256);
    bf16*  aggG    = (bf16*) alloc((size_t)B * CAP * 256 * 2);
    float* X2      = (float*)alloc((size_t)B * CAP * 256 * 4);
    float* gaggP   = (float*)alloc((size_t)B * 4 * 256 * 4);
    float* gbuf    = (float*)alloc((size_t)B * 512 * 4);
    float* hp0     = (float*)alloc((size_t)B * 512 * 4);
    float* mu0     = (float*)alloc(512 * 4);
    float* rstd0   = (float*)alloc(512 * 4);
    float* hp1     = (float*)alloc((size_t)B * 512 * 4);
    float* mu1     = (float*)alloc(512 * 4);
    float* rstd1   = (float*)alloc(512 * 4);

    k_prep0 <<<N + 36, 256, 0, stream>>>(adj, d_deg, w_gc1, w_gc2, wfrag, w2frag);
    k_prep1 <<<500 + B, 256, 0, stream>>>(adj, d_deg, x, csr_cnt, csr_idx, csr_val, sid, sidl, feA);
    k_x1    <<<dim3(32, B), 256, 0, stream>>>(adj, d_deg, sid, feA, wfrag, b_gc1, X1);
    k_gather<<<dim3(CAP / JG, B), 256, 0, stream>>>(csr_cnt, csr_idx, csr_val, sidl, X1, aggG);
    k_x2mm  <<<dim3(CAP / JT, B), 256, 0, stream>>>(csr_cnt, sidl, aggG, w2frag, b_gc2, X2);
    k_gagg  <<<dim3(B, 4), 256, 0, stream>>>(csr_cnt, csr_val, sidl, X2, gaggP);
    k_gmm   <<<dim3(B, 4), 256, 0, stream>>>(gaggP, w_gc3, b_gc3, gbuf);
    k_fc0s  <<<256, 256, 0, stream>>>(x, w_fc0, b_fc0, hp0, mu0, rstd0);
    k_fc1   <<<dim3(B, 4), 256, 0, stream>>>(hp0, mu0, rstd0, g_fc0, be_fc0, gbuf, w_fc1, b_fc1, hp1);
    k_bn1w  <<<16, 256, 0, stream>>>(hp1, mu1, rstd1);
    k_out   <<<B, 64, 0, stream>>>(hp1, mu1, rstd1, g_fc1, be_fc1, w_fc2, b_fc2, (float*)d_out);
}

// Round 14
// 124.739 us; speedup vs baseline: 2.5108x; 1.0799x over previous
//
#include <hip/hip_runtime.h>
#include <hip/hip_bf16.h>

typedef __hip_bfloat16 bf16;
typedef short s8v __attribute__((ext_vector_type(8)));
typedef float f4v __attribute__((ext_vector_type(4)));
typedef float f2v __attribute__((ext_vector_type(2)));

#define B   128
#define N   2000
#define S   64
#define CAP 128          // max neighbors per row (mean ~65, 8-sigma safe)
#define JT  16           // neighbors per block in k_x2g
#define JG  8            // j-rows per block in k_gather
#define XROW 1088        // S*17

__device__ inline ushort bfb(float v) {
    union { __hip_bfloat16 h; ushort u; } c; c.h = __float2bfloat16(v); return c.u;
}

// ---------------- k_prep0: rowsum (blk<N) + pack W frags (blk>=N) ----------
__global__ __launch_bounds__(256) void k_prep0(const float* __restrict__ adj,
                                               float* __restrict__ d,
                                               const float* __restrict__ w1,
                                               const float* __restrict__ w2,
                                               uint4* __restrict__ wf1,
                                               uint4* __restrict__ wf2) {
    int blk = blockIdx.x;
    if (blk < N) {
        int m = blk;
        const float* row = adj + (size_t)m * N;
        float s = 0.f;
        for (int c = threadIdx.x; c < N; c += 256) s += row[c];
        for (int o = 32; o > 0; o >>= 1) s += __shfl_down(s, o);
        __shared__ float red[4];
        int wave = threadIdx.x >> 6;
        if ((threadIdx.x & 63) == 0) red[wave] = s;
        __syncthreads();
        if (threadIdx.x == 0)
            d[m] = rsqrtf(red[0] + red[1] + red[2] + red[3] + 1.0f);
    } else {
        int blk2 = blk - N;
        if (blk2 < 4) {
            int e = blk2 * 256 + threadIdx.x;          // 0..1023
            int ct = e >> 6, l = e & 63;
            int kg = l >> 4, ch = ct * 16 + (l & 15);
            ushort h[8];
#pragma unroll
            for (int j = 0; j < 8; ++j) {
                int f = kg * 8 + j;
                h[j] = (f < 16) ? bfb(w1[f * 256 + ch]) : (ushort)0;
            }
            uint4 r;
            r.x = h[0] | ((uint)h[1] << 16);
            r.y = h[2] | ((uint)h[3] << 16);
            r.z = h[4] | ((uint)h[5] << 16);
            r.w = h[6] | ((uint)h[7] << 16);
            wf1[e] = r;
        } else {
            int e = (blk2 - 4) * 256 + threadIdx.x;    // 0..8191
            int l = e & 63;
            int kc = (e >> 6) & 7;
            int nt = e >> 9;
            int col = l & 15, kg = l >> 4;
            ushort h[8];
#pragma unroll
            for (int i = 0; i < 8; ++i) {
                int k = kc * 32 + kg * 8 + i;
                h[i] = bfb(w2[k * 256 + nt * 16 + col]);
            }
            uint4 r;
            r.x = h[0] | ((uint)h[1] << 16);
            r.y = h[2] | ((uint)h[3] << 16);
            r.z = h[4] | ((uint)h[5] << 16);
            r.w = h[6] | ((uint)h[7] << 16);
            wf2[e] = r;
        }
    }
}

// ---------------- k_prep1: CSR x4 rows/block (blk<500) + extract (>=500) ---
__global__ __launch_bounds__(256) void k_prep1(const float* __restrict__ adj,
                                               const float* __restrict__ d,
                                               const float* __restrict__ x,
                                               int* __restrict__ cnt,
                                               int* __restrict__ idx,
                                               float* __restrict__ val,
                                               int* __restrict__ sid,
                                               int* __restrict__ sid_last,
                                               uint4* __restrict__ feA) {
    int blk = blockIdx.x;
    if (blk < 500) {
        int m = blk * 4 + (threadIdx.x >> 6);
        int lane = threadIdx.x & 63;
        const float* row = adj + (size_t)m * N;
        float dm = d[m];
        int base = 0;
        for (int c0 = 0; c0 < N; c0 += 64) {
            int c = c0 + lane;
            float a = 0.f;
            if (c < N) { a = row[c]; if (c == m) a += 1.0f; }
            bool pred = (a != 0.f);
            unsigned long long mask = __ballot(pred);
            int pos = base + __popcll(mask & ((1ull << lane) - 1ull));
            if (pred && pos < CAP) {
                idx[m * CAP + pos] = c;
                val[m * CAP + pos] = dm * d[c] * a;
            }
            base += (int)__popcll(mask);
        }
        if (lane == 0) cnt[m] = base < CAP ? base : CAP;
    } else {
        int b = blk - 500, tid = threadIdx.x;
        const float* xb = x + (size_t)b * XROW;
        __shared__ float dss_sh[63];
        __shared__ float fe_sh[64][16];
        if (tid < S - 1) {
            int s_ = (int)xb[tid * 17 + 15];
            sid[b * (S - 1) + tid] = s_;
            dss_sh[tid] = d[s_];
        }
        if (tid == S - 1) sid_last[b] = (int)xb[(S - 1) * 17 + 15];
        if (tid >= 240 && tid < 256) fe_sh[63][tid - 240] = 0.f;   // zero pad
        __syncthreads();
        for (int i = tid; i < (S - 1) * 16; i += 256) {
            int t = i >> 4, f = i & 15;
            fe_sh[t][f] = dss_sh[t] * xb[t * 17 + (f < 15 ? f : 16)];
        }
        __syncthreads();
        if (tid < 128) {
            int kc = tid >> 6, l = tid & 63;
            int f = l & 15, tg = l >> 4;
            ushort h[8];
#pragma unroll
            for (int j = 0; j < 8; ++j)
                h[j] = bfb(fe_sh[kc * 32 + tg * 8 + j][f]);
            uint4 r;
            r.x = h[0] | ((uint)h[1] << 16);
            r.y = h[2] | ((uint)h[3] << 16);
            r.z = h[4] | ((uint)h[5] << 16);
            r.w = h[6] | ((uint)h[7] << 16);
            feA[(b * 2 + kc) * 64 + l] = r;
        }
    }
}

// ---------------- kernel 4: X1[b,p,:] = relu((Ahat X)[b,p] @ w1 + b1) ------
// fp8 X1; LDS-bounce transpose -> 4x uint4 coalesced stores/thread
__global__ __launch_bounds__(256) void k_x1(const float* __restrict__ adj,
                                            const float* __restrict__ d,
                                            const int* __restrict__ sid,
                                            const uint4* __restrict__ feA,
                                            const uint4* __restrict__ wfrag,
                                            const float* __restrict__ b1,
                                            unsigned char* __restrict__ X1) {
    __shared__ int sv[64];
    __shared__ __align__(16) ushort Ylds[64][40];   // 80B rows
    __shared__ float b1s[256];
    __shared__ __align__(16) uint Xs[4][16][68];    // pad 68: 2-way writes
    int b = blockIdx.y, p0 = blockIdx.x * 64, tid = threadIdx.x;
    b1s[tid] = b1[tid];
    if (tid < 63) sv[tid] = sid[b * 63 + tid];
    if (tid == 63) sv[63] = 0;
    __syncthreads();

    int l = tid & 63, wv = tid >> 6;
    int lm = l & 15, lg = l >> 4;
    int pt = p0 + wv * 16;
    int pcol = pt + lm;
    bool pv = (pcol < N);
    int pc = pv ? pcol : 0;

    s8v a1_0 = *(const s8v*)&feA[(b * 2 + 0) * 64 + l];
    s8v a1_1 = *(const s8v*)&feA[(b * 2 + 1) * 64 + l];

    int ss[16];
#pragma unroll
    for (int q = 0; q < 16; ++q)
        ss[q] = sv[(q >> 3) * 32 + lg * 8 + (q & 7)];
    float av[16];
#pragma unroll
    for (int q = 0; q < 16; ++q)
        av[q] = adj[(size_t)ss[q] * N + pc];
#pragma unroll
    for (int q = 0; q < 16; ++q) {
        av[q] = pv ? av[q] : 0.f;
        if (pcol == ss[q]) av[q] += 1.0f;
    }
    ushort h[16];
#pragma unroll
    for (int q = 0; q < 16; ++q) h[q] = bfb(av[q]);
    s8v b1f, b2f;
    {
        uint4 t0, t1;
        t0.x = h[0] | ((uint)h[1] << 16);  t0.y = h[2] | ((uint)h[3] << 16);
        t0.z = h[4] | ((uint)h[5] << 16);  t0.w = h[6] | ((uint)h[7] << 16);
        t1.x = h[8] | ((uint)h[9] << 16);  t1.y = h[10] | ((uint)h[11] << 16);
        t1.z = h[12] | ((uint)h[13] << 16); t1.w = h[14] | ((uint)h[15] << 16);
        b1f = *(s8v*)&t0; b2f = *(s8v*)&t1;
    }
    f4v D1 = (f4v){0.f, 0.f, 0.f, 0.f};
    D1 = __builtin_amdgcn_mfma_f32_16x16x32_bf16(a1_0, b1f, D1, 0, 0, 0);
    D1 = __builtin_amdgcn_mfma_f32_16x16x32_bf16(a1_1, b2f, D1, 0, 0, 0);
    float dp = d[pc] * (pv ? 1.f : 0.f);
    uint2 pk;
    pk.x = bfb(D1[0] * dp) | ((uint)bfb(D1[1] * dp) << 16);
    pk.y = bfb(D1[2] * dp) | ((uint)bfb(D1[3] * dp) << 16);
    *(uint2*)&Ylds[wv * 16 + lm][lg * 4] = pk;
    *(uint2*)&Ylds[wv * 16 + lm][16 + lg * 4] = make_uint2(0u, 0u);  // K-pad
    __syncthreads();

    s8v yf = *(const s8v*)&Ylds[wv * 16 + lm][lg * 8];      // B = Y^T frag
    f4v acc2[16];
#pragma unroll
    for (int ct = 0; ct < 16; ++ct) acc2[ct] = (f4v){0.f, 0.f, 0.f, 0.f};
#pragma unroll
    for (int ct = 0; ct < 16; ++ct) {
        s8v wfv = *(const s8v*)&wfrag[ct * 64 + l];         // A = W^T frag
        acc2[ct] = __builtin_amdgcn_mfma_f32_16x16x32_bf16(wfv, yf, acc2[ct], 0, 0, 0);
    }
    // epilogue: bias+relu+fp8-pack into per-wave LDS tile (transpose)
#pragma unroll
    for (int ct = 0; ct < 16; ++ct) {
        float4 bz = *(float4*)&b1s[ct * 16 + lg * 4];
        float v0 = acc2[ct][0] + bz.x; v0 = v0 > 0.f ? v0 : 0.f;
        float v1 = acc2[ct][1] + bz.y; v1 = v1 > 0.f ? v1 : 0.f;
        float v2 = acc2[ct][2] + bz.z; v2 = v2 > 0.f ? v2 : 0.f;
        float v3 = acc2[ct][3] + bz.w; v3 = v3 > 0.f ? v3 : 0.f;
        uint pk8 = (uint)__builtin_amdgcn_cvt_pk_fp8_f32(v0, v1, 0, false);
        pk8 = (uint)__builtin_amdgcn_cvt_pk_fp8_f32(v2, v3, (int)pk8, true);
        Xs[wv][lm][ct * 4 + lg] = pk8;
    }
    __syncthreads();
    {
        uint4* dstb = (uint4*)((uint*)X1 + ((size_t)b * N + p0 + wv * 16) * 64);
#pragma unroll
        for (int i = 0; i < 4; ++i) {
            int g = l + 64 * i;
            int r = g >> 4, c4 = g & 15;
            if (p0 + wv * 16 + r < N)
                dstb[g] = *(uint4*)&Xs[wv][r][c4 * 4];
        }
    }
}

// ---------------- kernel 5a: k_gather — 2 rows/wave, 4-deep prefetch -------
__global__ __launch_bounds__(256) void k_gather(const int* __restrict__ cnt,
                                                const int* __restrict__ idxA,
                                                const float* __restrict__ valA,
                                                const int* __restrict__ sid_last,
                                                const unsigned char* __restrict__ X1,
                                                bf16* __restrict__ aggG) {
    __shared__ int   nns[JG];
    __shared__ int   ncn_s[JG];
    __shared__ int   nidx[JG][CAP];
    __shared__ float nval[JG][CAP];
    int b = blockIdx.y, j0 = blockIdx.x * JG, tid = threadIdx.x;
    int m = sid_last[b];
    int cj = cnt[m];
    if (tid < JG) {
        int j = j0 + tid;
        int n = idxA[m * CAP + (j < cj ? j : 0)];
        nns[tid] = n;
        ncn_s[tid] = (j < cj) ? cnt[n] : 0;
    }
    __syncthreads();
    for (int i = tid; i < JG * CAP; i += 256) {
        int jj = i >> 7, k = i & (CAP - 1);
        int n = nns[jj], c = ncn_s[jj];
        nidx[jj][k] = (k < c) ? idxA[n * CAP + k] : 0;
        nval[jj][k] = (k < c) ? valA[n * CAP + k] : 0.f;
    }
    __syncthreads();
    int lane = tid & 63;
    int w = __builtin_amdgcn_readfirstlane(tid >> 6);
    int la = w * 2, lb = la + 1;
    const uint* X1bl = (const uint*)X1 + (size_t)b * N * 64 + lane;
    int cA = ncn_s[la], cB = ncn_s[lb];
    int cmax = cA > cB ? cA : cB;
    float aA0 = 0.f, aA1 = 0.f, aA2 = 0.f, aA3 = 0.f;
    float aB0 = 0.f, aB1 = 0.f, aB2 = 0.f, aB3 = 0.f;
    if (cmax > 0) {
        uint uA0, uA1, uA2, uA3, uB0, uB1, uB2, uB3;
        float vA0, vA1, vA2, vA3, vB0, vB1, vB2, vB3;
        uA0 = X1bl[(size_t)nidx[la][0] * 64]; vA0 = nval[la][0];
        uA1 = X1bl[(size_t)nidx[la][1] * 64]; vA1 = nval[la][1];
        uA2 = X1bl[(size_t)nidx[la][2] * 64]; vA2 = nval[la][2];
        uA3 = X1bl[(size_t)nidx[la][3] * 64]; vA3 = nval[la][3];
        uB0 = X1bl[(size_t)nidx[lb][0] * 64]; vB0 = nval[lb][0];
        uB1 = X1bl[(size_t)nidx[lb][1] * 64]; vB1 = nval[lb][1];
        uB2 = X1bl[(size_t)nidx[lb][2] * 64]; vB2 = nval[lb][2];
        uB3 = X1bl[(size_t)nidx[lb][3] * 64]; vB3 = nval[lb][3];
        int c4 = (cmax + 3) & ~3;
        for (int k = 0; k < c4; k += 4) {
            uint cA0 = uA0, cA1 = uA1, cA2 = uA2, cA3 = uA3;
            uint cB0 = uB0, cB1 = uB1, cB2 = uB2, cB3 = uB3;
            float wA0 = vA0, wA1 = vA1, wA2 = vA2, wA3 = vA3;
            float wB0 = vB0, wB1 = vB1, wB2 = vB2, wB3 = vB3;
            int k4 = k + 4; k4 = k4 < CAP ? k4 : CAP - 1;
            int k5 = k + 5; k5 = k5 < CAP ? k5 : CAP - 1;
            int k6 = k + 6; k6 = k6 < CAP ? k6 : CAP - 1;
            int k7 = k + 7; k7 = k7 < CAP ? k7 : CAP - 1;
            uA0 = X1bl[(size_t)nidx[la][k4] * 64]; vA0 = nval[la][k4];
            uA1 = X1bl[(size_t)nidx[la][k5] * 64]; vA1 = nval[la][k5];
            uA2 = X1bl[(size_t)nidx[la][k6] * 64]; vA2 = nval[la][k6];
            uA3 = X1bl[(size_t)nidx[la][k7] * 64]; vA3 = nval[la][k7];
            uB0 = X1bl[(size_t)nidx[lb][k4] * 64]; vB0 = nval[lb][k4];
            uB1 = X1bl[(size_t)nidx[lb][k5] * 64]; vB1 = nval[lb][k5];
            uB2 = X1bl[(size_t)nidx[lb][k6] * 64]; vB2 = nval[lb][k6];
            uB3 = X1bl[(size_t)nidx[lb][k7] * 64]; vB3 = nval[lb][k7];
            f2v lo, hi;
            lo = __builtin_amdgcn_cvt_pk_f32_fp8((int)cA0, false);
            hi = __builtin_amdgcn_cvt_pk_f32_fp8((int)cA0, true);
            aA0 += wA0 * lo.x; aA1 += wA0 * lo.y; aA2 += wA0 * hi.x; aA3 += wA0 * hi.y;
            lo = __builtin_amdgcn_cvt_pk_f32_fp8((int)cA1, false);
            hi = __builtin_amdgcn_cvt_pk_f32_fp8((int)cA1, true);
            aA0 += wA1 * lo.x; aA1 += wA1 * lo.y; aA2 += wA1 * hi.x; aA3 += wA1 * hi.y;
            lo = __builtin_amdgcn_cvt_pk_f32_fp8((int)cA2, false);
            hi = __builtin_amdgcn_cvt_pk_f32_fp8((int)cA2, true);
            aA0 += wA2 * lo.x; aA1 += wA2 * lo.y; aA2 += wA2 * hi.x; aA3 += wA2 * hi.y;
            lo = __builtin_amdgcn_cvt_pk_f32_fp8((int)cA3, false);
            hi = __builtin_amdgcn_cvt_pk_f32_fp8((int)cA3, true);
            aA0 += wA3 * lo.x; aA1 += wA3 * lo.y; aA2 += wA3 * hi.x; aA3 += wA3 * hi.y;
            lo = __builtin_amdgcn_cvt_pk_f32_fp8((int)cB0, false);
            hi = __builtin_amdgcn_cvt_pk_f32_fp8((int)cB0, true);
            aB0 += wB0 * lo.x; aB1 += wB0 * lo.y; aB2 += wB0 * hi.x; aB3 += wB0 * hi.y;
            lo = __builtin_amdgcn_cvt_pk_f32_fp8((int)cB1, false);
            hi = __builtin_amdgcn_cvt_pk_f32_fp8((int)cB1, true);
            aB0 += wB1 * lo.x; aB1 += wB1 * lo.y; aB2 += wB1 * hi.x; aB3 += wB1 * hi.y;
            lo = __builtin_amdgcn_cvt_pk_f32_fp8((int)cB2, false);
            hi = __builtin_amdgcn_cvt_pk_f32_fp8((int)cB2, true);
            aB0 += wB2 * lo.x; aB1 += wB2 * lo.y; aB2 += wB2 * hi.x; aB3 += wB2 * hi.y;
            lo = __builtin_amdgcn_cvt_pk_f32_fp8((int)cB3, false);
            hi = __builtin_amdgcn_cvt_pk_f32_fp8((int)cB3, true);
            aB0 += wB3 * lo.x; aB1 += wB3 * lo.y; aB2 += wB3 * hi.x; aB3 += wB3 * hi.y;
        }
    }
    uint2 pkA, pkB;
    pkA.x = bfb(aA0) | ((uint)bfb(aA1) << 16);
    pkA.y = bfb(aA2) | ((uint)bfb(aA3) << 16);
    pkB.x = bfb(aB0) | ((uint)bfb(aB1) << 16);
    pkB.y = bfb(aB2) | ((uint)bfb(aB3) << 16);
    uint2* ag = (uint2*)aggG;
    ag[((size_t)b * CAP + j0 + la) * 64 + lane] = pkA;
    ag[((size_t)b * CAP + j0 + lb) * 64 + lane] = pkB;
}

// ---------------- kernel 5b: k_x2g — fused X2-MFMA + j-reduction -----------
// gaggP[b][xblk][:] = sum_{rows in block} val[m, j] * relu(agg @ w2 + b2)[j,:]
__global__ __launch_bounds__(256) void k_x2g(const int* __restrict__ cnt,
                                             const int* __restrict__ sid_last,
                                             const float* __restrict__ valA,
                                             const bf16* __restrict__ aggG,
                                             const uint4* __restrict__ w2f,
                                             const float* __restrict__ b2,
                                             float* __restrict__ gaggP) {
    __shared__ ushort agg[JT][264];   // 528B row stride
    __shared__ float vs[JT];
    int b = blockIdx.y, j0 = blockIdx.x * JT, tid = threadIdx.x;
    int m = sid_last[b];
    int cj = cnt[m];
    if (j0 >= cj) return;
    int nj = cj - j0; if (nj > JT) nj = JT;
    if (tid < JT) vs[tid] = (tid < nj) ? valA[m * CAP + j0 + tid] : 0.f;
    {
        const uint4* src = (const uint4*)(aggG + ((size_t)b * CAP + j0) * 256);
        for (int i = tid; i < 512; i += 256) {
            int row = i >> 5, col = i & 31;
            *(uint4*)&agg[row][col * 8] = src[i];
        }
    }
    __syncthreads();
    int lane = tid & 63;
    int w = __builtin_amdgcn_readfirstlane(tid >> 6);
    int col = lane & 15, rg = lane >> 4;
    s8v af[8];
#pragma unroll
    for (int kc = 0; kc < 8; ++kc)
        af[kc] = *(const s8v*)&agg[col][kc * 32 + rg * 8];
    float* outp = gaggP + ((size_t)b * 8 + blockIdx.x) * 256;
#pragma unroll
    for (int t = 0; t < 4; ++t) {
        int nt = w * 4 + t;
        f4v acc = (f4v){0.f, 0.f, 0.f, 0.f};
#pragma unroll
        for (int kc = 0; kc < 8; ++kc) {
            s8v bf = *(const s8v*)&w2f[(nt * 8 + kc) * 64 + lane];
            acc = __builtin_amdgcn_mfma_f32_16x16x32_bf16(af[kc], bf, acc, 0, 0, 0);
        }
        float bv = b2[nt * 16 + col];
        float p = 0.f;
#pragma unroll
        for (int i = 0; i < 4; ++i) {
            float vv = acc[i] + bv;
            vv = vv > 0.f ? vv : 0.f;
            p += vs[rg * 4 + i] * vv;
        }
        p += __shfl_xor(p, 16);
        p += __shfl_xor(p, 32);
        if (lane < 16) outp[nt * 16 + col] = p;
    }
}

// ---------------- kernel 6b: k_gmm — g = relu(sum(gaggP) @ w3 + b3) --------
__global__ __launch_bounds__(256) void k_gmm(const int* __restrict__ cnt,
                                             const int* __restrict__ sid_last,
                                             const float* __restrict__ gaggP,
                                             const float* __restrict__ w3,
                                             const float* __restrict__ b3,
                                             float* __restrict__ g) {
    int b = blockIdx.x, ot = blockIdx.y, tid = threadIdx.x;
    __shared__ float h[256];
    {
        int m = sid_last[b];
        int cj = cnt[m];
        int nq = (cj + JT - 1) / JT;
        const float* p = gaggP + (size_t)b * 8 * 256 + tid;
        float s = 0.f;
        for (int q = 0; q < nq; ++q) s += p[q * 256];
        h[tid] = s;
    }
    __syncthreads();
    int q  = tid & 31;       // output quad
    int kg = tid >> 5;       // 0..7, K-group of 32
    const float4* w4 = (const float4*)w3;     // 128 quads per k-row
    int wq = ot * 32 + q;
    float4 acc = {0.f, 0.f, 0.f, 0.f};
    for (int k = kg * 32; k < kg * 32 + 32; ++k) {
        float hk = h[k];
        float4 w = w4[(size_t)k * 128 + wq];
        acc.x += hk * w.x; acc.y += hk * w.y; acc.z += hk * w.z; acc.w += hk * w.w;
    }
    __shared__ float4 red[8][32];
    red[kg][q] = acc;
    __syncthreads();
    if (tid < 32) {
        float4 s = red[0][tid];
#pragma unroll
        for (int gr = 1; gr < 8; ++gr) {
            float4 r = red[gr][tid];
            s.x += r.x; s.y += r.y; s.z += r.z; s.w += r.w;
        }
        int ob = ot * 128 + tid * 4;
        s.x += b3[ob];     s.x = s.x > 0.f ? s.x : 0.f;
        s.y += b3[ob + 1]; s.y = s.y > 0.f ? s.y : 0.f;
        s.z += b3[ob + 2]; s.z = s.z > 0.f ? s.z : 0.f;
        s.w += b3[ob + 3]; s.w = s.w > 0.f ? s.w : 0.f;
        *(float4*)&g[(size_t)b * 512 + ob] = s;
    }
}

// ---------------- k_fc0s: hp0 = x_last @ w0 + b0, fused batch stats --------
__global__ __launch_bounds__(256) void k_fc0s(const float* __restrict__ x,
                                              const float* __restrict__ w0,
                                              const float* __restrict__ b0,
                                              float* __restrict__ hp0,
                                              float* __restrict__ mu0,
                                              float* __restrict__ rstd0) {
    int tid = threadIdx.x;
    int c = tid >> 7, b = tid & 127;
    int o = blockIdx.x * 2 + c;
    const float* xr = x + (size_t)b * XROW + (S - 1) * 17;
    float acc = b0[o];
#pragma unroll
    for (int f = 0; f < 15; ++f) acc += xr[f] * w0[f * 512 + o];
    hp0[b * 512 + o] = acc;
    float s = acc, s2 = acc * acc;
    for (int off = 32; off > 0; off >>= 1) {
        s += __shfl_down(s, off);
        s2 += __shfl_down(s2, off);
    }
    __shared__ float rs[4], rs2[4];
    int wv = tid >> 6;
    if ((tid & 63) == 0) { rs[wv] = s; rs2[wv] = s2; }
    __syncthreads();
    if ((tid & 127) == 0) {
        float S1 = rs[c * 2] + rs[c * 2 + 1];
        float S2 = rs2[c * 2] + rs2[c * 2 + 1];
        float m = S1 * (1.f / B);
        float var = S2 * (1.f / B) - m * m;
        mu0[o] = m;
        rstd0[o] = rsqrtf(var + 1e-5f);
    }
}

// ---------------- k_bn1w: widened batch-norm stats for hp1 (grid 16) -------
__global__ __launch_bounds__(256) void k_bn1w(const float* __restrict__ h,
                                              float* __restrict__ mu,
                                              float* __restrict__ rstd) {
    int tid = threadIdx.x;
    int o = blockIdx.x * 32 + (tid & 31);
    int bg = tid >> 5;   // 0..7
    float s = 0.f, s2 = 0.f;
    for (int b = bg * 16; b < bg * 16 + 16; ++b) {
        float v = h[b * 512 + o];
        s += v; s2 += v * v;
    }
    __shared__ float rs[8][32], rs2[8][32];
    rs[bg][tid & 31] = s; rs2[bg][tid & 31] = s2;
    __syncthreads();
    if (tid < 32) {
        float S1 = 0.f, S2 = 0.f;
#pragma unroll
        for (int g2 = 0; g2 < 8; ++g2) { S1 += rs[g2][tid]; S2 += rs2[g2][tid]; }
        float m = S1 * (1.f / B);
        float var = S2 * (1.f / B) - m * m;
        mu[blockIdx.x * 32 + tid] = m;
        rstd[blockIdx.x * 32 + tid] = rsqrtf(var + 1e-5f);
    }
}

// ---------------- kernel 9: hp1 = [leaky(bn(hp0)), g] @ w1 + b1 ------------
__global__ __launch_bounds__(256) void k_fc1(const float* __restrict__ hp0,
                                             const float* __restrict__ mu0,
                                             const float* __restrict__ rstd0,
                                             const float* __restrict__ gam,
                                             const float* __restrict__ bet,
                                             const float* __restrict__ gbuf,
                                             const float* __restrict__ w1,
                                             const float* __restrict__ b1,
                                             float* __restrict__ hp1) {
    int b = blockIdx.x, ot = blockIdx.y, tid = threadIdx.x;
    __shared__ float h[1024];
    for (int o = tid; o < 512; o += 256) {
        float v = hp0[b * 512 + o];
        v = gam[o] * (v - mu0[o]) * rstd0[o] + bet[o];
        h[o] = v >= 0.f ? v : 0.01f * v;
        h[512 + o] = gbuf[(size_t)b * 512 + o];
    }
    __syncthreads();
    int q  = tid & 31;
    int kg = tid >> 5;
    const float4* w4 = (const float4*)w1;
    int wq = ot * 32 + q;
    float4 acc = {0.f, 0.f, 0.f, 0.f};
    for (int k = kg * 128; k < kg * 128 + 128; ++k) {
        float hk = h[k];
        float4 w = w4[(size_t)k * 128 + wq];
        acc.x += hk * w.x; acc.y += hk * w.y; acc.z += hk * w.z; acc.w += hk * w.w;
    }
    __shared__ float4 red[8][32];
    red[kg][q] = acc;
    __syncthreads();
    if (tid < 32) {
        float4 s = red[0][tid];
#pragma unroll
        for (int gr = 1; gr < 8; ++gr) {
            float4 r = red[gr][tid];
            s.x += r.x; s.y += r.y; s.z += r.z; s.w += r.w;
        }
        int ob = ot * 128 + tid * 4;
        s.x += b1[ob]; s.y += b1[ob + 1]; s.z += b1[ob + 2]; s.w += b1[ob + 3];
        *(float4*)&hp1[b * 512 + ob] = s;
    }
}

// ---------------- kernel 11: out = sigmoid(leaky(bn(hp1)) @ w2 + b2) -------
__global__ __launch_bounds__(64) void k_out(const float* __restrict__ hp1,
                                            const float* __restrict__ mu1,
                                            const float* __restrict__ rstd1,
                                            const float* __restrict__ gam,
                                            const float* __restrict__ bet,
                                            const float* __restrict__ w2,
                                            const float* __restrict__ b2,
                                            float* __restrict__ out) {
    int b = blockIdx.x, lane = threadIdx.x;
    float acc = 0.f;
    for (int o = lane; o < 512; o += 64) {
        float v = hp1[b * 512 + o];
        v = gam[o] * (v - mu1[o]) * rstd1[o] + bet[o];
        v = v >= 0.f ? v : 0.01f * v;
        acc += v * w2[o];
    }
    for (int off = 32; off > 0; off >>= 1) acc += __shfl_down(acc, off);
    if (lane == 0) out[b] = 1.f / (1.f + expf(-(acc + b2[0])));
}

static inline size_t align256(size_t x) { return (x + 255) & ~(size_t)255; }

extern "C" void kernel_launch(void* const* d_in, const int* in_sizes, int n_in,
                              void* d_out, int out_size, void* d_ws, size_t ws_size,
                              hipStream_t stream) {
    const float* x     = (const float*)d_in[0];
    const float* adj   = (const float*)d_in[1];
    const float* w_gc1 = (const float*)d_in[2];
    const float* b_gc1 = (const float*)d_in[3];
    const float* w_gc2 = (const float*)d_in[4];
    const float* b_gc2 = (const float*)d_in[5];
    const float* w_gc3 = (const float*)d_in[6];
    const float* b_gc3 = (const float*)d_in[7];
    const float* w_fc0 = (const float*)d_in[8];
    const float* b_fc0 = (const float*)d_in[9];
    const float* g_fc0 = (const float*)d_in[10];
    const float* be_fc0= (const float*)d_in[11];
    const float* w_fc1 = (const float*)d_in[12];
    const float* b_fc1 = (const float*)d_in[13];
    const float* g_fc1 = (const float*)d_in[14];
    const float* be_fc1= (const float*)d_in[15];
    const float* w_fc2 = (const float*)d_in[16];
    const float* b_fc2 = (const float*)d_in[17];

    char* wsp = (char*)d_ws;
    size_t off = 0;
    auto alloc = [&](size_t bytes) { void* p = wsp + off; off = align256(off + bytes); return p; };
    float* d_deg   = (float*)alloc((size_t)N * 4);
    int*   sid     = (int*)  alloc((size_t)B * 63 * 4);
    int*   sidl    = (int*)  alloc((size_t)B * 4);
    uint4* feA     = (uint4*)alloc((size_t)B * 2 * 64 * 16);
    uint4* wfrag   = (uint4*)alloc((size_t)1024 * 16);
    uint4* w2frag  = (uint4*)alloc((size_t)8192 * 16);
    int*   csr_cnt = (int*)  alloc((size_t)N * 4);
    int*   csr_idx = (int*)  alloc((size_t)N * CAP * 4);
    float* csr_val = (float*)alloc((size_t)N * CAP * 4);
    unsigned char* X1 = (unsigned char*)alloc((size_t)B * N * 256);
    bf16*  aggG    = (bf16*) alloc((size_t)B * CAP * 256 * 2);
    float* gaggP   = (float*)alloc((size_t)B * 8 * 256 * 4);
    float* gbuf    = (float*)alloc((size_t)B * 512 * 4);
    float* hp0     = (float*)alloc((size_t)B * 512 * 4);
    float* mu0     = (float*)alloc(512 * 4);
    float* rstd0   = (float*)alloc(512 * 4);
    float* hp1     = (float*)alloc((size_t)B * 512 * 4);
    float* mu1     = (float*)alloc(512 * 4);
    float* rstd1   = (float*)alloc(512 * 4);

    k_prep0 <<<N + 36, 256, 0, stream>>>(adj, d_deg, w_gc1, w_gc2, wfrag, w2frag);
    k_prep1 <<<500 + B, 256, 0, stream>>>(adj, d_deg, x, csr_cnt, csr_idx, csr_val, sid, sidl, feA);
    k_x1    <<<dim3(32, B), 256, 0, stream>>>(adj, d_deg, sid, feA, wfrag, b_gc1, X1);
    k_gather<<<dim3(CAP / JG, B), 256, 0, stream>>>(csr_cnt, csr_idx, csr_val, sidl, X1, aggG);
    k_x2g   <<<dim3(CAP / JT, B), 256, 0, stream>>>(csr_cnt, sidl, csr_val, aggG, w2frag, b_gc2, gaggP);
    k_gmm   <<<dim3(B, 4), 256, 0, stream>>>(csr_cnt, sidl, gaggP, w_gc3, b_gc3, gbuf);
    k_fc0s  <<<256, 256, 0, stream>>>(x, w_fc0, b_fc0, hp0, mu0, rstd0);
    k_fc1   <<<dim3(B, 4), 256, 0, stream>>>(hp0, mu0, rstd0, g_fc0, be_fc0, gbuf, w_fc1, b_fc1, hp1);
    k_bn1w  <<<16, 256, 0, stream>>>(hp1, mu1, rstd1);
    k_out   <<<B, 64, 0, stream>>>(hp1, mu1, rstd1, g_fc1, be_fc1, w_fc2, b_fc2, (float*)d_out);
}